// Round 10
// baseline (853.533 us; speedup 1.0000x reference)
//
#include <hip/hip_runtime.h>

// ---------------------------------------------------------------------------
// GATBottleneck (ALL I/O fp32; compute bf16 MFMA, fp32 accum)
//
//  1. trcvt: x fp32 NCHW -> xt bf16 [16384][1024]
//  2. trcvt: WgT2 bf16 [4096][512]; WgT2[hj][c] = w_gat[c][hj]
//  3. cvt  : w_reduce, w_restore fp32 -> bf16 (already B^T layout)
//  4. gemm<1>: xr = relu(bn(xt @ w_reduce^T))          [16384][512] bf16
//  5. attproj: P[s][h][c] = sum_t w_gat[c][h*512+t]*att_s[h][t]   (fp32)
//  6. att    : a_s[n][h] = xr[n] . P[s][h]                        (fp32)
//  7. gemm2b : Y = xr @ WgT2^T   [16384][4096] bf16 -- 256x256 tile, BK=32,
//              8 waves, DOUBLE-buffered LDS (64KB -> 2 blocks/CU), one
//              barrier + vmcnt(0) per tile, R6 conflict-free swizzle,
//              setprio on MFMA.  Cross-block overlap hides drains (m114).
//  8. agg2   : per node: head-softmax alphas over {self + 4 nbrs},
//              gat[n][j] = bias[j] + sum_e sum_h (alpha/8) Y[v_e][h*512+j]
//  9. gemm<3>: out = relu(bn(gat @ w_restore^T) + x)   -> fp32 NCHW
// edge_index is the fixed 4-neighbor grid + self loops -> analytic.
// ---------------------------------------------------------------------------

typedef unsigned short u16;
typedef __attribute__((ext_vector_type(4))) unsigned short u16x4;
typedef __attribute__((ext_vector_type(8))) unsigned short u16x8;
typedef __attribute__((ext_vector_type(8))) __bf16 bf16x8;
typedef __attribute__((ext_vector_type(4))) float f32x4;

#define B_    64
#define CIN   1024
#define CRED  512
#define COUT  1024
#define NPIX  256
#define HEADS 8
#define KGAT  4096
#define MTOT  16384
#define EPSB  1e-5f

__device__ __forceinline__ float b2f(u16 u) {
  union { unsigned u; float f; } c; c.u = ((unsigned)u) << 16; return c.f;
}
__device__ __forceinline__ u16 f2b(float f) {
  union { float f; unsigned u; } c; c.f = f;
  unsigned r = (c.u + 0x7FFFu + ((c.u >> 16) & 1u)) >> 16;
  return (u16)r;
}

__device__ __forceinline__ void gload_lds16(const void* g, void* lds) {
  __builtin_amdgcn_global_load_lds(
      (const __attribute__((address_space(1))) void*)g,
      (__attribute__((address_space(3))) void*)lds, 16, 0, 0);
}

// ============ 256x256 double-buffered GEMM: Y = A @ Bt^T ===================
// A [16384][512] bf16, Bt [4096][512] bf16, out [16384][4096] bf16.
// 8 waves (2M x 4N), wave tile 128x64.  BK=32, 16 K-tiles.
// LDS: 2 buffers x { A 256x32 (16KB) | B 256x32 (16KB) } = 64 KiB
//   -> 2 blocks/CU (16 waves/CU) for cross-block latency hiding.
// Swizzle (R6-verified, 0 conflicts): 16B chunk (row,kb) at kb ^ ((row>>1)&3);
//   staging pre-swizzles the GLOBAL source, LDS dest linear (both-sides).
// Sync: ONE barrier + vmcnt(0) per tile.  Race ledger: stage at tile t
//   writes buf (t+1)&1 (readers touch t&1, disjoint); reads of buf (t+1)&1
//   happen after barrier t+1, which follows every wave's vmcnt(0) drain.
__global__ __launch_bounds__(512, 4) void gemm2b_kernel(
    const u16* __restrict__ A, const u16* __restrict__ Bt,
    u16* __restrict__ out)
{
  extern __shared__ u16 lds[];
  const int tid = threadIdx.x;
  const int wave = tid >> 6, lane = tid & 63;
  const int wm = wave >> 2, wn = wave & 3;
  const int l15 = lane & 15, l4 = lane >> 4;

  // XCD-chunked swizzle over 1024 blocks (16 n-blocks x 64 m-blocks)
  int lin = blockIdx.y * 16 + blockIdx.x;
  lin = (lin & 7) * 128 + (lin >> 3);
  const int m0 = (lin >> 4) * 256;
  const int n0 = (lin & 15) * 256;

  // staging: 16B chunk f = issue*512 + tid -> (row = f>>2, kb' = f&3);
  // fetch global kb = kb' ^ ((row>>1)&3)  (involution)
  int offS[2], ldsS[2];
#pragma unroll
  for (int i = 0; i < 2; ++i) {
    const int f = i * 512 + tid;
    const int r = f >> 2;
    const int kb = (f & 3) ^ ((r >> 1) & 3);
    offS[i] = r * 512 + kb * 8;          // global element offset: row*K + k
    ldsS[i] = (i * 512 + wave * 64) * 8; // wave-uniform base (lane*16B auto)
  }
  const u16* gA = A + (size_t)m0 * 512;
  const u16* gB = Bt + (size_t)n0 * 512;

  auto stageA = [&](int kt) {
    const int bo = (kt & 1) * 16384;
    gload_lds16(gA + kt * 32 + offS[0], &lds[bo + ldsS[0]]);
    gload_lds16(gA + kt * 32 + offS[1], &lds[bo + ldsS[1]]);
  };
  auto stageB = [&](int kt) {
    const int bo = (kt & 1) * 16384 + 8192;
    gload_lds16(gB + kt * 32 + offS[0], &lds[bo + ldsS[0]]);
    gload_lds16(gB + kt * 32 + offS[1], &lds[bo + ldsS[1]]);
  };

  f32x4 acc[8][4];
#pragma unroll
  for (int i = 0; i < 8; ++i)
#pragma unroll
    for (int j = 0; j < 4; ++j) acc[i][j] = f32x4{0.f, 0.f, 0.f, 0.f};

  // ds_read bases: frag (row = base + f*16 + l15, kblk = l4), swizzled.
  const int kq = (l4 ^ ((l15 >> 1) & 3)) * 8;
  const int aBase = (wm * 128 + l15) * 32 + kq;
  const int bBase = 8192 + (wn * 64 + l15) * 32 + kq;

  stageA(0); stageB(0);

  for (int kt = 0; kt < 16; ++kt) {
    asm volatile("s_waitcnt vmcnt(0)" ::: "memory");
    __builtin_amdgcn_s_barrier();
    const int bo = (kt & 1) * 16384;
    bf16x8 bfr[4], af0[4], af1[4];
#pragma unroll
    for (int f = 0; f < 4; ++f)
      bfr[f] = *(const bf16x8*)&lds[bo + bBase + f * 512];
#pragma unroll
    for (int f = 0; f < 4; ++f)
      af0[f] = *(const bf16x8*)&lds[bo + aBase + f * 512];
#pragma unroll
    for (int f = 0; f < 4; ++f)
      af1[f] = *(const bf16x8*)&lds[bo + aBase + (f + 4) * 512];
    if (kt < 15) { stageA(kt + 1); stageB(kt + 1); }
    __builtin_amdgcn_s_setprio(1);
#pragma unroll
    for (int fm = 0; fm < 4; ++fm)
#pragma unroll
      for (int fn = 0; fn < 4; ++fn)
        acc[fm][fn] = __builtin_amdgcn_mfma_f32_16x16x32_bf16(
            af0[fm], bfr[fn], acc[fm][fn], 0, 0, 0);
#pragma unroll
    for (int fm = 0; fm < 4; ++fm)
#pragma unroll
      for (int fn = 0; fn < 4; ++fn)
        acc[fm + 4][fn] = __builtin_amdgcn_mfma_f32_16x16x32_bf16(
            af1[fm], bfr[fn], acc[fm + 4][fn], 0, 0, 0);
    __builtin_amdgcn_s_setprio(0);
  }

  // epilogue: row = m0 + wm*128 + fm*16 + l4*4 + r; col = n0 + wn*64 + fn*16 + l15
  const int rowb = m0 + wm * 128 + l4 * 4;
  const int colb = n0 + wn * 64 + l15;
#pragma unroll
  for (int fm = 0; fm < 8; ++fm)
#pragma unroll
    for (int fn = 0; fn < 4; ++fn)
#pragma unroll
      for (int r = 0; r < 4; ++r)
        out[(size_t)(rowb + fm * 16 + r) * KGAT + colb + fn * 16] =
            f2b(acc[fm][fn][r]);
}

// ------------- 64x64 transpose fp32 -> bf16 --------------------------------
__global__ __launch_bounds__(256) void trcvt_kernel(
    const float* __restrict__ src, u16* __restrict__ dst,
    int srs, int drs, long szs, long dzs)
{
  __shared__ float tile[64][65];
  const int t = threadIdx.x;
  const int tr = t >> 4, tc = (t & 15) * 4;
  const long sbase = (long)blockIdx.z * szs +
                     (long)(blockIdx.y * 64) * srs + blockIdx.x * 64;
#pragma unroll
  for (int i = 0; i < 4; ++i) {
    const int r = i * 16 + tr;
    const float4 v = *(const float4*)&src[sbase + (long)r * srs + tc];
    tile[r][tc]     = v.x;
    tile[r][tc + 1] = v.y;
    tile[r][tc + 2] = v.z;
    tile[r][tc + 3] = v.w;
  }
  __syncthreads();
  const long dbase = (long)blockIdx.z * dzs +
                     (long)(blockIdx.x * 64) * drs + blockIdx.y * 64;
#pragma unroll
  for (int i = 0; i < 4; ++i) {
    const int c = i * 16 + tr;
    u16x4 o;
#pragma unroll
    for (int q = 0; q < 4; ++q) o[q] = f2b(tile[tc + q][c]);
    *(u16x4*)&dst[dbase + (long)c * drs + tc] = o;
  }
}

// --------------------- elementwise fp32 -> bf16 convert --------------------
__global__ __launch_bounds__(256) void cvt_kernel(
    const float* __restrict__ src, u16* __restrict__ dst)
{
  const int i = (blockIdx.x * 256 + threadIdx.x) * 8;
  const float4 a = *(const float4*)&src[i];
  const float4 b = *(const float4*)&src[i + 4];
  u16x8 o;
  o[0] = f2b(a.x); o[1] = f2b(a.y); o[2] = f2b(a.z); o[3] = f2b(a.w);
  o[4] = f2b(b.x); o[5] = f2b(b.y); o[6] = f2b(b.z); o[7] = f2b(b.w);
  *(u16x8*)&dst[i] = o;
}

// ------------------------- 128x128 MFMA GEMM -------------------------------
// MODE 1: out16 = relu(bn(C)) bf16 row-major   (pg..pv fp32, len Nloc)
// MODE 3: out32 = relu(bn(C) + auxf) fp32 NCHW (auxf = x residual)
#define BM 128
#define BN 128
#define BK 32

template <int MODE>
__global__ __launch_bounds__(256, 2) void gemm_kernel(
    const u16* __restrict__ A, const u16* __restrict__ Bt,
    u16* __restrict__ out16, float* __restrict__ out32,
    const float* __restrict__ pg, const float* __restrict__ pb,
    const float* __restrict__ pm, const float* __restrict__ pv,
    const float* __restrict__ auxf, int K, int Nloc)
{
  const int gx = gridDim.x;
  const int nwg = gx * gridDim.y;
  int lin = blockIdx.y * gx + blockIdx.x;
  lin = (lin & 7) * (nwg >> 3) + (lin >> 3);
  const int m0 = (lin / gx) * BM, n0 = (lin % gx) * BN;

  __shared__ u16 As[BM * BK];
  __shared__ u16 Bs[BN * BK];
  const int tid = threadIdx.x;
  const int wave = tid >> 6, lane = tid & 63;

  const int eA0 = wave * 512 + lane * 8;
  const int eA1 = eA0 + 2048;
  const u16* gA0 = A + (size_t)(m0 + (eA0 >> 5)) * K + (eA0 & 31);
  const u16* gA1 = A + (size_t)(m0 + (eA1 >> 5)) * K + (eA1 & 31);
  const u16* gB0 = Bt + (size_t)(n0 + (eA0 >> 5)) * K + (eA0 & 31);
  const u16* gB1 = Bt + (size_t)(n0 + (eA1 >> 5)) * K + (eA1 & 31);
  u16* lA0 = &As[wave * 512];
  u16* lA1 = &As[wave * 512 + 2048];
  u16* lB0 = &Bs[wave * 512];
  u16* lB1 = &Bs[wave * 512 + 2048];

  f32x4 acc[4][4];
#pragma unroll
  for (int i = 0; i < 4; ++i)
#pragma unroll
    for (int j = 0; j < 4; ++j) acc[i][j] = f32x4{0.f, 0.f, 0.f, 0.f};

  const int wr = wave >> 1, wc = wave & 1;
  const int l15 = lane & 15, kb = (lane >> 4) * 8;

  for (int kt = 0; kt < K; kt += BK) {
    gload_lds16(gA0, lA0); gload_lds16(gA1, lA1);
    gload_lds16(gB0, lB0); gload_lds16(gB1, lB1);
    gA0 += BK; gA1 += BK; gB0 += BK; gB1 += BK;
    __syncthreads();
    bf16x8 af[4], bfr[4];
#pragma unroll
    for (int f = 0; f < 4; ++f) {
      af[f]  = *(const bf16x8*)&As[(wr * 64 + f * 16 + l15) * BK + kb];
      bfr[f] = *(const bf16x8*)&Bs[(wc * 64 + f * 16 + l15) * BK + kb];
    }
#pragma unroll
    for (int fm = 0; fm < 4; ++fm)
#pragma unroll
      for (int fn = 0; fn < 4; ++fn)
        acc[fm][fn] = __builtin_amdgcn_mfma_f32_16x16x32_bf16(
            af[fm], bfr[fn], acc[fm][fn], 0, 0, 0);
    __syncthreads();
  }

  const int rowb = m0 + wr * 64 + (lane >> 4) * 4;
#pragma unroll
  for (int fn = 0; fn < 4; ++fn) {
    const int col = n0 + wc * 64 + fn * 16 + l15;
    const float sc = pg[col] * rsqrtf(pv[col] + EPSB);
    const float off = pb[col] - pm[col] * sc;
#pragma unroll
    for (int fm = 0; fm < 4; ++fm) {
      const int row = rowb + fm * 16;
      if (MODE == 3) {
        const int bimg = row >> 8, p0 = row & 255;
        const size_t oa = (size_t)bimg * (COUT * NPIX) + (size_t)col * NPIX + p0;
        const float4 rv = *(const float4*)&auxf[oa];
        float4 ov;
        ov.x = fmaxf(acc[fm][fn][0] * sc + off + rv.x, 0.f);
        ov.y = fmaxf(acc[fm][fn][1] * sc + off + rv.y, 0.f);
        ov.z = fmaxf(acc[fm][fn][2] * sc + off + rv.z, 0.f);
        ov.w = fmaxf(acc[fm][fn][3] * sc + off + rv.w, 0.f);
        *(float4*)&out32[oa] = ov;
      } else {
#pragma unroll
        for (int r = 0; r < 4; ++r) {
          const float y = fmaxf(acc[fm][fn][r] * sc + off, 0.f);
          out16[(size_t)(row + r) * Nloc + col] = f2b(y);
        }
      }
    }
  }
}

// ---------- P[s][h][c] = sum_t w_gat[c][h*512+t] * att_s[h][t] (fp32) ------
__global__ __launch_bounds__(256) void attproj_kernel(
    const float* __restrict__ w_gat, const float* __restrict__ att_src,
    const float* __restrict__ att_dst, float* __restrict__ P)
{
  __shared__ float av[CRED];
  const int sh = blockIdx.x;
  const int s = sh >> 3, h = sh & 7;
  const float* att = (s == 0) ? att_src : att_dst;
  for (int t = threadIdx.x; t < CRED; t += 256) av[t] = att[h * CRED + t];
  __syncthreads();
#pragma unroll
  for (int half = 0; half < 2; ++half) {
    const int c = threadIdx.x + half * 256;
    const float* wrow = w_gat + (size_t)c * KGAT + h * CRED;
    float acc = 0.f;
    for (int j = 0; j < CRED; j += 4) {
      const float4 w = *(const float4*)&wrow[j];
      acc += w.x * av[j] + w.y * av[j + 1] + w.z * av[j + 2] + w.w * av[j + 3];
    }
    P[(size_t)sh * CRED + c] = acc;
  }
}

// ---------- a_all[s][n][h] = xr[n] . P[s][h]   (one wave per node) ---------
__global__ __launch_bounds__(256) void att_kernel(
    const u16* __restrict__ xr, const float* __restrict__ P,
    float* __restrict__ a_all)
{
  const int wave = threadIdx.x >> 6, lane = threadIdx.x & 63;
  const int m = blockIdx.x * 4 + wave;
  const int sh = lane & 15, q = lane >> 4;
  const u16* xp = xr + (size_t)m * CRED + q * 128;
  const float* Pp = P + (size_t)sh * CRED + q * 128;
  float s = 0.f;
#pragma unroll
  for (int c = 0; c < 128; c += 8) {
    u16x8 xv = *(const u16x8*)&xp[c];
#pragma unroll
    for (int t = 0; t < 8; ++t) s += b2f(xv[t]) * Pp[c + t];
  }
  s += __shfl_xor(s, 16);
  s += __shfl_xor(s, 32);
  if (q == 0)
    a_all[(size_t)(sh >> 3) * MTOT * HEADS + (size_t)m * HEADS + (sh & 7)] = s;
}

// ---- per node: softmax alphas (8 heads x 5 edges) in LDS, then
//      gat[n][j] = bias[j] + sum_e sum_h (alpha[e][h]/8) * Y[v_e][h*512+j] ---
__global__ __launch_bounds__(256) void agg2_kernel(
    const u16* __restrict__ Y, const float* __restrict__ a_all,
    const float* __restrict__ gat_bias, u16* __restrict__ gat)
{
  int bid = blockIdx.x;
  bid = (bid & 7) * (MTOT >> 3) + (bid >> 3);
  const int u = bid & 255, b = bid >> 8;
  const int gi = u >> 4, gj = u & 15;
  const size_t nb = (size_t)b * NPIX;
  const int t = threadIdx.x;

  const int v0 = u;
  const int v1 = (gi > 0)  ? u - 16 : -1;
  const int v2 = (gi < 15) ? u + 16 : -1;
  const int v3 = (gj > 0)  ? u - 1  : -1;
  const int v4 = (gj < 15) ? u + 1  : -1;
  const int vs[5] = { v0, v1, v2, v3, v4 };

  __shared__ float alf[5][8];
  if (t < 8) {
    const int h = t;
    const float* a_src = a_all;
    const float* a_dst = a_all + (size_t)MTOT * HEADS;
    const float adst = a_dst[(nb + u) * HEADS + h];
    float l[5];
    float mx = -1e30f;
#pragma unroll
    for (int e = 0; e < 5; ++e) {
      if (vs[e] >= 0) {
        const float xx = a_src[(nb + vs[e]) * HEADS + h] + adst;
        l[e] = xx > 0.f ? xx : 0.2f * xx;
        mx = fmaxf(mx, l[e]);
      } else {
        l[e] = -1e30f;
      }
    }
    float s = 0.f, ee[5];
#pragma unroll
    for (int e = 0; e < 5; ++e) {
      ee[e] = (vs[e] >= 0) ? __expf(l[e] - mx) : 0.f;
      s += ee[e];
    }
    const float inv = 0.125f / s;
#pragma unroll
    for (int e = 0; e < 5; ++e) alf[e][h] = ee[e] * inv;
  }
  __syncthreads();

  const int j0 = t * 2;
  float o0 = gat_bias[j0], o1 = gat_bias[j0 + 1];
#pragma unroll
  for (int e = 0; e < 5; ++e) {
    const int vv = vs[e];
    if (vv < 0) continue;
    const u16* yp = Y + (nb + vv) * (size_t)KGAT + j0;
#pragma unroll
    for (int h = 0; h < HEADS; ++h) {
      const float a = alf[e][h];
      const unsigned w = *(const unsigned*)(yp + h * CRED);
      o0 += a * b2f((u16)(w & 0xffffu));
      o1 += a * b2f((u16)(w >> 16));
    }
  }
  const unsigned ow = ((unsigned)f2b(o1) << 16) | (unsigned)f2b(o0);
  *(unsigned*)&gat[(nb + u) * (size_t)CRED + j0] = ow;
}

// ---------------------------------------------------------------------------
extern "C" void kernel_launch(void* const* d_in, const int* in_sizes, int n_in,
                              void* d_out, int out_size, void* d_ws, size_t ws_size,
                              hipStream_t stream)
{
  const float* x         = (const float*)d_in[0];
  const float* w_reduce  = (const float*)d_in[1];
  const float* g_red     = (const float*)d_in[2];
  const float* b_red     = (const float*)d_in[3];
  const float* m_red     = (const float*)d_in[4];
  const float* v_red     = (const float*)d_in[5];
  const float* w_gat     = (const float*)d_in[6];
  const float* att_src   = (const float*)d_in[7];
  const float* att_dst   = (const float*)d_in[8];
  const float* gat_bias  = (const float*)d_in[9];
  const float* w_restore = (const float*)d_in[10];
  const float* g_res     = (const float*)d_in[11];
  const float* b_res     = (const float*)d_in[12];
  const float* m_res     = (const float*)d_in[13];
  const float* v_res     = (const float*)d_in[14];

  constexpr size_t SZ_Y    = (size_t)MTOT * KGAT * 2;
  constexpr size_t SZ_XR   = (size_t)MTOT * CRED * 2;
  constexpr size_t SZ_GAT  = SZ_XR;
  constexpr size_t SZ_WGT  = (size_t)KGAT * CRED * 2;
  constexpr size_t SZ_WRD  = (size_t)CRED * CIN * 2;
  constexpr size_t SZ_WRS  = (size_t)COUT * CRED * 2;
  constexpr size_t SZ_P    = (size_t)16 * CRED * 4;
  char* ws = (char*)d_ws;
  u16*   Y      = (u16*)ws;
  u16*   xt     = (u16*)ws;  // alias of Y (xt dead before Y written)
  u16*   xr     = (u16*)(ws + SZ_Y);
  u16*   gat    = (u16*)(ws + SZ_Y + SZ_XR);
  u16*   WgT2   = (u16*)(ws + SZ_Y + SZ_XR + SZ_GAT);
  u16*   wred_b = (u16*)(ws + SZ_Y + SZ_XR + SZ_GAT + SZ_WGT);
  u16*   wres_b = (u16*)(ws + SZ_Y + SZ_XR + SZ_GAT + SZ_WGT + SZ_WRD);
  float* P      = (float*)(ws + SZ_Y + SZ_XR + SZ_GAT + SZ_WGT + SZ_WRD + SZ_WRS);
  float* a_all  = (float*)(ws + SZ_Y + SZ_XR + SZ_GAT + SZ_WGT + SZ_WRD + SZ_WRS + SZ_P);
  float* outp   = (float*)d_out;

  hipFuncSetAttribute((const void*)gemm2b_kernel,
                      hipFuncAttributeMaxDynamicSharedMemorySize, 65536);

  trcvt_kernel<<<dim3(4, 16, 64), 256, 0, stream>>>(
      x, xt, NPIX, CIN, (long)CIN * NPIX, (long)CIN * NPIX);
  trcvt_kernel<<<dim3(64, 8, 1), 256, 0, stream>>>(
      w_gat, WgT2, KGAT, CRED, 0, 0);
  cvt_kernel<<<(CRED * CIN) / 2048, 256, 0, stream>>>(w_reduce, wred_b);
  cvt_kernel<<<(COUT * CRED) / 2048, 256, 0, stream>>>(w_restore, wres_b);
  gemm_kernel<1><<<dim3(4, 128), 256, 0, stream>>>(
      xt, wred_b, xr, nullptr, g_red, b_red, m_red, v_red, nullptr, CIN, CRED);
  attproj_kernel<<<16, 256, 0, stream>>>(w_gat, att_src, att_dst, P);
  att_kernel<<<MTOT / 4, 256, 0, stream>>>(xr, P, a_all);
  gemm2b_kernel<<<dim3(16, 64), 512, 65536, stream>>>(xr, WgT2, Y);
  agg2_kernel<<<MTOT, 256, 0, stream>>>(Y, a_all, gat_bias, gat);
  gemm_kernel<3><<<dim3(8, 128), 256, 0, stream>>>(
      gat, wres_b, nullptr, outp, g_res, b_res, m_res, v_res, x, CRED, COUT);
  (void)in_sizes; (void)n_in; (void)out_size; (void)ws_size;
}

// Round 11
// 323.048 us; speedup vs baseline: 2.6421x; 2.6421x over previous
//
#include <hip/hip_runtime.h>

// ---------------------------------------------------------------------------
// GATBottleneck (ALL I/O fp32; compute bf16 MFMA, fp32 accum)
//
//  1. trcvt: x fp32 NCHW -> xt bf16 [16384][1024]
//  2. trcvt: WgT2 bf16 [4096][512]; WgT2[hj][c] = w_gat[c][hj]
//  3. cvt  : w_reduce, w_restore fp32 -> bf16 (already B^T layout)
//  4. gemm_red: xr = relu(bn(xt @ w_reduce^T))  [16384][512] bf16
//              64x128 tile -> 1024 blocks (4/CU) for cross-block overlap
//  5. attproj: P[s][h][c] = sum_t w_gat[c][h*512+t]*att_s[h][t]   (fp32)
//  6. att    : a_s[n][h] = xr[n] . P[s][h]                        (fp32)
//  7. gemm8p : Y = xr @ WgT2^T   [16384][4096] bf16  (R6-verified: 256x256,
//              BK=32, 8 waves, 4-deep LDS (128KB), one barrier + counted
//              vmcnt(4) per K-tile, conflict-free swizzle, setprio)
//  8. agg2   : per node: head-softmax alphas over {self + 4 nbrs},
//              gat[n][j] = bias[j] + sum_e sum_h (alpha/8) Y[v_e][h*512+j]
//  9. gemm<3>: out = relu(bn(gat @ w_restore^T) + x)   -> fp32 NCHW
// edge_index is the fixed 4-neighbor grid + self loops -> analytic.
// R10 lesson: 256^2-tile 8-wave kernel CANNOT run 2 blocks/CU -- acc alone
// is 128 regs; __launch_bounds__(512,4) caused full accumulator spill (2GB
// scratch writes).  Y-GEMM stays at R6's 1-block/CU counted-vmcnt config.
// ---------------------------------------------------------------------------

typedef unsigned short u16;
typedef __attribute__((ext_vector_type(4))) unsigned short u16x4;
typedef __attribute__((ext_vector_type(8))) unsigned short u16x8;
typedef __attribute__((ext_vector_type(8))) __bf16 bf16x8;
typedef __attribute__((ext_vector_type(4))) float f32x4;

#define B_    64
#define CIN   1024
#define CRED  512
#define COUT  1024
#define NPIX  256
#define HEADS 8
#define KGAT  4096
#define MTOT  16384
#define EPSB  1e-5f

__device__ __forceinline__ float b2f(u16 u) {
  union { unsigned u; float f; } c; c.u = ((unsigned)u) << 16; return c.f;
}
__device__ __forceinline__ u16 f2b(float f) {
  union { float f; unsigned u; } c; c.f = f;
  unsigned r = (c.u + 0x7FFFu + ((c.u >> 16) & 1u)) >> 16;
  return (u16)r;
}

__device__ __forceinline__ void gload_lds16(const void* g, void* lds) {
  __builtin_amdgcn_global_load_lds(
      (const __attribute__((address_space(1))) void*)g,
      (__attribute__((address_space(3))) void*)lds, 16, 0, 0);
}

// ================= 256x256 pipelined GEMM: Y = A @ Bt^T (R6 exact) =========
__global__ __launch_bounds__(512, 1) void gemm8p_kernel(
    const u16* __restrict__ A, const u16* __restrict__ Bt,
    u16* __restrict__ out)
{
  extern __shared__ u16 lds[];
  const int tid = threadIdx.x;
  const int wave = tid >> 6, lane = tid & 63;
  const int wm = wave >> 2, wn = wave & 3;
  const int l15 = lane & 15, l4 = lane >> 4;

  int lin = blockIdx.y * 16 + blockIdx.x;
  lin = (lin & 7) * 128 + (lin >> 3);
  const int m0 = (lin >> 4) * 256;
  const int n0 = (lin & 15) * 256;

  int offS[2], ldsS[2];
#pragma unroll
  for (int i = 0; i < 2; ++i) {
    const int f = i * 512 + tid;
    const int r = f >> 2;
    const int kb = (f & 3) ^ ((r >> 1) & 3);
    offS[i] = r * 512 + kb * 8;
    ldsS[i] = (i * 512 + wave * 64) * 8;
  }
  const u16* gA = A + (size_t)m0 * 512;
  const u16* gB = Bt + (size_t)n0 * 512;

  auto stageA = [&](int kt) {
    const int bo = (kt & 3) * 16384;
    gload_lds16(gA + kt * 32 + offS[0], &lds[bo + ldsS[0]]);
    gload_lds16(gA + kt * 32 + offS[1], &lds[bo + ldsS[1]]);
  };
  auto stageB = [&](int kt) {
    const int bo = (kt & 3) * 16384 + 8192;
    gload_lds16(gB + kt * 32 + offS[0], &lds[bo + ldsS[0]]);
    gload_lds16(gB + kt * 32 + offS[1], &lds[bo + ldsS[1]]);
  };

  f32x4 acc[8][4];
#pragma unroll
  for (int i = 0; i < 8; ++i)
#pragma unroll
    for (int j = 0; j < 4; ++j) acc[i][j] = f32x4{0.f, 0.f, 0.f, 0.f};

  const int kq = (l4 ^ ((l15 >> 1) & 3)) * 8;
  const int aBase = (wm * 128 + l15) * 32 + kq;
  const int bBase = 8192 + (wn * 64 + l15) * 32 + kq;

  stageA(0); stageB(0); stageA(1); stageB(1);

  for (int kt = 0; kt < 16; ++kt) {
    if (kt == 15) { asm volatile("s_waitcnt vmcnt(0)" ::: "memory"); }
    else         { asm volatile("s_waitcnt vmcnt(4)" ::: "memory"); }
    __builtin_amdgcn_s_barrier();
    const int bo = (kt & 3) * 16384;
    bf16x8 bfr[4], af0[4], af1[4];
#pragma unroll
    for (int f = 0; f < 4; ++f)
      bfr[f] = *(const bf16x8*)&lds[bo + bBase + f * 512];
#pragma unroll
    for (int f = 0; f < 4; ++f)
      af0[f] = *(const bf16x8*)&lds[bo + aBase + f * 512];
#pragma unroll
    for (int f = 0; f < 4; ++f)
      af1[f] = *(const bf16x8*)&lds[bo + aBase + (f + 4) * 512];
    if (kt < 14) { stageA(kt + 2); stageB(kt + 2); }
    __builtin_amdgcn_s_setprio(1);
#pragma unroll
    for (int fm = 0; fm < 4; ++fm)
#pragma unroll
      for (int fn = 0; fn < 4; ++fn)
        acc[fm][fn] = __builtin_amdgcn_mfma_f32_16x16x32_bf16(
            af0[fm], bfr[fn], acc[fm][fn], 0, 0, 0);
#pragma unroll
    for (int fm = 0; fm < 4; ++fm)
#pragma unroll
      for (int fn = 0; fn < 4; ++fn)
        acc[fm + 4][fn] = __builtin_amdgcn_mfma_f32_16x16x32_bf16(
            af1[fm], bfr[fn], acc[fm + 4][fn], 0, 0, 0);
    __builtin_amdgcn_s_setprio(0);
  }

  const int rowb = m0 + wm * 128 + l4 * 4;
  const int colb = n0 + wn * 64 + l15;
#pragma unroll
  for (int fm = 0; fm < 8; ++fm)
#pragma unroll
    for (int fn = 0; fn < 4; ++fn)
#pragma unroll
      for (int r = 0; r < 4; ++r)
        out[(size_t)(rowb + fm * 16 + r) * KGAT + colb + fn * 16] =
            f2b(acc[fm][fn][r]);
}

// ============== 64x128 reduce GEMM: xr = relu(bn(xt @ w^T)) ================
// M=16384 K=1024 N=512.  Grid 4x256 = 1024 blocks (4/CU) -> cross-block
// overlap hides the 2-barrier drain (m114).  LDS 12KB, acc[2][4] (~80 VGPR).
__global__ __launch_bounds__(256, 2) void gemm_red_kernel(
    const u16* __restrict__ A, const u16* __restrict__ Bt,
    u16* __restrict__ out16,
    const float* __restrict__ pg, const float* __restrict__ pb,
    const float* __restrict__ pm, const float* __restrict__ pv)
{
  __shared__ u16 As[64 * 32];
  __shared__ u16 Bs[128 * 32];
  const int tid = threadIdx.x;
  const int wave = tid >> 6, lane = tid & 63;
  const int gx = gridDim.x;              // 4 (n-blocks)
  const int nwg = gx * gridDim.y;        // 1024
  int lin = blockIdx.y * gx + blockIdx.x;
  lin = (lin & 7) * (nwg >> 3) + (lin >> 3);
  const int m0 = (lin / gx) * 64, n0 = (lin % gx) * 128;

  const int e = wave * 512 + lane * 8;   // 0..2047
  const u16* gA0 = A + (size_t)(m0 + (e >> 5)) * CIN + (e & 31);
  const u16* gB0 = Bt + (size_t)(n0 + (e >> 5)) * CIN + (e & 31);
  const u16* gB1 = Bt + (size_t)(n0 + ((e + 2048) >> 5)) * CIN + (e & 31);
  u16* lA0 = &As[wave * 512];
  u16* lB0 = &Bs[wave * 512];
  u16* lB1 = &Bs[wave * 512 + 2048];

  f32x4 acc[2][4];
#pragma unroll
  for (int i = 0; i < 2; ++i)
#pragma unroll
    for (int j = 0; j < 4; ++j) acc[i][j] = f32x4{0.f, 0.f, 0.f, 0.f};

  const int wr = wave >> 1, wc = wave & 1;
  const int l15 = lane & 15, kb = (lane >> 4) * 8;

  for (int kt = 0; kt < CIN; kt += 32) {
    gload_lds16(gA0, lA0);
    gload_lds16(gB0, lB0); gload_lds16(gB1, lB1);
    gA0 += 32; gB0 += 32; gB1 += 32;
    __syncthreads();
    bf16x8 af[2], bfr[4];
#pragma unroll
    for (int f = 0; f < 2; ++f)
      af[f] = *(const bf16x8*)&As[(wr * 32 + f * 16 + l15) * 32 + kb];
#pragma unroll
    for (int f = 0; f < 4; ++f)
      bfr[f] = *(const bf16x8*)&Bs[(wc * 64 + f * 16 + l15) * 32 + kb];
#pragma unroll
    for (int fm = 0; fm < 2; ++fm)
#pragma unroll
      for (int fn = 0; fn < 4; ++fn)
        acc[fm][fn] = __builtin_amdgcn_mfma_f32_16x16x32_bf16(
            af[fm], bfr[fn], acc[fm][fn], 0, 0, 0);
    __syncthreads();
  }

  const int rowb = m0 + wr * 32 + (lane >> 4) * 4;
#pragma unroll
  for (int fn = 0; fn < 4; ++fn) {
    const int col = n0 + wc * 64 + fn * 16 + l15;
    const float sc = pg[col] * rsqrtf(pv[col] + EPSB);
    const float off = pb[col] - pm[col] * sc;
#pragma unroll
    for (int fm = 0; fm < 2; ++fm) {
      const int row = rowb + fm * 16;
#pragma unroll
      for (int r = 0; r < 4; ++r) {
        const float y = fmaxf(acc[fm][fn][r] * sc + off, 0.f);
        out16[(size_t)(row + r) * CRED + col] = f2b(y);
      }
    }
  }
}

// ------------- 64x64 transpose fp32 -> bf16 --------------------------------
__global__ __launch_bounds__(256) void trcvt_kernel(
    const float* __restrict__ src, u16* __restrict__ dst,
    int srs, int drs, long szs, long dzs)
{
  __shared__ float tile[64][65];
  const int t = threadIdx.x;
  const int tr = t >> 4, tc = (t & 15) * 4;
  const long sbase = (long)blockIdx.z * szs +
                     (long)(blockIdx.y * 64) * srs + blockIdx.x * 64;
#pragma unroll
  for (int i = 0; i < 4; ++i) {
    const int r = i * 16 + tr;
    const float4 v = *(const float4*)&src[sbase + (long)r * srs + tc];
    tile[r][tc]     = v.x;
    tile[r][tc + 1] = v.y;
    tile[r][tc + 2] = v.z;
    tile[r][tc + 3] = v.w;
  }
  __syncthreads();
  const long dbase = (long)blockIdx.z * dzs +
                     (long)(blockIdx.x * 64) * drs + blockIdx.y * 64;
#pragma unroll
  for (int i = 0; i < 4; ++i) {
    const int c = i * 16 + tr;
    u16x4 o;
#pragma unroll
    for (int q = 0; q < 4; ++q) o[q] = f2b(tile[tc + q][c]);
    *(u16x4*)&dst[dbase + (long)c * drs + tc] = o;
  }
}

// --------------------- elementwise fp32 -> bf16 convert --------------------
__global__ __launch_bounds__(256) void cvt_kernel(
    const float* __restrict__ src, u16* __restrict__ dst)
{
  const int i = (blockIdx.x * 256 + threadIdx.x) * 8;
  const float4 a = *(const float4*)&src[i];
  const float4 b = *(const float4*)&src[i + 4];
  u16x8 o;
  o[0] = f2b(a.x); o[1] = f2b(a.y); o[2] = f2b(a.z); o[3] = f2b(a.w);
  o[4] = f2b(b.x); o[5] = f2b(b.y); o[6] = f2b(b.z); o[7] = f2b(b.w);
  *(u16x8*)&dst[i] = o;
}

// ------------------- 128x128 MFMA GEMM (restore, MODE 3) -------------------
__global__ __launch_bounds__(256, 2) void gemm_res_kernel(
    const u16* __restrict__ A, const u16* __restrict__ Bt,
    float* __restrict__ out32,
    const float* __restrict__ pg, const float* __restrict__ pb,
    const float* __restrict__ pm, const float* __restrict__ pv,
    const float* __restrict__ auxf)
{
  const int K = CRED;
  const int gx = gridDim.x;
  const int nwg = gx * gridDim.y;
  int lin = blockIdx.y * gx + blockIdx.x;
  lin = (lin & 7) * (nwg >> 3) + (lin >> 3);
  const int m0 = (lin / gx) * 128, n0 = (lin % gx) * 128;

  __shared__ u16 As[128 * 32];
  __shared__ u16 Bs[128 * 32];
  const int tid = threadIdx.x;
  const int wave = tid >> 6, lane = tid & 63;

  const int eA0 = wave * 512 + lane * 8;
  const int eA1 = eA0 + 2048;
  const u16* gA0 = A + (size_t)(m0 + (eA0 >> 5)) * K + (eA0 & 31);
  const u16* gA1 = A + (size_t)(m0 + (eA1 >> 5)) * K + (eA1 & 31);
  const u16* gB0 = Bt + (size_t)(n0 + (eA0 >> 5)) * K + (eA0 & 31);
  const u16* gB1 = Bt + (size_t)(n0 + (eA1 >> 5)) * K + (eA1 & 31);
  u16* lA0 = &As[wave * 512];
  u16* lA1 = &As[wave * 512 + 2048];
  u16* lB0 = &Bs[wave * 512];
  u16* lB1 = &Bs[wave * 512 + 2048];

  f32x4 acc[4][4];
#pragma unroll
  for (int i = 0; i < 4; ++i)
#pragma unroll
    for (int j = 0; j < 4; ++j) acc[i][j] = f32x4{0.f, 0.f, 0.f, 0.f};

  const int wr = wave >> 1, wc = wave & 1;
  const int l15 = lane & 15, kb = (lane >> 4) * 8;

  for (int kt = 0; kt < K; kt += 32) {
    gload_lds16(gA0, lA0); gload_lds16(gA1, lA1);
    gload_lds16(gB0, lB0); gload_lds16(gB1, lB1);
    gA0 += 32; gA1 += 32; gB0 += 32; gB1 += 32;
    __syncthreads();
    bf16x8 af[4], bfr[4];
#pragma unroll
    for (int f = 0; f < 4; ++f) {
      af[f]  = *(const bf16x8*)&As[(wr * 64 + f * 16 + l15) * 32 + kb];
      bfr[f] = *(const bf16x8*)&Bs[(wc * 64 + f * 16 + l15) * 32 + kb];
    }
#pragma unroll
    for (int fm = 0; fm < 4; ++fm)
#pragma unroll
      for (int fn = 0; fn < 4; ++fn)
        acc[fm][fn] = __builtin_amdgcn_mfma_f32_16x16x32_bf16(
            af[fm], bfr[fn], acc[fm][fn], 0, 0, 0);
    __syncthreads();
  }

  const int rowb = m0 + wr * 64 + (lane >> 4) * 4;
#pragma unroll
  for (int fn = 0; fn < 4; ++fn) {
    const int col = n0 + wc * 64 + fn * 16 + l15;
    const float sc = pg[col] * rsqrtf(pv[col] + EPSB);
    const float off = pb[col] - pm[col] * sc;
#pragma unroll
    for (int fm = 0; fm < 4; ++fm) {
      const int row = rowb + fm * 16;
      const int bimg = row >> 8, p0 = row & 255;
      const size_t oa = (size_t)bimg * (COUT * NPIX) + (size_t)col * NPIX + p0;
      const float4 rv = *(const float4*)&auxf[oa];
      float4 ov;
      ov.x = fmaxf(acc[fm][fn][0] * sc + off + rv.x, 0.f);
      ov.y = fmaxf(acc[fm][fn][1] * sc + off + rv.y, 0.f);
      ov.z = fmaxf(acc[fm][fn][2] * sc + off + rv.z, 0.f);
      ov.w = fmaxf(acc[fm][fn][3] * sc + off + rv.w, 0.f);
      *(float4*)&out32[oa] = ov;
    }
  }
}

// ---------- P[s][h][c] = sum_t w_gat[c][h*512+t] * att_s[h][t] (fp32) ------
__global__ __launch_bounds__(256) void attproj_kernel(
    const float* __restrict__ w_gat, const float* __restrict__ att_src,
    const float* __restrict__ att_dst, float* __restrict__ P)
{
  __shared__ float av[CRED];
  const int sh = blockIdx.x;
  const int s = sh >> 3, h = sh & 7;
  const float* att = (s == 0) ? att_src : att_dst;
  for (int t = threadIdx.x; t < CRED; t += 256) av[t] = att[h * CRED + t];
  __syncthreads();
#pragma unroll
  for (int half = 0; half < 2; ++half) {
    const int c = threadIdx.x + half * 256;
    const float* wrow = w_gat + (size_t)c * KGAT + h * CRED;
    float acc = 0.f;
    for (int j = 0; j < CRED; j += 4) {
      const float4 w = *(const float4*)&wrow[j];
      acc += w.x * av[j] + w.y * av[j + 1] + w.z * av[j + 2] + w.w * av[j + 3];
    }
    P[(size_t)sh * CRED + c] = acc;
  }
}

// ---------- a_all[s][n][h] = xr[n] . P[s][h]   (one wave per node) ---------
__global__ __launch_bounds__(256) void att_kernel(
    const u16* __restrict__ xr, const float* __restrict__ P,
    float* __restrict__ a_all)
{
  const int wave = threadIdx.x >> 6, lane = threadIdx.x & 63;
  const int m = blockIdx.x * 4 + wave;
  const int sh = lane & 15, q = lane >> 4;
  const u16* xp = xr + (size_t)m * CRED + q * 128;
  const float* Pp = P + (size_t)sh * CRED + q * 128;
  float s = 0.f;
#pragma unroll
  for (int c = 0; c < 128; c += 8) {
    u16x8 xv = *(const u16x8*)&xp[c];
#pragma unroll
    for (int t = 0; t < 8; ++t) s += b2f(xv[t]) * Pp[c + t];
  }
  s += __shfl_xor(s, 16);
  s += __shfl_xor(s, 32);
  if (q == 0)
    a_all[(size_t)(sh >> 3) * MTOT * HEADS + (size_t)m * HEADS + (sh & 7)] = s;
}

// ---- per node: softmax alphas (8 heads x 5 edges) in LDS, then
//      gat[n][j] = bias[j] + sum_e sum_h (alpha[e][h]/8) * Y[v_e][h*512+j] ---
__global__ __launch_bounds__(256) void agg2_kernel(
    const u16* __restrict__ Y, const float* __restrict__ a_all,
    const float* __restrict__ gat_bias, u16* __restrict__ gat)
{
  int bid = blockIdx.x;
  bid = (bid & 7) * (MTOT >> 3) + (bid >> 3);
  const int u = bid & 255, b = bid >> 8;
  const int gi = u >> 4, gj = u & 15;
  const size_t nb = (size_t)b * NPIX;
  const int t = threadIdx.x;

  const int v0 = u;
  const int v1 = (gi > 0)  ? u - 16 : -1;
  const int v2 = (gi < 15) ? u + 16 : -1;
  const int v3 = (gj > 0)  ? u - 1  : -1;
  const int v4 = (gj < 15) ? u + 1  : -1;
  const int vs[5] = { v0, v1, v2, v3, v4 };

  __shared__ float alf[5][8];
  if (t < 8) {
    const int h = t;
    const float* a_src = a_all;
    const float* a_dst = a_all + (size_t)MTOT * HEADS;
    const float adst = a_dst[(nb + u) * HEADS + h];
    float l[5];
    float mx = -1e30f;
#pragma unroll
    for (int e = 0; e < 5; ++e) {
      if (vs[e] >= 0) {
        const float xx = a_src[(nb + vs[e]) * HEADS + h] + adst;
        l[e] = xx > 0.f ? xx : 0.2f * xx;
        mx = fmaxf(mx, l[e]);
      } else {
        l[e] = -1e30f;
      }
    }
    float s = 0.f, ee[5];
#pragma unroll
    for (int e = 0; e < 5; ++e) {
      ee[e] = (vs[e] >= 0) ? __expf(l[e] - mx) : 0.f;
      s += ee[e];
    }
    const float inv = 0.125f / s;
#pragma unroll
    for (int e = 0; e < 5; ++e) alf[e][h] = ee[e] * inv;
  }
  __syncthreads();

  const int j0 = t * 2;
  float o0 = gat_bias[j0], o1 = gat_bias[j0 + 1];
#pragma unroll
  for (int e = 0; e < 5; ++e) {
    const int vv = vs[e];
    if (vv < 0) continue;
    const u16* yp = Y + (nb + vv) * (size_t)KGAT + j0;
#pragma unroll
    for (int h = 0; h < HEADS; ++h) {
      const float a = alf[e][h];
      const unsigned w = *(const unsigned*)(yp + h * CRED);
      o0 += a * b2f((u16)(w & 0xffffu));
      o1 += a * b2f((u16)(w >> 16));
    }
  }
  const unsigned ow = ((unsigned)f2b(o1) << 16) | (unsigned)f2b(o0);
  *(unsigned*)&gat[(nb + u) * (size_t)CRED + j0] = ow;
}

// ---------------------------------------------------------------------------
extern "C" void kernel_launch(void* const* d_in, const int* in_sizes, int n_in,
                              void* d_out, int out_size, void* d_ws, size_t ws_size,
                              hipStream_t stream)
{
  const float* x         = (const float*)d_in[0];
  const float* w_reduce  = (const float*)d_in[1];
  const float* g_red     = (const float*)d_in[2];
  const float* b_red     = (const float*)d_in[3];
  const float* m_red     = (const float*)d_in[4];
  const float* v_red     = (const float*)d_in[5];
  const float* w_gat     = (const float*)d_in[6];
  const float* att_src   = (const float*)d_in[7];
  const float* att_dst   = (const float*)d_in[8];
  const float* gat_bias  = (const float*)d_in[9];
  const float* w_restore = (const float*)d_in[10];
  const float* g_res     = (const float*)d_in[11];
  const float* b_res     = (const float*)d_in[12];
  const float* m_res     = (const float*)d_in[13];
  const float* v_res     = (const float*)d_in[14];

  constexpr size_t SZ_Y    = (size_t)MTOT * KGAT * 2;
  constexpr size_t SZ_XR   = (size_t)MTOT * CRED * 2;
  constexpr size_t SZ_GAT  = SZ_XR;
  constexpr size_t SZ_WGT  = (size_t)KGAT * CRED * 2;
  constexpr size_t SZ_WRD  = (size_t)CRED * CIN * 2;
  constexpr size_t SZ_WRS  = (size_t)COUT * CRED * 2;
  constexpr size_t SZ_P    = (size_t)16 * CRED * 4;
  char* ws = (char*)d_ws;
  u16*   Y      = (u16*)ws;
  u16*   xt     = (u16*)ws;  // alias of Y (xt dead before Y written)
  u16*   xr     = (u16*)(ws + SZ_Y);
  u16*   gat    = (u16*)(ws + SZ_Y + SZ_XR);
  u16*   WgT2   = (u16*)(ws + SZ_Y + SZ_XR + SZ_GAT);
  u16*   wred_b = (u16*)(ws + SZ_Y + SZ_XR + SZ_GAT + SZ_WGT);
  u16*   wres_b = (u16*)(ws + SZ_Y + SZ_XR + SZ_GAT + SZ_WGT + SZ_WRD);
  float* P      = (float*)(ws + SZ_Y + SZ_XR + SZ_GAT + SZ_WGT + SZ_WRD + SZ_WRS);
  float* a_all  = (float*)(ws + SZ_Y + SZ_XR + SZ_GAT + SZ_WGT + SZ_WRD + SZ_WRS + SZ_P);
  float* outp   = (float*)d_out;

  hipFuncSetAttribute((const void*)gemm8p_kernel,
                      hipFuncAttributeMaxDynamicSharedMemorySize, 131072);

  trcvt_kernel<<<dim3(4, 16, 64), 256, 0, stream>>>(
      x, xt, NPIX, CIN, (long)CIN * NPIX, (long)CIN * NPIX);
  trcvt_kernel<<<dim3(64, 8, 1), 256, 0, stream>>>(
      w_gat, WgT2, KGAT, CRED, 0, 0);
  cvt_kernel<<<(CRED * CIN) / 2048, 256, 0, stream>>>(w_reduce, wred_b);
  cvt_kernel<<<(COUT * CRED) / 2048, 256, 0, stream>>>(w_restore, wres_b);
  gemm_red_kernel<<<dim3(4, 256), 256, 0, stream>>>(
      xt, wred_b, xr, g_red, b_red, m_red, v_red);
  attproj_kernel<<<16, 256, 0, stream>>>(w_gat, att_src, att_dst, P);
  att_kernel<<<MTOT / 4, 256, 0, stream>>>(xr, P, a_all);
  gemm8p_kernel<<<dim3(16, 64), 512, 131072, stream>>>(xr, WgT2, Y);
  agg2_kernel<<<MTOT, 256, 0, stream>>>(Y, a_all, gat_bias, gat);
  gemm_res_kernel<<<dim3(8, 128), 256, 0, stream>>>(
      gat, wres_b, outp, g_res, b_res, m_res, v_res, x);
  (void)in_sizes; (void)n_in; (void)out_size; (void)ws_size;
}

// Round 12
// 311.361 us; speedup vs baseline: 2.7413x; 1.0375x over previous
//
#include <hip/hip_runtime.h>

// ---------------------------------------------------------------------------
// GATBottleneck (ALL I/O fp32; compute bf16 MFMA, fp32 accum)
//
//  1. trcvt: WgT2 bf16 [4096][512]; WgT2[hj][c] = w_gat[c][hj]
//  2. cvt  : w_reduce, w_restore fp32 -> bf16 (already B^T layout)
//  3. gemm_redf: xr = relu(bn(x_nchw @ w_reduce^T))  [16384][512] bf16
//              FUSED transpose+convert: A staged straight from NCHW fp32 x
//              (8 coalesced dword cols/wave -> pack bf16 -> swizzled
//              ds_write_b128).  R6 XOR swizzle on BOTH operands.
//  4. attproj: P[s][h][c] = sum_t w_gat[c][h*512+t]*att_s[h][t]   (fp32)
//  5. att    : a_s[n][h] = xr[n] . P[s][h]                        (fp32)
//  6. gemm8p : Y = xr @ WgT2^T   [16384][4096] bf16  (R6-verified: 256x256,
//              BK=32, 8 waves, 4-deep LDS (128KB), one barrier + counted
//              vmcnt(4) per K-tile, conflict-free swizzle, setprio)
//  7. agg2   : per node: head-softmax alphas over {self + 4 nbrs},
//              gat[n][j] = bias[j] + sum_e sum_h (alpha/8) Y[v_e][h*512+j]
//  8. gemm_res: out = relu(bn(gat @ w_restore^T) + x)   -> fp32 NCHW
// edge_index is the fixed 4-neighbor grid + self loops -> analytic.
// R10 lesson: 256^2 8-wave kernel is 1 block/CU by register arithmetic
// (acc alone = 128 regs); forcing 2 blocks spills catastrophically.
// ---------------------------------------------------------------------------

typedef unsigned short u16;
typedef __attribute__((ext_vector_type(4))) unsigned short u16x4;
typedef __attribute__((ext_vector_type(8))) unsigned short u16x8;
typedef __attribute__((ext_vector_type(8))) __bf16 bf16x8;
typedef __attribute__((ext_vector_type(4))) float f32x4;

#define B_    64
#define CIN   1024
#define CRED  512
#define COUT  1024
#define NPIX  256
#define HEADS 8
#define KGAT  4096
#define MTOT  16384
#define EPSB  1e-5f

__device__ __forceinline__ float b2f(u16 u) {
  union { unsigned u; float f; } c; c.u = ((unsigned)u) << 16; return c.f;
}
__device__ __forceinline__ u16 f2b(float f) {
  union { float f; unsigned u; } c; c.f = f;
  unsigned r = (c.u + 0x7FFFu + ((c.u >> 16) & 1u)) >> 16;
  return (u16)r;
}

__device__ __forceinline__ void gload_lds16(const void* g, void* lds) {
  __builtin_amdgcn_global_load_lds(
      (const __attribute__((address_space(1))) void*)g,
      (__attribute__((address_space(3))) void*)lds, 16, 0, 0);
}

// ================= 256x256 pipelined GEMM: Y = A @ Bt^T (R6 exact) =========
__global__ __launch_bounds__(512, 1) void gemm8p_kernel(
    const u16* __restrict__ A, const u16* __restrict__ Bt,
    u16* __restrict__ out)
{
  extern __shared__ u16 lds[];
  const int tid = threadIdx.x;
  const int wave = tid >> 6, lane = tid & 63;
  const int wm = wave >> 2, wn = wave & 3;
  const int l15 = lane & 15, l4 = lane >> 4;

  int lin = blockIdx.y * 16 + blockIdx.x;
  lin = (lin & 7) * 128 + (lin >> 3);
  const int m0 = (lin >> 4) * 256;
  const int n0 = (lin & 15) * 256;

  int offS[2], ldsS[2];
#pragma unroll
  for (int i = 0; i < 2; ++i) {
    const int f = i * 512 + tid;
    const int r = f >> 2;
    const int kb = (f & 3) ^ ((r >> 1) & 3);
    offS[i] = r * 512 + kb * 8;
    ldsS[i] = (i * 512 + wave * 64) * 8;
  }
  const u16* gA = A + (size_t)m0 * 512;
  const u16* gB = Bt + (size_t)n0 * 512;

  auto stageA = [&](int kt) {
    const int bo = (kt & 3) * 16384;
    gload_lds16(gA + kt * 32 + offS[0], &lds[bo + ldsS[0]]);
    gload_lds16(gA + kt * 32 + offS[1], &lds[bo + ldsS[1]]);
  };
  auto stageB = [&](int kt) {
    const int bo = (kt & 3) * 16384 + 8192;
    gload_lds16(gB + kt * 32 + offS[0], &lds[bo + ldsS[0]]);
    gload_lds16(gB + kt * 32 + offS[1], &lds[bo + ldsS[1]]);
  };

  f32x4 acc[8][4];
#pragma unroll
  for (int i = 0; i < 8; ++i)
#pragma unroll
    for (int j = 0; j < 4; ++j) acc[i][j] = f32x4{0.f, 0.f, 0.f, 0.f};

  const int kq = (l4 ^ ((l15 >> 1) & 3)) * 8;
  const int aBase = (wm * 128 + l15) * 32 + kq;
  const int bBase = 8192 + (wn * 64 + l15) * 32 + kq;

  stageA(0); stageB(0); stageA(1); stageB(1);

  for (int kt = 0; kt < 16; ++kt) {
    if (kt == 15) { asm volatile("s_waitcnt vmcnt(0)" ::: "memory"); }
    else         { asm volatile("s_waitcnt vmcnt(4)" ::: "memory"); }
    __builtin_amdgcn_s_barrier();
    const int bo = (kt & 3) * 16384;
    bf16x8 bfr[4], af0[4], af1[4];
#pragma unroll
    for (int f = 0; f < 4; ++f)
      bfr[f] = *(const bf16x8*)&lds[bo + bBase + f * 512];
#pragma unroll
    for (int f = 0; f < 4; ++f)
      af0[f] = *(const bf16x8*)&lds[bo + aBase + f * 512];
#pragma unroll
    for (int f = 0; f < 4; ++f)
      af1[f] = *(const bf16x8*)&lds[bo + aBase + (f + 4) * 512];
    if (kt < 14) { stageA(kt + 2); stageB(kt + 2); }
    __builtin_amdgcn_s_setprio(1);
#pragma unroll
    for (int fm = 0; fm < 4; ++fm)
#pragma unroll
      for (int fn = 0; fn < 4; ++fn)
        acc[fm][fn] = __builtin_amdgcn_mfma_f32_16x16x32_bf16(
            af0[fm], bfr[fn], acc[fm][fn], 0, 0, 0);
#pragma unroll
    for (int fm = 0; fm < 4; ++fm)
#pragma unroll
      for (int fn = 0; fn < 4; ++fn)
        acc[fm + 4][fn] = __builtin_amdgcn_mfma_f32_16x16x32_bf16(
            af1[fm], bfr[fn], acc[fm + 4][fn], 0, 0, 0);
    __builtin_amdgcn_s_setprio(0);
  }

  const int rowb = m0 + wm * 128 + l4 * 4;
  const int colb = n0 + wn * 64 + l15;
#pragma unroll
  for (int fm = 0; fm < 8; ++fm)
#pragma unroll
    for (int fn = 0; fn < 4; ++fn)
#pragma unroll
      for (int r = 0; r < 4; ++r)
        out[(size_t)(rowb + fm * 16 + r) * KGAT + colb + fn * 16] =
            f2b(acc[fm][fn][r]);
}

// ====== 64x128 FUSED reduce GEMM: xr = relu(bn(x_nchw @ w_reduce^T)) =======
// A staged from NCHW fp32 x directly: wave w loads 8 coalesced dword
// columns (k = kt+w*8+j, rows = 64 consecutive pixels), packs to bf16,
// ONE swizzled ds_write_b128.  B via gload_lds with pre-swizzled source.
// Both frag reads use the R6 kq swizzle -> conflict-free.
__global__ __launch_bounds__(256, 2) void gemm_redf_kernel(
    const float* __restrict__ x, const u16* __restrict__ Bt,
    u16* __restrict__ out16,
    const float* __restrict__ pg, const float* __restrict__ pb,
    const float* __restrict__ pm, const float* __restrict__ pv)
{
  __shared__ u16 As[64 * 32];
  __shared__ u16 Bs[128 * 32];
  const int tid = threadIdx.x;
  const int wave = tid >> 6, lane = tid & 63;
  const int gx = gridDim.x;              // 4 n-blocks
  const int nwg = gx * gridDim.y;        // 1024
  int lin = blockIdx.y * gx + blockIdx.x;
  lin = (lin & 7) * (nwg >> 3) + (lin >> 3);
  const int m0 = (lin / gx) * 64, n0 = (lin % gx) * 128;
  const int bimg = m0 >> 8, p0 = m0 & 255;   // 64 | 256 -> single image

  // A source: x[bimg][k][p0 + lane], k = kt + wave*8 + j
  const float* xsrc = x + (size_t)bimg * CIN * NPIX + p0 + lane;

  // B staging (R6 pre-swizzled global source, linear LDS dest):
  int offB[2], dstB[2];
#pragma unroll
  for (int i = 0; i < 2; ++i) {
    const int f = i * 256 + tid;         // chunk 0..511
    const int r = f >> 2;                // B row 0..127
    const int kb = (f & 3) ^ ((r >> 1) & 3);
    offB[i] = r * CIN + kb * 8;
    dstB[i] = (i * 256 + wave * 64) * 8;
  }
  const u16* gB = Bt + (size_t)n0 * CIN;

  // A ds_write chunk swizzle: chunk c = wave ^ ((row>>1)&3), row = lane
  const int aWr = (lane * 4 + (wave ^ ((lane >> 1) & 3))) * 8;

  f32x4 acc[2][4];
#pragma unroll
  for (int i = 0; i < 2; ++i)
#pragma unroll
    for (int j = 0; j < 4; ++j) acc[i][j] = f32x4{0.f, 0.f, 0.f, 0.f};

  const int wr = wave >> 1, wc = wave & 1;
  const int l15 = lane & 15, l4 = lane >> 4;
  const int kq = (l4 ^ ((l15 >> 1) & 3)) * 8;

  // prologue: A regs for kt=0
  float av[8];
#pragma unroll
  for (int j = 0; j < 8; ++j) av[j] = xsrc[(wave * 8 + j) * NPIX];

  for (int kt = 0; kt < CIN; kt += 32) {
    u16x8 pv;
#pragma unroll
    for (int j = 0; j < 8; ++j) pv[j] = f2b(av[j]);
    *(u16x8*)&As[aWr] = pv;
    gload_lds16(gB + kt + offB[0], &Bs[dstB[0]]);
    gload_lds16(gB + kt + offB[1], &Bs[dstB[1]]);
    __syncthreads();
    if (kt + 32 < CIN) {
#pragma unroll
      for (int j = 0; j < 8; ++j)
        av[j] = xsrc[(kt + 32 + wave * 8 + j) * NPIX];
    }
    bf16x8 af[2], bfr[4];
#pragma unroll
    for (int f = 0; f < 2; ++f)
      af[f] = *(const bf16x8*)&As[(wr * 32 + f * 16 + l15) * 32 + kq];
#pragma unroll
    for (int f = 0; f < 4; ++f)
      bfr[f] = *(const bf16x8*)&Bs[(wc * 64 + f * 16 + l15) * 32 + kq];
#pragma unroll
    for (int fm = 0; fm < 2; ++fm)
#pragma unroll
      for (int fn = 0; fn < 4; ++fn)
        acc[fm][fn] = __builtin_amdgcn_mfma_f32_16x16x32_bf16(
            af[fm], bfr[fn], acc[fm][fn], 0, 0, 0);
    __syncthreads();
  }

  const int rowb = m0 + wr * 32 + (lane >> 4) * 4;
#pragma unroll
  for (int fn = 0; fn < 4; ++fn) {
    const int col = n0 + wc * 64 + fn * 16 + l15;
    const float sc = pg[col] * rsqrtf(pv[col] + EPSB);
    const float off = pb[col] - pm[col] * sc;
#pragma unroll
    for (int fm = 0; fm < 2; ++fm) {
      const int row = rowb + fm * 16;
#pragma unroll
      for (int r = 0; r < 4; ++r) {
        const float y = fmaxf(acc[fm][fn][r] * sc + off, 0.f);
        out16[(size_t)(row + r) * CRED + col] = f2b(y);
      }
    }
  }
}

// ------------- 64x64 transpose fp32 -> bf16 (w_gat only now) ---------------
__global__ __launch_bounds__(256) void trcvt_kernel(
    const float* __restrict__ src, u16* __restrict__ dst,
    int srs, int drs, long szs, long dzs)
{
  __shared__ float tile[64][65];
  const int t = threadIdx.x;
  const int tr = t >> 4, tc = (t & 15) * 4;
  const long sbase = (long)blockIdx.z * szs +
                     (long)(blockIdx.y * 64) * srs + blockIdx.x * 64;
#pragma unroll
  for (int i = 0; i < 4; ++i) {
    const int r = i * 16 + tr;
    const float4 v = *(const float4*)&src[sbase + (long)r * srs + tc];
    tile[r][tc]     = v.x;
    tile[r][tc + 1] = v.y;
    tile[r][tc + 2] = v.z;
    tile[r][tc + 3] = v.w;
  }
  __syncthreads();
  const long dbase = (long)blockIdx.z * dzs +
                     (long)(blockIdx.x * 64) * drs + blockIdx.y * 64;
#pragma unroll
  for (int i = 0; i < 4; ++i) {
    const int c = i * 16 + tr;
    u16x4 o;
#pragma unroll
    for (int q = 0; q < 4; ++q) o[q] = f2b(tile[tc + q][c]);
    *(u16x4*)&dst[dbase + (long)c * drs + tc] = o;
  }
}

// --------------------- elementwise fp32 -> bf16 convert --------------------
__global__ __launch_bounds__(256) void cvt_kernel(
    const float* __restrict__ src, u16* __restrict__ dst)
{
  const int i = (blockIdx.x * 256 + threadIdx.x) * 8;
  const float4 a = *(const float4*)&src[i];
  const float4 b = *(const float4*)&src[i + 4];
  u16x8 o;
  o[0] = f2b(a.x); o[1] = f2b(a.y); o[2] = f2b(a.z); o[3] = f2b(a.w);
  o[4] = f2b(b.x); o[5] = f2b(b.y); o[6] = f2b(b.z); o[7] = f2b(b.w);
  *(u16x8*)&dst[i] = o;
}

// ------------------- 128x128 MFMA GEMM (restore, MODE 3) -------------------
__global__ __launch_bounds__(256, 2) void gemm_res_kernel(
    const u16* __restrict__ A, const u16* __restrict__ Bt,
    float* __restrict__ out32,
    const float* __restrict__ pg, const float* __restrict__ pb,
    const float* __restrict__ pm, const float* __restrict__ pv,
    const float* __restrict__ auxf)
{
  const int K = CRED;
  const int gx = gridDim.x;
  const int nwg = gx * gridDim.y;
  int lin = blockIdx.y * gx + blockIdx.x;
  lin = (lin & 7) * (nwg >> 3) + (lin >> 3);
  const int m0 = (lin / gx) * 128, n0 = (lin % gx) * 128;

  __shared__ u16 As[128 * 32];
  __shared__ u16 Bs[128 * 32];
  const int tid = threadIdx.x;
  const int wave = tid >> 6, lane = tid & 63;

  const int eA0 = wave * 512 + lane * 8;
  const int eA1 = eA0 + 2048;
  const u16* gA0 = A + (size_t)(m0 + (eA0 >> 5)) * K + (eA0 & 31);
  const u16* gA1 = A + (size_t)(m0 + (eA1 >> 5)) * K + (eA1 & 31);
  const u16* gB0 = Bt + (size_t)(n0 + (eA0 >> 5)) * K + (eA0 & 31);
  const u16* gB1 = Bt + (size_t)(n0 + (eA1 >> 5)) * K + (eA1 & 31);
  u16* lA0 = &As[wave * 512];
  u16* lA1 = &As[wave * 512 + 2048];
  u16* lB0 = &Bs[wave * 512];
  u16* lB1 = &Bs[wave * 512 + 2048];

  f32x4 acc[4][4];
#pragma unroll
  for (int i = 0; i < 4; ++i)
#pragma unroll
    for (int j = 0; j < 4; ++j) acc[i][j] = f32x4{0.f, 0.f, 0.f, 0.f};

  const int wr = wave >> 1, wc = wave & 1;
  const int l15 = lane & 15, kb = (lane >> 4) * 8;

  for (int kt = 0; kt < K; kt += 32) {
    gload_lds16(gA0, lA0); gload_lds16(gA1, lA1);
    gload_lds16(gB0, lB0); gload_lds16(gB1, lB1);
    gA0 += 32; gA1 += 32; gB0 += 32; gB1 += 32;
    __syncthreads();
    bf16x8 af[4], bfr[4];
#pragma unroll
    for (int f = 0; f < 4; ++f) {
      af[f]  = *(const bf16x8*)&As[(wr * 64 + f * 16 + l15) * 32 + kb];
      bfr[f] = *(const bf16x8*)&Bs[(wc * 64 + f * 16 + l15) * 32 + kb];
    }
#pragma unroll
    for (int fm = 0; fm < 4; ++fm)
#pragma unroll
      for (int fn = 0; fn < 4; ++fn)
        acc[fm][fn] = __builtin_amdgcn_mfma_f32_16x16x32_bf16(
            af[fm], bfr[fn], acc[fm][fn], 0, 0, 0);
    __syncthreads();
  }

  const int rowb = m0 + wr * 64 + (lane >> 4) * 4;
#pragma unroll
  for (int fn = 0; fn < 4; ++fn) {
    const int col = n0 + wc * 64 + fn * 16 + l15;
    const float sc = pg[col] * rsqrtf(pv[col] + EPSB);
    const float off = pb[col] - pm[col] * sc;
#pragma unroll
    for (int fm = 0; fm < 4; ++fm) {
      const int row = rowb + fm * 16;
      const int bimg = row >> 8, p0 = row & 255;
      const size_t oa = (size_t)bimg * (COUT * NPIX) + (size_t)col * NPIX + p0;
      const float4 rv = *(const float4*)&auxf[oa];
      float4 ov;
      ov.x = fmaxf(acc[fm][fn][0] * sc + off + rv.x, 0.f);
      ov.y = fmaxf(acc[fm][fn][1] * sc + off + rv.y, 0.f);
      ov.z = fmaxf(acc[fm][fn][2] * sc + off + rv.z, 0.f);
      ov.w = fmaxf(acc[fm][fn][3] * sc + off + rv.w, 0.f);
      *(float4*)&out32[oa] = ov;
    }
  }
}

// ---------- P[s][h][c] = sum_t w_gat[c][h*512+t] * att_s[h][t] (fp32) ------
__global__ __launch_bounds__(256) void attproj_kernel(
    const float* __restrict__ w_gat, const float* __restrict__ att_src,
    const float* __restrict__ att_dst, float* __restrict__ P)
{
  __shared__ float av[CRED];
  const int sh = blockIdx.x;
  const int s = sh >> 3, h = sh & 7;
  const float* att = (s == 0) ? att_src : att_dst;
  for (int t = threadIdx.x; t < CRED; t += 256) av[t] = att[h * CRED + t];
  __syncthreads();
#pragma unroll
  for (int half = 0; half < 2; ++half) {
    const int c = threadIdx.x + half * 256;
    const float* wrow = w_gat + (size_t)c * KGAT + h * CRED;
    float acc = 0.f;
    for (int j = 0; j < CRED; j += 4) {
      const float4 w = *(const float4*)&wrow[j];
      acc += w.x * av[j] + w.y * av[j + 1] + w.z * av[j + 2] + w.w * av[j + 3];
    }
    P[(size_t)sh * CRED + c] = acc;
  }
}

// ---------- a_all[s][n][h] = xr[n] . P[s][h]   (one wave per node) ---------
__global__ __launch_bounds__(256) void att_kernel(
    const u16* __restrict__ xr, const float* __restrict__ P,
    float* __restrict__ a_all)
{
  const int wave = threadIdx.x >> 6, lane = threadIdx.x & 63;
  const int m = blockIdx.x * 4 + wave;
  const int sh = lane & 15, q = lane >> 4;
  const u16* xp = xr + (size_t)m * CRED + q * 128;
  const float* Pp = P + (size_t)sh * CRED + q * 128;
  float s = 0.f;
#pragma unroll
  for (int c = 0; c < 128; c += 8) {
    u16x8 xv = *(const u16x8*)&xp[c];
#pragma unroll
    for (int t = 0; t < 8; ++t) s += b2f(xv[t]) * Pp[c + t];
  }
  s += __shfl_xor(s, 16);
  s += __shfl_xor(s, 32);
  if (q == 0)
    a_all[(size_t)(sh >> 3) * MTOT * HEADS + (size_t)m * HEADS + (sh & 7)] = s;
}

// ---- per node: softmax alphas (8 heads x 5 edges) in LDS, then
//      gat[n][j] = bias[j] + sum_e sum_h (alpha[e][h]/8) * Y[v_e][h*512+j] ---
__global__ __launch_bounds__(256) void agg2_kernel(
    const u16* __restrict__ Y, const float* __restrict__ a_all,
    const float* __restrict__ gat_bias, u16* __restrict__ gat)
{
  int bid = blockIdx.x;
  bid = (bid & 7) * (MTOT >> 3) + (bid >> 3);
  const int u = bid & 255, b = bid >> 8;
  const int gi = u >> 4, gj = u & 15;
  const size_t nb = (size_t)b * NPIX;
  const int t = threadIdx.x;

  const int v0 = u;
  const int v1 = (gi > 0)  ? u - 16 : -1;
  const int v2 = (gi < 15) ? u + 16 : -1;
  const int v3 = (gj > 0)  ? u - 1  : -1;
  const int v4 = (gj < 15) ? u + 1  : -1;
  const int vs[5] = { v0, v1, v2, v3, v4 };

  __shared__ float alf[5][8];
  if (t < 8) {
    const int h = t;
    const float* a_src = a_all;
    const float* a_dst = a_all + (size_t)MTOT * HEADS;
    const float adst = a_dst[(nb + u) * HEADS + h];
    float l[5];
    float mx = -1e30f;
#pragma unroll
    for (int e = 0; e < 5; ++e) {
      if (vs[e] >= 0) {
        const float xx = a_src[(nb + vs[e]) * HEADS + h] + adst;
        l[e] = xx > 0.f ? xx : 0.2f * xx;
        mx = fmaxf(mx, l[e]);
      } else {
        l[e] = -1e30f;
      }
    }
    float s = 0.f, ee[5];
#pragma unroll
    for (int e = 0; e < 5; ++e) {
      ee[e] = (vs[e] >= 0) ? __expf(l[e] - mx) : 0.f;
      s += ee[e];
    }
    const float inv = 0.125f / s;
#pragma unroll
    for (int e = 0; e < 5; ++e) alf[e][h] = ee[e] * inv;
  }
  __syncthreads();

  const int j0 = t * 2;
  float o0 = gat_bias[j0], o1 = gat_bias[j0 + 1];
#pragma unroll
  for (int e = 0; e < 5; ++e) {
    const int vv = vs[e];
    if (vv < 0) continue;
    const u16* yp = Y + (nb + vv) * (size_t)KGAT + j0;
#pragma unroll
    for (int h = 0; h < HEADS; ++h) {
      const float a = alf[e][h];
      const unsigned w = *(const unsigned*)(yp + h * CRED);
      o0 += a * b2f((u16)(w & 0xffffu));
      o1 += a * b2f((u16)(w >> 16));
    }
  }
  const unsigned ow = ((unsigned)f2b(o1) << 16) | (unsigned)f2b(o0);
  *(unsigned*)&gat[(nb + u) * (size_t)CRED + j0] = ow;
}

// ---------------------------------------------------------------------------
extern "C" void kernel_launch(void* const* d_in, const int* in_sizes, int n_in,
                              void* d_out, int out_size, void* d_ws, size_t ws_size,
                              hipStream_t stream)
{
  const float* x         = (const float*)d_in[0];
  const float* w_reduce  = (const float*)d_in[1];
  const float* g_red     = (const float*)d_in[2];
  const float* b_red     = (const float*)d_in[3];
  const float* m_red     = (const float*)d_in[4];
  const float* v_red     = (const float*)d_in[5];
  const float* w_gat     = (const float*)d_in[6];
  const float* att_src   = (const float*)d_in[7];
  const float* att_dst   = (const float*)d_in[8];
  const float* gat_bias  = (const float*)d_in[9];
  const float* w_restore = (const float*)d_in[10];
  const float* g_res     = (const float*)d_in[11];
  const float* b_res     = (const float*)d_in[12];
  const float* m_res     = (const float*)d_in[13];
  const float* v_res     = (const float*)d_in[14];

  constexpr size_t SZ_Y    = (size_t)MTOT * KGAT * 2;
  constexpr size_t SZ_XR   = (size_t)MTOT * CRED * 2;
  constexpr size_t SZ_GAT  = SZ_XR;
  constexpr size_t SZ_WGT  = (size_t)KGAT * CRED * 2;
  constexpr size_t SZ_WRD  = (size_t)CRED * CIN * 2;
  constexpr size_t SZ_WRS  = (size_t)COUT * CRED * 2;
  constexpr size_t SZ_P    = (size_t)16 * CRED * 4;
  char* ws = (char*)d_ws;
  u16*   Y      = (u16*)ws;
  u16*   xr     = (u16*)(ws + SZ_Y);
  u16*   gat    = (u16*)(ws + SZ_Y + SZ_XR);
  u16*   WgT2   = (u16*)(ws + SZ_Y + SZ_XR + SZ_GAT);
  u16*   wred_b = (u16*)(ws + SZ_Y + SZ_XR + SZ_GAT + SZ_WGT);
  u16*   wres_b = (u16*)(ws + SZ_Y + SZ_XR + SZ_GAT + SZ_WGT + SZ_WRD);
  float* P      = (float*)(ws + SZ_Y + SZ_XR + SZ_GAT + SZ_WGT + SZ_WRD + SZ_WRS);
  float* a_all  = (float*)(ws + SZ_Y + SZ_XR + SZ_GAT + SZ_WGT + SZ_WRD + SZ_WRS + SZ_P);
  float* outp   = (float*)d_out;

  hipFuncSetAttribute((const void*)gemm8p_kernel,
                      hipFuncAttributeMaxDynamicSharedMemorySize, 131072);

  trcvt_kernel<<<dim3(64, 8, 1), 256, 0, stream>>>(
      w_gat, WgT2, KGAT, CRED, 0, 0);
  cvt_kernel<<<(CRED * CIN) / 2048, 256, 0, stream>>>(w_reduce, wred_b);
  cvt_kernel<<<(COUT * CRED) / 2048, 256, 0, stream>>>(w_restore, wres_b);
  gemm_redf_kernel<<<dim3(4, 256), 256, 0, stream>>>(
      x, wred_b, xr, g_red, b_red, m_red, v_red);
  attproj_kernel<<<16, 256, 0, stream>>>(w_gat, att_src, att_dst, P);
  att_kernel<<<MTOT / 4, 256, 0, stream>>>(xr, P, a_all);
  gemm8p_kernel<<<dim3(16, 64), 512, 131072, stream>>>(xr, WgT2, Y);
  agg2_kernel<<<MTOT, 256, 0, stream>>>(Y, a_all, gat_bias, gat);
  gemm_res_kernel<<<dim3(8, 128), 256, 0, stream>>>(
      gat, wres_b, outp, g_res, b_res, m_res, v_res, x);
  (void)in_sizes; (void)n_in; (void)out_size; (void)ws_size;
}

// Round 13
// 310.165 us; speedup vs baseline: 2.7519x; 1.0039x over previous
//
#include <hip/hip_runtime.h>

// ---------------------------------------------------------------------------
// GATBottleneck (ALL I/O fp32; compute bf16 MFMA, fp32 accum)
//
//  1. trcvt: WgT2 bf16 [4096][512]; WgT2[hj][c] = w_gat[c][hj]
//  2. cvt  : w_reduce, w_restore fp32 -> bf16 (already B^T layout)
//  3. gemm_redf: xr = relu(bn(x_nchw @ w_reduce^T))  [16384][512] bf16
//              (fused NCHW transpose+convert in A-staging; both-side swizzle)
//  4. attproj: P[s][h][c] = sum_t w_gat[c][h*512+t]*att_s[h][t]  (64 blocks)
//  5. att    : a_s[n][h] = xr[n] . P[s][h]                        (fp32)
//  6. gemm8p : Y = xr @ WgT2^T   [16384][4096] bf16  (R6-verified config)
//  7. agg4   : 4 nodes/block; head-softmax alphas; gat row via u16x8 loads
//  8. gemm_res: out = relu(bn(gat @ w_restore^T) + x) -> fp32 NCHW
//              (NOW with R6 both-sides swizzle -> 0 LDS conflicts)
// edge_index is the fixed 4-neighbor grid + self loops -> analytic.
// ---------------------------------------------------------------------------

typedef unsigned short u16;
typedef __attribute__((ext_vector_type(4))) unsigned short u16x4;
typedef __attribute__((ext_vector_type(8))) unsigned short u16x8;
typedef __attribute__((ext_vector_type(8))) __bf16 bf16x8;
typedef __attribute__((ext_vector_type(4))) float f32x4;

#define B_    64
#define CIN   1024
#define CRED  512
#define COUT  1024
#define NPIX  256
#define HEADS 8
#define KGAT  4096
#define MTOT  16384
#define EPSB  1e-5f

__device__ __forceinline__ float b2f(u16 u) {
  union { unsigned u; float f; } c; c.u = ((unsigned)u) << 16; return c.f;
}
__device__ __forceinline__ u16 f2b(float f) {
  union { float f; unsigned u; } c; c.f = f;
  unsigned r = (c.u + 0x7FFFu + ((c.u >> 16) & 1u)) >> 16;
  return (u16)r;
}

__device__ __forceinline__ void gload_lds16(const void* g, void* lds) {
  __builtin_amdgcn_global_load_lds(
      (const __attribute__((address_space(1))) void*)g,
      (__attribute__((address_space(3))) void*)lds, 16, 0, 0);
}

// ================= 256x256 pipelined GEMM: Y = A @ Bt^T (R6 exact) =========
__global__ __launch_bounds__(512, 1) void gemm8p_kernel(
    const u16* __restrict__ A, const u16* __restrict__ Bt,
    u16* __restrict__ out)
{
  extern __shared__ u16 lds[];
  const int tid = threadIdx.x;
  const int wave = tid >> 6, lane = tid & 63;
  const int wm = wave >> 2, wn = wave & 3;
  const int l15 = lane & 15, l4 = lane >> 4;

  int lin = blockIdx.y * 16 + blockIdx.x;
  lin = (lin & 7) * 128 + (lin >> 3);
  const int m0 = (lin >> 4) * 256;
  const int n0 = (lin & 15) * 256;

  int offS[2], ldsS[2];
#pragma unroll
  for (int i = 0; i < 2; ++i) {
    const int f = i * 512 + tid;
    const int r = f >> 2;
    const int kb = (f & 3) ^ ((r >> 1) & 3);
    offS[i] = r * 512 + kb * 8;
    ldsS[i] = (i * 512 + wave * 64) * 8;
  }
  const u16* gA = A + (size_t)m0 * 512;
  const u16* gB = Bt + (size_t)n0 * 512;

  auto stageA = [&](int kt) {
    const int bo = (kt & 3) * 16384;
    gload_lds16(gA + kt * 32 + offS[0], &lds[bo + ldsS[0]]);
    gload_lds16(gA + kt * 32 + offS[1], &lds[bo + ldsS[1]]);
  };
  auto stageB = [&](int kt) {
    const int bo = (kt & 3) * 16384 + 8192;
    gload_lds16(gB + kt * 32 + offS[0], &lds[bo + ldsS[0]]);
    gload_lds16(gB + kt * 32 + offS[1], &lds[bo + ldsS[1]]);
  };

  f32x4 acc[8][4];
#pragma unroll
  for (int i = 0; i < 8; ++i)
#pragma unroll
    for (int j = 0; j < 4; ++j) acc[i][j] = f32x4{0.f, 0.f, 0.f, 0.f};

  const int kq = (l4 ^ ((l15 >> 1) & 3)) * 8;
  const int aBase = (wm * 128 + l15) * 32 + kq;
  const int bBase = 8192 + (wn * 64 + l15) * 32 + kq;

  stageA(0); stageB(0); stageA(1); stageB(1);

  for (int kt = 0; kt < 16; ++kt) {
    if (kt == 15) { asm volatile("s_waitcnt vmcnt(0)" ::: "memory"); }
    else         { asm volatile("s_waitcnt vmcnt(4)" ::: "memory"); }
    __builtin_amdgcn_s_barrier();
    const int bo = (kt & 3) * 16384;
    bf16x8 bfr[4], af0[4], af1[4];
#pragma unroll
    for (int f = 0; f < 4; ++f)
      bfr[f] = *(const bf16x8*)&lds[bo + bBase + f * 512];
#pragma unroll
    for (int f = 0; f < 4; ++f)
      af0[f] = *(const bf16x8*)&lds[bo + aBase + f * 512];
#pragma unroll
    for (int f = 0; f < 4; ++f)
      af1[f] = *(const bf16x8*)&lds[bo + aBase + (f + 4) * 512];
    if (kt < 14) { stageA(kt + 2); stageB(kt + 2); }
    __builtin_amdgcn_s_setprio(1);
#pragma unroll
    for (int fm = 0; fm < 4; ++fm)
#pragma unroll
      for (int fn = 0; fn < 4; ++fn)
        acc[fm][fn] = __builtin_amdgcn_mfma_f32_16x16x32_bf16(
            af0[fm], bfr[fn], acc[fm][fn], 0, 0, 0);
#pragma unroll
    for (int fm = 0; fm < 4; ++fm)
#pragma unroll
      for (int fn = 0; fn < 4; ++fn)
        acc[fm + 4][fn] = __builtin_amdgcn_mfma_f32_16x16x32_bf16(
            af1[fm], bfr[fn], acc[fm + 4][fn], 0, 0, 0);
    __builtin_amdgcn_s_setprio(0);
  }

  const int rowb = m0 + wm * 128 + l4 * 4;
  const int colb = n0 + wn * 64 + l15;
#pragma unroll
  for (int fm = 0; fm < 8; ++fm)
#pragma unroll
    for (int fn = 0; fn < 4; ++fn)
#pragma unroll
      for (int r = 0; r < 4; ++r)
        out[(size_t)(rowb + fm * 16 + r) * KGAT + colb + fn * 16] =
            f2b(acc[fm][fn][r]);
}

// ====== 64x128 FUSED reduce GEMM: xr = relu(bn(x_nchw @ w_reduce^T)) =======
__global__ __launch_bounds__(256, 2) void gemm_redf_kernel(
    const float* __restrict__ x, const u16* __restrict__ Bt,
    u16* __restrict__ out16,
    const float* __restrict__ pg, const float* __restrict__ pb,
    const float* __restrict__ pm, const float* __restrict__ pv)
{
  __shared__ u16 As[64 * 32];
  __shared__ u16 Bs[128 * 32];
  const int tid = threadIdx.x;
  const int wave = tid >> 6, lane = tid & 63;
  const int gx = gridDim.x;
  const int nwg = gx * gridDim.y;
  int lin = blockIdx.y * gx + blockIdx.x;
  lin = (lin & 7) * (nwg >> 3) + (lin >> 3);
  const int m0 = (lin / gx) * 64, n0 = (lin % gx) * 128;
  const int bimg = m0 >> 8, p0 = m0 & 255;

  const float* xsrc = x + (size_t)bimg * CIN * NPIX + p0 + lane;

  int offB[2], dstB[2];
#pragma unroll
  for (int i = 0; i < 2; ++i) {
    const int f = i * 256 + tid;
    const int r = f >> 2;
    const int kb = (f & 3) ^ ((r >> 1) & 3);
    offB[i] = r * CIN + kb * 8;
    dstB[i] = (i * 256 + wave * 64) * 8;
  }
  const u16* gB = Bt + (size_t)n0 * CIN;

  const int aWr = (lane * 4 + (wave ^ ((lane >> 1) & 3))) * 8;

  f32x4 acc[2][4];
#pragma unroll
  for (int i = 0; i < 2; ++i)
#pragma unroll
    for (int j = 0; j < 4; ++j) acc[i][j] = f32x4{0.f, 0.f, 0.f, 0.f};

  const int wr = wave >> 1, wc = wave & 1;
  const int l15 = lane & 15, l4 = lane >> 4;
  const int kq = (l4 ^ ((l15 >> 1) & 3)) * 8;

  float av[8];
#pragma unroll
  for (int j = 0; j < 8; ++j) av[j] = xsrc[(wave * 8 + j) * NPIX];

  for (int kt = 0; kt < CIN; kt += 32) {
    u16x8 pvv;
#pragma unroll
    for (int j = 0; j < 8; ++j) pvv[j] = f2b(av[j]);
    *(u16x8*)&As[aWr] = pvv;
    gload_lds16(gB + kt + offB[0], &Bs[dstB[0]]);
    gload_lds16(gB + kt + offB[1], &Bs[dstB[1]]);
    __syncthreads();
    if (kt + 32 < CIN) {
#pragma unroll
      for (int j = 0; j < 8; ++j)
        av[j] = xsrc[(kt + 32 + wave * 8 + j) * NPIX];
    }
    bf16x8 af[2], bfr[4];
#pragma unroll
    for (int f = 0; f < 2; ++f)
      af[f] = *(const bf16x8*)&As[(wr * 32 + f * 16 + l15) * 32 + kq];
#pragma unroll
    for (int f = 0; f < 4; ++f)
      bfr[f] = *(const bf16x8*)&Bs[(wc * 64 + f * 16 + l15) * 32 + kq];
#pragma unroll
    for (int fm = 0; fm < 2; ++fm)
#pragma unroll
      for (int fn = 0; fn < 4; ++fn)
        acc[fm][fn] = __builtin_amdgcn_mfma_f32_16x16x32_bf16(
            af[fm], bfr[fn], acc[fm][fn], 0, 0, 0);
    __syncthreads();
  }

  const int rowb = m0 + wr * 32 + (lane >> 4) * 4;
#pragma unroll
  for (int fn = 0; fn < 4; ++fn) {
    const int col = n0 + wc * 64 + fn * 16 + l15;
    const float sc = pg[col] * rsqrtf(pv[col] + EPSB);
    const float off = pb[col] - pm[col] * sc;
#pragma unroll
    for (int fm = 0; fm < 2; ++fm) {
      const int row = rowb + fm * 16;
#pragma unroll
      for (int r = 0; r < 4; ++r) {
        const float y = fmaxf(acc[fm][fn][r] * sc + off, 0.f);
        out16[(size_t)(row + r) * CRED + col] = f2b(y);
      }
    }
  }
}

// ------------- 64x64 transpose fp32 -> bf16 (w_gat only) -------------------
__global__ __launch_bounds__(256) void trcvt_kernel(
    const float* __restrict__ src, u16* __restrict__ dst,
    int srs, int drs, long szs, long dzs)
{
  __shared__ float tile[64][65];
  const int t = threadIdx.x;
  const int tr = t >> 4, tc = (t & 15) * 4;
  const long sbase = (long)blockIdx.z * szs +
                     (long)(blockIdx.y * 64) * srs + blockIdx.x * 64;
#pragma unroll
  for (int i = 0; i < 4; ++i) {
    const int r = i * 16 + tr;
    const float4 v = *(const float4*)&src[sbase + (long)r * srs + tc];
    tile[r][tc]     = v.x;
    tile[r][tc + 1] = v.y;
    tile[r][tc + 2] = v.z;
    tile[r][tc + 3] = v.w;
  }
  __syncthreads();
  const long dbase = (long)blockIdx.z * dzs +
                     (long)(blockIdx.x * 64) * drs + blockIdx.y * 64;
#pragma unroll
  for (int i = 0; i < 4; ++i) {
    const int c = i * 16 + tr;
    u16x4 o;
#pragma unroll
    for (int q = 0; q < 4; ++q) o[q] = f2b(tile[tc + q][c]);
    *(u16x4*)&dst[dbase + (long)c * drs + tc] = o;
  }
}

// --------------------- elementwise fp32 -> bf16 convert --------------------
__global__ __launch_bounds__(256) void cvt_kernel(
    const float* __restrict__ src, u16* __restrict__ dst)
{
  const int i = (blockIdx.x * 256 + threadIdx.x) * 8;
  const float4 a = *(const float4*)&src[i];
  const float4 b = *(const float4*)&src[i + 4];
  u16x8 o;
  o[0] = f2b(a.x); o[1] = f2b(a.y); o[2] = f2b(a.z); o[3] = f2b(a.w);
  o[4] = f2b(b.x); o[5] = f2b(b.y); o[6] = f2b(b.z); o[7] = f2b(b.w);
  *(u16x8*)&dst[i] = o;
}

// ---- 128x128 restore GEMM, R6 both-sides swizzle: out = relu(bn+res) ------
__global__ __launch_bounds__(256, 2) void gemm_res_kernel(
    const u16* __restrict__ A, const u16* __restrict__ Bt,
    float* __restrict__ out32,
    const float* __restrict__ pg, const float* __restrict__ pb,
    const float* __restrict__ pm, const float* __restrict__ pv,
    const float* __restrict__ auxf)
{
  const int K = CRED;
  const int gx = gridDim.x;
  const int nwg = gx * gridDim.y;
  int lin = blockIdx.y * gx + blockIdx.x;
  lin = (lin & 7) * (nwg >> 3) + (lin >> 3);
  const int m0 = (lin / gx) * 128, n0 = (lin % gx) * 128;

  __shared__ u16 As[128 * 32];
  __shared__ u16 Bs[128 * 32];
  const int tid = threadIdx.x;
  const int wave = tid >> 6, lane = tid & 63;

  // 16B-chunk staging with pre-swizzled global source (both-sides rule)
  int offS[2], dstS[2];
#pragma unroll
  for (int i = 0; i < 2; ++i) {
    const int f = i * 256 + tid;         // chunk 0..511
    const int r = f >> 2;                // row 0..127
    const int kb = (f & 3) ^ ((r >> 1) & 3);
    offS[i] = r * K + kb * 8;
    dstS[i] = (i * 256 + wave * 64) * 8;
  }
  const u16* gA = A + (size_t)m0 * K;
  const u16* gB = Bt + (size_t)n0 * K;

  f32x4 acc[4][4];
#pragma unroll
  for (int i = 0; i < 4; ++i)
#pragma unroll
    for (int j = 0; j < 4; ++j) acc[i][j] = f32x4{0.f, 0.f, 0.f, 0.f};

  const int wr = wave >> 1, wc = wave & 1;
  const int l15 = lane & 15, l4 = lane >> 4;
  const int kq = (l4 ^ ((l15 >> 1) & 3)) * 8;

  for (int kt = 0; kt < K; kt += 32) {
    gload_lds16(gA + kt + offS[0], &As[dstS[0]]);
    gload_lds16(gA + kt + offS[1], &As[dstS[1]]);
    gload_lds16(gB + kt + offS[0], &Bs[dstS[0]]);
    gload_lds16(gB + kt + offS[1], &Bs[dstS[1]]);
    __syncthreads();
    bf16x8 af[4], bfr[4];
#pragma unroll
    for (int f = 0; f < 4; ++f) {
      af[f]  = *(const bf16x8*)&As[(wr * 64 + f * 16 + l15) * 32 + kq];
      bfr[f] = *(const bf16x8*)&Bs[(wc * 64 + f * 16 + l15) * 32 + kq];
    }
#pragma unroll
    for (int fm = 0; fm < 4; ++fm)
#pragma unroll
      for (int fn = 0; fn < 4; ++fn)
        acc[fm][fn] = __builtin_amdgcn_mfma_f32_16x16x32_bf16(
            af[fm], bfr[fn], acc[fm][fn], 0, 0, 0);
    __syncthreads();
  }

  const int rowb = m0 + wr * 64 + (lane >> 4) * 4;
#pragma unroll
  for (int fn = 0; fn < 4; ++fn) {
    const int col = n0 + wc * 64 + fn * 16 + l15;
    const float sc = pg[col] * rsqrtf(pv[col] + EPSB);
    const float off = pb[col] - pm[col] * sc;
#pragma unroll
    for (int fm = 0; fm < 4; ++fm) {
      const int row = rowb + fm * 16;
      const int bimg = row >> 8, p0 = row & 255;
      const size_t oa = (size_t)bimg * (COUT * NPIX) + (size_t)col * NPIX + p0;
      const float4 rv = *(const float4*)&auxf[oa];
      float4 ov;
      ov.x = fmaxf(acc[fm][fn][0] * sc + off + rv.x, 0.f);
      ov.y = fmaxf(acc[fm][fn][1] * sc + off + rv.y, 0.f);
      ov.z = fmaxf(acc[fm][fn][2] * sc + off + rv.z, 0.f);
      ov.w = fmaxf(acc[fm][fn][3] * sc + off + rv.w, 0.f);
      *(float4*)&out32[oa] = ov;
    }
  }
}

// ---------- P[s][h][c] = sum_t w_gat[c][h*512+t] * att_s[h][t] -------------
// 64 blocks = (sh 0..15) x (channel-quarter 0..3), 128 threads, 1 c/thread.
__global__ __launch_bounds__(128) void attproj_kernel(
    const float* __restrict__ w_gat, const float* __restrict__ att_src,
    const float* __restrict__ att_dst, float* __restrict__ P)
{
  __shared__ float av[CRED];
  const int bi = blockIdx.x;
  const int sh = bi & 15, q = bi >> 4;
  const int s = sh >> 3, h = sh & 7;
  const float* att = (s == 0) ? att_src : att_dst;
  for (int t = threadIdx.x; t < CRED; t += 128) av[t] = att[h * CRED + t];
  __syncthreads();
  const int c = q * 128 + threadIdx.x;
  const float* wrow = w_gat + (size_t)c * KGAT + h * CRED;
  float acc = 0.f;
  for (int j = 0; j < CRED; j += 4) {
    const float4 w = *(const float4*)&wrow[j];
    acc += w.x * av[j] + w.y * av[j + 1] + w.z * av[j + 2] + w.w * av[j + 3];
  }
  P[(size_t)sh * CRED + c] = acc;
}

// ---------- a_all[s][n][h] = xr[n] . P[s][h]   (one wave per node) ---------
__global__ __launch_bounds__(256) void att_kernel(
    const u16* __restrict__ xr, const float* __restrict__ P,
    float* __restrict__ a_all)
{
  const int wave = threadIdx.x >> 6, lane = threadIdx.x & 63;
  const int m = blockIdx.x * 4 + wave;
  const int sh = lane & 15, q = lane >> 4;
  const u16* xp = xr + (size_t)m * CRED + q * 128;
  const float* Pp = P + (size_t)sh * CRED + q * 128;
  float s = 0.f;
#pragma unroll
  for (int c = 0; c < 128; c += 8) {
    u16x8 xv = *(const u16x8*)&xp[c];
#pragma unroll
    for (int t = 0; t < 8; ++t) s += b2f(xv[t]) * Pp[c + t];
  }
  s += __shfl_xor(s, 16);
  s += __shfl_xor(s, 32);
  if (q == 0)
    a_all[(size_t)(sh >> 3) * MTOT * HEADS + (size_t)m * HEADS + (sh & 7)] = s;
}

// ---- 4 nodes/block: head softmax (32 threads) then per-group u16x8 gather -
// gat[n][j] = bias[j] + sum_e sum_h (alpha[e][h]/8) * Y[v_e][h*512+j]
__global__ __launch_bounds__(256) void agg4_kernel(
    const u16* __restrict__ Y, const float* __restrict__ a_all,
    const float* __restrict__ gat_bias, u16* __restrict__ gat)
{
  int bid = blockIdx.x;                      // 0..4095
  bid = (bid & 7) * 512 + (bid >> 3);        // XCD-chunked (bijective)
  const int n0g = bid * 4;
  const int b = n0g >> 8;
  const size_t nb = (size_t)b * NPIX;
  const int t = threadIdx.x;
  const int g = t >> 6, tg = t & 63;
  const int u = (n0g & 255) + g;             // 4 | 256 so stays in-image

  __shared__ float alf[4][5][8];
  if (t < 32) {
    const int nl = t >> 3, h = t & 7;
    const int un = (n0g & 255) + nl;
    const int gi = un >> 4, gj = un & 15;
    int vv[5];
    vv[0] = un;
    vv[1] = (gi > 0)  ? un - 16 : -1;
    vv[2] = (gi < 15) ? un + 16 : -1;
    vv[3] = (gj > 0)  ? un - 1  : -1;
    vv[4] = (gj < 15) ? un + 1  : -1;
    const float* a_src = a_all;
    const float* a_dst = a_all + (size_t)MTOT * HEADS;
    const float ad = a_dst[(nb + un) * HEADS + h];
    float l[5]; float mx = -1e30f;
#pragma unroll
    for (int e = 0; e < 5; ++e) {
      if (vv[e] >= 0) {
        const float xx = a_src[(nb + vv[e]) * HEADS + h] + ad;
        l[e] = xx > 0.f ? xx : 0.2f * xx;    // leaky_relu(0.2)
        mx = fmaxf(mx, l[e]);
      } else l[e] = -1e30f;
    }
    float s = 0.f, ee[5];
#pragma unroll
    for (int e = 0; e < 5; ++e) {
      ee[e] = (vv[e] >= 0) ? __expf(l[e] - mx) : 0.f;
      s += ee[e];
    }
    const float inv = 0.125f / s;            // head-mean folded
#pragma unroll
    for (int e = 0; e < 5; ++e) alf[nl][e][h] = ee[e] * inv;
  }
  __syncthreads();

  const int gi = u >> 4, gj = u & 15;
  int vv[5];
  vv[0] = u;
  vv[1] = (gi > 0)  ? u - 16 : u;            // invalid -> alpha==0, read self
  vv[2] = (gi < 15) ? u + 16 : u;
  vv[3] = (gj > 0)  ? u - 1  : u;
  vv[4] = (gj < 15) ? u + 1  : u;

  const int j0 = tg * 8;
  float o[8];
  {
    const float4 b0 = *(const float4*)&gat_bias[j0];
    const float4 b1 = *(const float4*)&gat_bias[j0 + 4];
    o[0] = b0.x; o[1] = b0.y; o[2] = b0.z; o[3] = b0.w;
    o[4] = b1.x; o[5] = b1.y; o[6] = b1.z; o[7] = b1.w;
  }
#pragma unroll
  for (int e = 0; e < 5; ++e) {
    const u16* yp = Y + (nb + vv[e]) * (size_t)KGAT + j0;
#pragma unroll
    for (int h = 0; h < HEADS; ++h) {
      const float a = alf[g][e][h];
      const u16x8 yv = *(const u16x8*)(yp + h * CRED);
#pragma unroll
      for (int q = 0; q < 8; ++q) o[q] += a * b2f(yv[q]);
    }
  }
  u16x8 ov;
#pragma unroll
  for (int q = 0; q < 8; ++q) ov[q] = f2b(o[q]);
  *(u16x8*)&gat[(nb + u) * (size_t)CRED + j0] = ov;
}

// ---------------------------------------------------------------------------
extern "C" void kernel_launch(void* const* d_in, const int* in_sizes, int n_in,
                              void* d_out, int out_size, void* d_ws, size_t ws_size,
                              hipStream_t stream)
{
  const float* x         = (const float*)d_in[0];
  const float* w_reduce  = (const float*)d_in[1];
  const float* g_red     = (const float*)d_in[2];
  const float* b_red     = (const float*)d_in[3];
  const float* m_red     = (const float*)d_in[4];
  const float* v_red     = (const float*)d_in[5];
  const float* w_gat     = (const float*)d_in[6];
  const float* att_src   = (const float*)d_in[7];
  const float* att_dst   = (const float*)d_in[8];
  const float* gat_bias  = (const float*)d_in[9];
  const float* w_restore = (const float*)d_in[10];
  const float* g_res     = (const float*)d_in[11];
  const float* b_res     = (const float*)d_in[12];
  const float* m_res     = (const float*)d_in[13];
  const float* v_res     = (const float*)d_in[14];

  constexpr size_t SZ_Y    = (size_t)MTOT * KGAT * 2;
  constexpr size_t SZ_XR   = (size_t)MTOT * CRED * 2;
  constexpr size_t SZ_GAT  = SZ_XR;
  constexpr size_t SZ_WGT  = (size_t)KGAT * CRED * 2;
  constexpr size_t SZ_WRD  = (size_t)CRED * CIN * 2;
  constexpr size_t SZ_WRS  = (size_t)COUT * CRED * 2;
  constexpr size_t SZ_P    = (size_t)16 * CRED * 4;
  char* ws = (char*)d_ws;
  u16*   Y      = (u16*)ws;
  u16*   xr     = (u16*)(ws + SZ_Y);
  u16*   gat    = (u16*)(ws + SZ_Y + SZ_XR);
  u16*   WgT2   = (u16*)(ws + SZ_Y + SZ_XR + SZ_GAT);
  u16*   wred_b = (u16*)(ws + SZ_Y + SZ_XR + SZ_GAT + SZ_WGT);
  u16*   wres_b = (u16*)(ws + SZ_Y + SZ_XR + SZ_GAT + SZ_WGT + SZ_WRD);
  float* P      = (float*)(ws + SZ_Y + SZ_XR + SZ_GAT + SZ_WGT + SZ_WRD + SZ_WRS);
  float* a_all  = (float*)(ws + SZ_Y + SZ_XR + SZ_GAT + SZ_WGT + SZ_WRD + SZ_WRS + SZ_P);
  float* outp   = (float*)d_out;

  hipFuncSetAttribute((const void*)gemm8p_kernel,
                      hipFuncAttributeMaxDynamicSharedMemorySize, 131072);

  trcvt_kernel<<<dim3(64, 8, 1), 256, 0, stream>>>(
      w_gat, WgT2, KGAT, CRED, 0, 0);
  cvt_kernel<<<(CRED * CIN) / 2048, 256, 0, stream>>>(w_reduce, wred_b);
  cvt_kernel<<<(COUT * CRED) / 2048, 256, 0, stream>>>(w_restore, wres_b);
  gemm_redf_kernel<<<dim3(4, 256), 256, 0, stream>>>(
      x, wred_b, xr, g_red, b_red, m_red, v_red);
  attproj_kernel<<<64, 128, 0, stream>>>(w_gat, att_src, att_dst, P);
  att_kernel<<<MTOT / 4, 256, 0, stream>>>(xr, P, a_all);
  gemm8p_kernel<<<dim3(16, 64), 512, 131072, stream>>>(xr, WgT2, Y);
  agg4_kernel<<<4096, 256, 0, stream>>>(Y, a_all, gat_bias, gat);
  gemm_res_kernel<<<dim3(8, 128), 256, 0, stream>>>(
      gat, wres_b, outp, g_res, b_res, m_res, v_res, x);
  (void)in_sizes; (void)n_in; (void)out_size; (void)ws_size;
}

// Round 14
// 299.885 us; speedup vs baseline: 2.8462x; 1.0343x over previous
//
#include <hip/hip_runtime.h>

// ---------------------------------------------------------------------------
// GATBottleneck (ALL I/O fp32; compute bf16 MFMA, fp32 accum)
//
//  1. trcvt: WgT2 bf16 [4096][512]; WgT2[hj][c] = w_gat[c][hj]
//  2. cvt  : w_reduce, w_restore fp32 -> bf16 (already B^T layout)
//  3. gemm_redf: xr = relu(bn(x_nchw @ w_reduce^T))  [16384][512] bf16
//  4. attproj/att: alpha logits via factored projections       (fp32)
//  5. gemm8p : Y = xr @ WgT2^T  [16384][4096] bf16 -- m201-style port:
//              256x256 tile, BK=64, 2 LDS buffers (128KB), 4 phases/K-tile
//              {reads | stage 2 units | bar | setprio 16xMFMA | bar},
//              ONE late vmcnt(0)+barrier per K-tile, 3-bit XOR swizzle.
//  6. agg4   : 4 nodes/block; head-softmax alphas; u16x8 Y gathers
//  7. gemm_res: out = relu(bn(gat @ w_restore^T) + x) -> fp32 NCHW
// edge_index is the fixed 4-neighbor grid + self loops -> analytic.
// ---------------------------------------------------------------------------

typedef unsigned short u16;
typedef __attribute__((ext_vector_type(4))) unsigned short u16x4;
typedef __attribute__((ext_vector_type(8))) unsigned short u16x8;
typedef __attribute__((ext_vector_type(8))) __bf16 bf16x8;
typedef __attribute__((ext_vector_type(4))) float f32x4;

#define B_    64
#define CIN   1024
#define CRED  512
#define COUT  1024
#define NPIX  256
#define HEADS 8
#define KGAT  4096
#define MTOT  16384
#define EPSB  1e-5f

__device__ __forceinline__ float b2f(u16 u) {
  union { unsigned u; float f; } c; c.u = ((unsigned)u) << 16; return c.f;
}
__device__ __forceinline__ u16 f2b(float f) {
  union { float f; unsigned u; } c; c.f = f;
  unsigned r = (c.u + 0x7FFFu + ((c.u >> 16) & 1u)) >> 16;
  return (u16)r;
}

__device__ __forceinline__ void gload_lds16(const void* g, void* lds) {
  __builtin_amdgcn_global_load_lds(
      (const __attribute__((address_space(1))) void*)g,
      (__attribute__((address_space(3))) void*)lds, 16, 0, 0);
}

// ========== 256x256 m201-style GEMM: Y = A @ Bt^T, BK=64, 2 buffers ========
// 8 waves (2M x 4N), wave tile 128x64.  K=512 -> 8 K-tiles of 64.
// LDS buffer d (64KB): A[256][64] @ d*32768, B[256][64] @ d*32768+16384 (u16).
// Stage units: 8 per K-tile (A quarters u0-3 = rows u*64..+63; B quarters
//   u4-7), each 64 rows x 8 chunks x 16B = 512 chunks = 1 gload/thread.
// Swizzle (both-sides): chunk (row,kb) stored at kb ^ (row&7); staging
//   pre-swizzles the GLOBAL k-chunk, LDS dest linear; frag reads XOR the
//   same -> 16 lanes x fixed l4 hit all 8 bank-quads exactly 2x (free).
// Phases per tile: 4 x { frag reads | stage 2 units of t+1 | s_barrier |
//   setprio(1) 16 MFMA setprio(0) | s_barrier }, then vmcnt(0)+barrier at
//   the tile boundary (issued AFTER all 4 MFMA clusters -> drain is
//   residual latency only, not a cold stall).
// Race ledger: stages of t+1 issue after the boundary barrier ending t-1
//   (whose reads of buf (t+1)&1 completed before it) -> no write/read race;
//   buf t&1 resident after boundary barrier (each wave's own vmcnt(0)
//   drained its unit loads before it; barrier publishes cross-wave).
__global__ __launch_bounds__(512, 1) void gemm8p_kernel(
    const u16* __restrict__ A, const u16* __restrict__ Bt,
    u16* __restrict__ out)
{
  extern __shared__ u16 lds[];
  const int tid = threadIdx.x;
  const int wave = tid >> 6, lane = tid & 63;
  const int wm = wave >> 2, wn = wave & 3;
  const int l15 = lane & 15, l4 = lane >> 4;

  // XCD-chunked swizzle over 1024 blocks (16 n-blocks x 64 m-blocks)
  int lin = blockIdx.y * 16 + blockIdx.x;
  lin = (lin & 7) * 128 + (lin >> 3);
  const int m0 = (lin >> 4) * 256;
  const int n0 = (lin & 15) * 256;

  const u16* gA = A + (size_t)m0 * 512;
  const u16* gB = Bt + (size_t)n0 * 512;

  // staging map: thread stages chunk f = tid of each unit:
  //   r_local = tid>>3 (0..63), kb' = tid&7, global kb = kb' ^ (r_local&7)
  const int rl = tid >> 3;
  const int kb = (tid & 7) ^ (rl & 7);
  const int gcol = kb * 8;                 // element offset within k-window
  const int ldsW = wave * 512;             // + lane*16B auto

  auto stageU = [&](int t1, int u) {
    const int d = (t1 & 1) * 32768;
    const int ko = t1 * 64;
    if (u < 4)
      gload_lds16(gA + (size_t)(u * 64 + rl) * 512 + ko + gcol,
                  &lds[d + u * 4096 + ldsW]);
    else
      gload_lds16(gB + (size_t)((u - 4) * 64 + rl) * 512 + ko + gcol,
                  &lds[d + 16384 + (u - 4) * 4096 + ldsW]);
  };

  f32x4 acc[8][4];
#pragma unroll
  for (int i = 0; i < 8; ++i)
#pragma unroll
    for (int j = 0; j < 4; ++j) acc[i][j] = f32x4{0.f, 0.f, 0.f, 0.f};

  // frag read bases (u16): row-major 64 u16/row within each operand
  const int swz = l15 & 7;
  const int aRow = (wm * 128 + l15) * 64;          // + fm*1024
  const int bRow = 16384 + (wn * 64 + l15) * 64;   // + fn*1024
  const int kq0 = (l4 ^ swz) * 8;                  // ks=0 chunk
  const int kq1 = ((4 + l4) ^ swz) * 8;            // ks=1 chunk

  // prologue: stage tile 0 -> buf 0
#pragma unroll
  for (int u = 0; u < 8; ++u) stageU(0, u);
  asm volatile("s_waitcnt vmcnt(0)" ::: "memory");
  __builtin_amdgcn_s_barrier();

  for (int t = 0; t < 8; ++t) {
    const int db = (t & 1) * 32768;
    bf16x8 bfr[4], af[4];
    // ---- phase 0: B ks0 + A fmh0 ks0 ----
#pragma unroll
    for (int fn = 0; fn < 4; ++fn)
      bfr[fn] = *(const bf16x8*)&lds[db + bRow + fn * 1024 + kq0];
#pragma unroll
    for (int f = 0; f < 4; ++f)
      af[f] = *(const bf16x8*)&lds[db + aRow + f * 1024 + kq0];
    if (t < 7) { stageU(t + 1, 0); stageU(t + 1, 1); }
    __builtin_amdgcn_s_barrier();
    __builtin_amdgcn_s_setprio(1);
#pragma unroll
    for (int fm = 0; fm < 4; ++fm)
#pragma unroll
      for (int fn = 0; fn < 4; ++fn)
        acc[fm][fn] = __builtin_amdgcn_mfma_f32_16x16x32_bf16(
            af[fm], bfr[fn], acc[fm][fn], 0, 0, 0);
    __builtin_amdgcn_s_setprio(0);
    __builtin_amdgcn_s_barrier();
    // ---- phase 1: A fmh1 ks0 ----
#pragma unroll
    for (int f = 0; f < 4; ++f)
      af[f] = *(const bf16x8*)&lds[db + aRow + (f + 4) * 1024 + kq0];
    if (t < 7) { stageU(t + 1, 2); stageU(t + 1, 3); }
    __builtin_amdgcn_s_barrier();
    __builtin_amdgcn_s_setprio(1);
#pragma unroll
    for (int fm = 0; fm < 4; ++fm)
#pragma unroll
      for (int fn = 0; fn < 4; ++fn)
        acc[fm + 4][fn] = __builtin_amdgcn_mfma_f32_16x16x32_bf16(
            af[fm], bfr[fn], acc[fm + 4][fn], 0, 0, 0);
    __builtin_amdgcn_s_setprio(0);
    __builtin_amdgcn_s_barrier();
    // ---- phase 2: B ks1 + A fmh0 ks1 ----
#pragma unroll
    for (int fn = 0; fn < 4; ++fn)
      bfr[fn] = *(const bf16x8*)&lds[db + bRow + fn * 1024 + kq1];
#pragma unroll
    for (int f = 0; f < 4; ++f)
      af[f] = *(const bf16x8*)&lds[db + aRow + f * 1024 + kq1];
    if (t < 7) { stageU(t + 1, 4); stageU(t + 1, 5); }
    __builtin_amdgcn_s_barrier();
    __builtin_amdgcn_s_setprio(1);
#pragma unroll
    for (int fm = 0; fm < 4; ++fm)
#pragma unroll
      for (int fn = 0; fn < 4; ++fn)
        acc[fm][fn] = __builtin_amdgcn_mfma_f32_16x16x32_bf16(
            af[fm], bfr[fn], acc[fm][fn], 0, 0, 0);
    __builtin_amdgcn_s_setprio(0);
    __builtin_amdgcn_s_barrier();
    // ---- phase 3: A fmh1 ks1 ----
#pragma unroll
    for (int f = 0; f < 4; ++f)
      af[f] = *(const bf16x8*)&lds[db + aRow + (f + 4) * 1024 + kq1];
    if (t < 7) { stageU(t + 1, 6); stageU(t + 1, 7); }
    __builtin_amdgcn_s_barrier();
    __builtin_amdgcn_s_setprio(1);
#pragma unroll
    for (int fm = 0; fm < 4; ++fm)
#pragma unroll
      for (int fn = 0; fn < 4; ++fn)
        acc[fm + 4][fn] = __builtin_amdgcn_mfma_f32_16x16x32_bf16(
            af[fm], bfr[fn], acc[fm + 4][fn], 0, 0, 0);
    __builtin_amdgcn_s_setprio(0);
    // ---- tile boundary: buf t+1 resident for all waves after this ----
    asm volatile("s_waitcnt vmcnt(0)" ::: "memory");
    __builtin_amdgcn_s_barrier();
  }

  // epilogue: row = m0 + wm*128 + fm*16 + l4*4 + r; col = n0 + wn*64 + fn*16 + l15
  const int rowb = m0 + wm * 128 + l4 * 4;
  const int colb = n0 + wn * 64 + l15;
#pragma unroll
  for (int fm = 0; fm < 8; ++fm)
#pragma unroll
    for (int fn = 0; fn < 4; ++fn)
#pragma unroll
      for (int r = 0; r < 4; ++r)
        out[(size_t)(rowb + fm * 16 + r) * KGAT + colb + fn * 16] =
            f2b(acc[fm][fn][r]);
}

// ====== 64x128 FUSED reduce GEMM: xr = relu(bn(x_nchw @ w_reduce^T)) =======
__global__ __launch_bounds__(256, 2) void gemm_redf_kernel(
    const float* __restrict__ x, const u16* __restrict__ Bt,
    u16* __restrict__ out16,
    const float* __restrict__ pg, const float* __restrict__ pb,
    const float* __restrict__ pm, const float* __restrict__ pv)
{
  __shared__ u16 As[64 * 32];
  __shared__ u16 Bs[128 * 32];
  const int tid = threadIdx.x;
  const int wave = tid >> 6, lane = tid & 63;
  const int gx = gridDim.x;
  const int nwg = gx * gridDim.y;
  int lin = blockIdx.y * gx + blockIdx.x;
  lin = (lin & 7) * (nwg >> 3) + (lin >> 3);
  const int m0 = (lin / gx) * 64, n0 = (lin % gx) * 128;
  const int bimg = m0 >> 8, p0 = m0 & 255;

  const float* xsrc = x + (size_t)bimg * CIN * NPIX + p0 + lane;

  int offB[2], dstB[2];
#pragma unroll
  for (int i = 0; i < 2; ++i) {
    const int f = i * 256 + tid;
    const int r = f >> 2;
    const int kb = (f & 3) ^ ((r >> 1) & 3);
    offB[i] = r * CIN + kb * 8;
    dstB[i] = (i * 256 + wave * 64) * 8;
  }
  const u16* gB = Bt + (size_t)n0 * CIN;

  const int aWr = (lane * 4 + (wave ^ ((lane >> 1) & 3))) * 8;

  f32x4 acc[2][4];
#pragma unroll
  for (int i = 0; i < 2; ++i)
#pragma unroll
    for (int j = 0; j < 4; ++j) acc[i][j] = f32x4{0.f, 0.f, 0.f, 0.f};

  const int wr = wave >> 1, wc = wave & 1;
  const int l15 = lane & 15, l4 = lane >> 4;
  const int kq = (l4 ^ ((l15 >> 1) & 3)) * 8;

  float av[8];
#pragma unroll
  for (int j = 0; j < 8; ++j) av[j] = xsrc[(wave * 8 + j) * NPIX];

  for (int kt = 0; kt < CIN; kt += 32) {
    u16x8 pvv;
#pragma unroll
    for (int j = 0; j < 8; ++j) pvv[j] = f2b(av[j]);
    *(u16x8*)&As[aWr] = pvv;
    gload_lds16(gB + kt + offB[0], &Bs[dstB[0]]);
    gload_lds16(gB + kt + offB[1], &Bs[dstB[1]]);
    __syncthreads();
    if (kt + 32 < CIN) {
#pragma unroll
      for (int j = 0; j < 8; ++j)
        av[j] = xsrc[(kt + 32 + wave * 8 + j) * NPIX];
    }
    bf16x8 af[2], bfr[4];
#pragma unroll
    for (int f = 0; f < 2; ++f)
      af[f] = *(const bf16x8*)&As[(wr * 32 + f * 16 + l15) * 32 + kq];
#pragma unroll
    for (int f = 0; f < 4; ++f)
      bfr[f] = *(const bf16x8*)&Bs[(wc * 64 + f * 16 + l15) * 32 + kq];
#pragma unroll
    for (int fm = 0; fm < 2; ++fm)
#pragma unroll
      for (int fn = 0; fn < 4; ++fn)
        acc[fm][fn] = __builtin_amdgcn_mfma_f32_16x16x32_bf16(
            af[fm], bfr[fn], acc[fm][fn], 0, 0, 0);
    __syncthreads();
  }

  const int rowb = m0 + wr * 32 + (lane >> 4) * 4;
#pragma unroll
  for (int fn = 0; fn < 4; ++fn) {
    const int col = n0 + wc * 64 + fn * 16 + l15;
    const float sc = pg[col] * rsqrtf(pv[col] + EPSB);
    const float off = pb[col] - pm[col] * sc;
#pragma unroll
    for (int fm = 0; fm < 2; ++fm) {
      const int row = rowb + fm * 16;
#pragma unroll
      for (int r = 0; r < 4; ++r) {
        const float y = fmaxf(acc[fm][fn][r] * sc + off, 0.f);
        out16[(size_t)(row + r) * CRED + col] = f2b(y);
      }
    }
  }
}

// ------------- 64x64 transpose fp32 -> bf16 (w_gat only) -------------------
__global__ __launch_bounds__(256) void trcvt_kernel(
    const float* __restrict__ src, u16* __restrict__ dst,
    int srs, int drs, long szs, long dzs)
{
  __shared__ float tile[64][65];
  const int t = threadIdx.x;
  const int tr = t >> 4, tc = (t & 15) * 4;
  const long sbase = (long)blockIdx.z * szs +
                     (long)(blockIdx.y * 64) * srs + blockIdx.x * 64;
#pragma unroll
  for (int i = 0; i < 4; ++i) {
    const int r = i * 16 + tr;
    const float4 v = *(const float4*)&src[sbase + (long)r * srs + tc];
    tile[r][tc]     = v.x;
    tile[r][tc + 1] = v.y;
    tile[r][tc + 2] = v.z;
    tile[r][tc + 3] = v.w;
  }
  __syncthreads();
  const long dbase = (long)blockIdx.z * dzs +
                     (long)(blockIdx.x * 64) * drs + blockIdx.y * 64;
#pragma unroll
  for (int i = 0; i < 4; ++i) {
    const int c = i * 16 + tr;
    u16x4 o;
#pragma unroll
    for (int q = 0; q < 4; ++q) o[q] = f2b(tile[tc + q][c]);
    *(u16x4*)&dst[dbase + (long)c * drs + tc] = o;
  }
}

// --------------------- elementwise fp32 -> bf16 convert --------------------
__global__ __launch_bounds__(256) void cvt_kernel(
    const float* __restrict__ src, u16* __restrict__ dst)
{
  const int i = (blockIdx.x * 256 + threadIdx.x) * 8;
  const float4 a = *(const float4*)&src[i];
  const float4 b = *(const float4*)&src[i + 4];
  u16x8 o;
  o[0] = f2b(a.x); o[1] = f2b(a.y); o[2] = f2b(a.z); o[3] = f2b(a.w);
  o[4] = f2b(b.x); o[5] = f2b(b.y); o[6] = f2b(b.z); o[7] = f2b(b.w);
  *(u16x8*)&dst[i] = o;
}

// ---- 128x128 restore GEMM, both-sides swizzle: out = relu(bn+res) ---------
__global__ __launch_bounds__(256, 2) void gemm_res_kernel(
    const u16* __restrict__ A, const u16* __restrict__ Bt,
    float* __restrict__ out32,
    const float* __restrict__ pg, const float* __restrict__ pb,
    const float* __restrict__ pm, const float* __restrict__ pv,
    const float* __restrict__ auxf)
{
  const int K = CRED;
  const int gx = gridDim.x;
  const int nwg = gx * gridDim.y;
  int lin = blockIdx.y * gx + blockIdx.x;
  lin = (lin & 7) * (nwg >> 3) + (lin >> 3);
  const int m0 = (lin / gx) * 128, n0 = (lin % gx) * 128;

  __shared__ u16 As[128 * 32];
  __shared__ u16 Bs[128 * 32];
  const int tid = threadIdx.x;
  const int wave = tid >> 6, lane = tid & 63;

  int offS[2], dstS[2];
#pragma unroll
  for (int i = 0; i < 2; ++i) {
    const int f = i * 256 + tid;
    const int r = f >> 2;
    const int kb = (f & 3) ^ ((r >> 1) & 3);
    offS[i] = r * K + kb * 8;
    dstS[i] = (i * 256 + wave * 64) * 8;
  }
  const u16* gA = A + (size_t)m0 * K;
  const u16* gB = Bt + (size_t)n0 * K;

  f32x4 acc[4][4];
#pragma unroll
  for (int i = 0; i < 4; ++i)
#pragma unroll
    for (int j = 0; j < 4; ++j) acc[i][j] = f32x4{0.f, 0.f, 0.f, 0.f};

  const int wr = wave >> 1, wc = wave & 1;
  const int l15 = lane & 15, l4 = lane >> 4;
  const int kq = (l4 ^ ((l15 >> 1) & 3)) * 8;

  for (int kt = 0; kt < K; kt += 32) {
    gload_lds16(gA + kt + offS[0], &As[dstS[0]]);
    gload_lds16(gA + kt + offS[1], &As[dstS[1]]);
    gload_lds16(gB + kt + offS[0], &Bs[dstS[0]]);
    gload_lds16(gB + kt + offS[1], &Bs[dstS[1]]);
    __syncthreads();
    bf16x8 af[4], bfr[4];
#pragma unroll
    for (int f = 0; f < 4; ++f) {
      af[f]  = *(const bf16x8*)&As[(wr * 64 + f * 16 + l15) * 32 + kq];
      bfr[f] = *(const bf16x8*)&Bs[(wc * 64 + f * 16 + l15) * 32 + kq];
    }
#pragma unroll
    for (int fm = 0; fm < 4; ++fm)
#pragma unroll
      for (int fn = 0; fn < 4; ++fn)
        acc[fm][fn] = __builtin_amdgcn_mfma_f32_16x16x32_bf16(
            af[fm], bfr[fn], acc[fm][fn], 0, 0, 0);
    __syncthreads();
  }

  const int rowb = m0 + wr * 64 + (lane >> 4) * 4;
#pragma unroll
  for (int fn = 0; fn < 4; ++fn) {
    const int col = n0 + wc * 64 + fn * 16 + l15;
    const float sc = pg[col] * rsqrtf(pv[col] + EPSB);
    const float off = pb[col] - pm[col] * sc;
#pragma unroll
    for (int fm = 0; fm < 4; ++fm) {
      const int row = rowb + fm * 16;
      const int bimg = row >> 8, p0 = row & 255;
      const size_t oa = (size_t)bimg * (COUT * NPIX) + (size_t)col * NPIX + p0;
      const float4 rv = *(const float4*)&auxf[oa];
      float4 ov;
      ov.x = fmaxf(acc[fm][fn][0] * sc + off + rv.x, 0.f);
      ov.y = fmaxf(acc[fm][fn][1] * sc + off + rv.y, 0.f);
      ov.z = fmaxf(acc[fm][fn][2] * sc + off + rv.z, 0.f);
      ov.w = fmaxf(acc[fm][fn][3] * sc + off + rv.w, 0.f);
      *(float4*)&out32[oa] = ov;
    }
  }
}

// ---------- P[s][h][c] = sum_t w_gat[c][h*512+t] * att_s[h][t] -------------
__global__ __launch_bounds__(128) void attproj_kernel(
    const float* __restrict__ w_gat, const float* __restrict__ att_src,
    const float* __restrict__ att_dst, float* __restrict__ P)
{
  __shared__ float av[CRED];
  const int bi = blockIdx.x;
  const int sh = bi & 15, q = bi >> 4;
  const int s = sh >> 3, h = sh & 7;
  const float* att = (s == 0) ? att_src : att_dst;
  for (int t = threadIdx.x; t < CRED; t += 128) av[t] = att[h * CRED + t];
  __syncthreads();
  const int c = q * 128 + threadIdx.x;
  const float* wrow = w_gat + (size_t)c * KGAT + h * CRED;
  float acc = 0.f;
  for (int j = 0; j < CRED; j += 4) {
    const float4 w = *(const float4*)&wrow[j];
    acc += w.x * av[j] + w.y * av[j + 1] + w.z * av[j + 2] + w.w * av[j + 3];
  }
  P[(size_t)sh * CRED + c] = acc;
}

// ---------- a_all[s][n][h] = xr[n] . P[s][h]   (one wave per node) ---------
__global__ __launch_bounds__(256) void att_kernel(
    const u16* __restrict__ xr, const float* __restrict__ P,
    float* __restrict__ a_all)
{
  const int wave = threadIdx.x >> 6, lane = threadIdx.x & 63;
  const int m = blockIdx.x * 4 + wave;
  const int sh = lane & 15, q = lane >> 4;
  const u16* xp = xr + (size_t)m * CRED + q * 128;
  const float* Pp = P + (size_t)sh * CRED + q * 128;
  float s = 0.f;
#pragma unroll
  for (int c = 0; c < 128; c += 8) {
    u16x8 xv = *(const u16x8*)&xp[c];
#pragma unroll
    for (int t = 0; t < 8; ++t) s += b2f(xv[t]) * Pp[c + t];
  }
  s += __shfl_xor(s, 16);
  s += __shfl_xor(s, 32);
  if (q == 0)
    a_all[(size_t)(sh >> 3) * MTOT * HEADS + (size_t)m * HEADS + (sh & 7)] = s;
}

// ---- 4 nodes/block: head softmax (32 threads) then per-group u16x8 gather -
__global__ __launch_bounds__(256) void agg4_kernel(
    const u16* __restrict__ Y, const float* __restrict__ a_all,
    const float* __restrict__ gat_bias, u16* __restrict__ gat)
{
  int bid = blockIdx.x;
  bid = (bid & 7) * 512 + (bid >> 3);
  const int n0g = bid * 4;
  const int b = n0g >> 8;
  const size_t nb = (size_t)b * NPIX;
  const int t = threadIdx.x;
  const int g = t >> 6, tg = t & 63;
  const int u = (n0g & 255) + g;

  __shared__ float alf[4][5][8];
  if (t < 32) {
    const int nl = t >> 3, h = t & 7;
    const int un = (n0g & 255) + nl;
    const int gi = un >> 4, gj = un & 15;
    int vv[5];
    vv[0] = un;
    vv[1] = (gi > 0)  ? un - 16 : -1;
    vv[2] = (gi < 15) ? un + 16 : -1;
    vv[3] = (gj > 0)  ? un - 1  : -1;
    vv[4] = (gj < 15) ? un + 1  : -1;
    const float* a_src = a_all;
    const float* a_dst = a_all + (size_t)MTOT * HEADS;
    const float ad = a_dst[(nb + un) * HEADS + h];
    float l[5]; float mx = -1e30f;
#pragma unroll
    for (int e = 0; e < 5; ++e) {
      if (vv[e] >= 0) {
        const float xx = a_src[(nb + vv[e]) * HEADS + h] + ad;
        l[e] = xx > 0.f ? xx : 0.2f * xx;
        mx = fmaxf(mx, l[e]);
      } else l[e] = -1e30f;
    }
    float s = 0.f, ee[5];
#pragma unroll
    for (int e = 0; e < 5; ++e) {
      ee[e] = (vv[e] >= 0) ? __expf(l[e] - mx) : 0.f;
      s += ee[e];
    }
    const float inv = 0.125f / s;
#pragma unroll
    for (int e = 0; e < 5; ++e) alf[nl][e][h] = ee[e] * inv;
  }
  __syncthreads();

  const int gi = u >> 4, gj = u & 15;
  int vv[5];
  vv[0] = u;
  vv[1] = (gi > 0)  ? u - 16 : u;
  vv[2] = (gi < 15) ? u + 16 : u;
  vv[3] = (gj > 0)  ? u - 1  : u;
  vv[4] = (gj < 15) ? u + 1  : u;

  const int j0 = tg * 8;
  float o[8];
  {
    const float4 b0 = *(const float4*)&gat_bias[j0];
    const float4 b1 = *(const float4*)&gat_bias[j0 + 4];
    o[0] = b0.x; o[1] = b0.y; o[2] = b0.z; o[3] = b0.w;
    o[4] = b1.x; o[5] = b1.y; o[6] = b1.z; o[7] = b1.w;
  }
#pragma unroll
  for (int e = 0; e < 5; ++e) {
    const u16* yp = Y + (nb + vv[e]) * (size_t)KGAT + j0;
#pragma unroll
    for (int h = 0; h < HEADS; ++h) {
      const float a = alf[g][e][h];
      const u16x8 yv = *(const u16x8*)(yp + h * CRED);
#pragma unroll
      for (int q = 0; q < 8; ++q) o[q] += a * b2f(yv[q]);
    }
  }
  u16x8 ov;
#pragma unroll
  for (int q = 0; q < 8; ++q) ov[q] = f2b(o[q]);
  *(u16x8*)&gat[(nb + u) * (size_t)CRED + j0] = ov;
}

// ---------------------------------------------------------------------------
extern "C" void kernel_launch(void* const* d_in, const int* in_sizes, int n_in,
                              void* d_out, int out_size, void* d_ws, size_t ws_size,
                              hipStream_t stream)
{
  const float* x         = (const float*)d_in[0];
  const float* w_reduce  = (const float*)d_in[1];
  const float* g_red     = (const float*)d_in[2];
  const float* b_red     = (const float*)d_in[3];
  const float* m_red     = (const float*)d_in[4];
  const float* v_red     = (const float*)d_in[5];
  const float* w_gat     = (const float*)d_in[6];
  const float* att_src   = (const float*)d_in[7];
  const float* att_dst   = (const float*)d_in[8];
  const float* gat_bias  = (const float*)d_in[9];
  const float* w_restore = (const float*)d_in[10];
  const float* g_res     = (const float*)d_in[11];
  const float* b_res     = (const float*)d_in[12];
  const float* m_res     = (const float*)d_in[13];
  const float* v_res     = (const float*)d_in[14];

  constexpr size_t SZ_Y    = (size_t)MTOT * KGAT * 2;
  constexpr size_t SZ_XR   = (size_t)MTOT * CRED * 2;
  constexpr size_t SZ_GAT  = SZ_XR;
  constexpr size_t SZ_WGT  = (size_t)KGAT * CRED * 2;
  constexpr size_t SZ_WRD  = (size_t)CRED * CIN * 2;
  constexpr size_t SZ_WRS  = (size_t)COUT * CRED * 2;
  constexpr size_t SZ_P    = (size_t)16 * CRED * 4;
  char* ws = (char*)d_ws;
  u16*   Y      = (u16*)ws;
  u16*   xr     = (u16*)(ws + SZ_Y);
  u16*   gat    = (u16*)(ws + SZ_Y + SZ_XR);
  u16*   WgT2   = (u16*)(ws + SZ_Y + SZ_XR + SZ_GAT);
  u16*   wred_b = (u16*)(ws + SZ_Y + SZ_XR + SZ_GAT + SZ_WGT);
  u16*   wres_b = (u16*)(ws + SZ_Y + SZ_XR + SZ_GAT + SZ_WGT + SZ_WRD);
  float* P      = (float*)(ws + SZ_Y + SZ_XR + SZ_GAT + SZ_WGT + SZ_WRD + SZ_WRS);
  float* a_all  = (float*)(ws + SZ_Y + SZ_XR + SZ_GAT + SZ_WGT + SZ_WRD + SZ_WRS + SZ_P);
  float* outp   = (float*)d_out;

  hipFuncSetAttribute((const void*)gemm8p_kernel,
                      hipFuncAttributeMaxDynamicSharedMemorySize, 131072);

  trcvt_kernel<<<dim3(64, 8, 1), 256, 0, stream>>>(
      w_gat, WgT2, KGAT, CRED, 0, 0);
  cvt_kernel<<<(CRED * CIN) / 2048, 256, 0, stream>>>(w_reduce, wred_b);
  cvt_kernel<<<(COUT * CRED) / 2048, 256, 0, stream>>>(w_restore, wres_b);
  gemm_redf_kernel<<<dim3(4, 256), 256, 0, stream>>>(
      x, wred_b, xr, g_red, b_red, m_red, v_red);
  attproj_kernel<<<64, 128, 0, stream>>>(w_gat, att_src, att_dst, P);
  att_kernel<<<MTOT / 4, 256, 0, stream>>>(xr, P, a_all);
  gemm8p_kernel<<<dim3(16, 64), 512, 131072, stream>>>(xr, WgT2, Y);
  agg4_kernel<<<4096, 256, 0, stream>>>(Y, a_all, gat_bias, gat);
  gemm_res_kernel<<<dim3(8, 128), 256, 0, stream>>>(
      gat, wres_b, outp, g_res, b_res, m_res, v_res, x);
  (void)in_sizes; (void)n_in; (void)out_size; (void)ws_size;
}

// Round 15
// 254.182 us; speedup vs baseline: 3.3580x; 1.1798x over previous
//
#include <hip/hip_runtime.h>

// ---------------------------------------------------------------------------
// GATBottleneck (ALL I/O fp32; compute bf16 MFMA, fp32 accum)
//
//  1. wgatp: WgT2p bf16 [4096][512]; WgT2p[j*8+h][k] = w_gat[k][h*512+j]
//            (COLUMN-REORDERED so Y' cols are (j,h)-interleaved)
//  2. cvt  : w_reduce, w_restore fp32 -> bf16 (already B^T layout)
//  3. gemm_redf: xr = relu(bn(x_nchw @ w_reduce^T))  [16384][512] bf16
//  4. attproj/att: alpha logits via factored projections       (fp32)
//  5. gemm8p : FUSED Y-projection + GAT aggregation.  Per block
//              (img, 32-gat-col tile): K-loop computes Y'[256 nodes]
//              [32 j x 8 h] in regs (R6-schedule, SWAPPED operands),
//              epilogue: acc -> LDS Ys[256][264] bf16 (staging region,
//              dead) -> per-node 5-edge x 8-head alpha-stencil -> gat.
//              Y NEVER touches HBM; agg kernel eliminated.
//  6. gemm_res: out = relu(bn(gat @ w_restore^T) + x) -> fp32 NCHW
// edge_index is the fixed 4-neighbor grid + self loops -> analytic.
// ---------------------------------------------------------------------------

typedef unsigned short u16;
typedef __attribute__((ext_vector_type(4))) unsigned short u16x4;
typedef __attribute__((ext_vector_type(8))) unsigned short u16x8;
typedef __attribute__((ext_vector_type(8))) __bf16 bf16x8;
typedef __attribute__((ext_vector_type(4))) float f32x4;

#define B_    64
#define CIN   1024
#define CRED  512
#define COUT  1024
#define NPIX  256
#define HEADS 8
#define KGAT  4096
#define MTOT  16384
#define EPSB  1e-5f

__device__ __forceinline__ float b2f(u16 u) {
  union { unsigned u; float f; } c; c.u = ((unsigned)u) << 16; return c.f;
}
__device__ __forceinline__ u16 f2b(float f) {
  union { float f; unsigned u; } c; c.f = f;
  unsigned r = (c.u + 0x7FFFu + ((c.u >> 16) & 1u)) >> 16;
  return (u16)r;
}

__device__ __forceinline__ void gload_lds16(const void* g, void* lds) {
  __builtin_amdgcn_global_load_lds(
      (const __attribute__((address_space(1))) void*)g,
      (__attribute__((address_space(3))) void*)lds, 16, 0, 0);
}

// ===== FUSED 256x256 GEMM + GAT stencil: gat-tile = stencil(xr @ Btp^T) ====
// K-loop: R6-verified schedule (BK=32, 16 tiles, 4-deep LDS, counted
// vmcnt(4), one barrier/tile, conflict-free XOR swizzle), operands SWAPPED
// (R4-verified D-layout: reg r <-> Y'-col; lane l15 <-> node).
// LDS: staging [0,131072)B (dead after K-loop) | Ys[256][264] u16 =
//   [0,135168)B overlay | alf[256][5*8] bf16 @135168 (survives: disjoint).
// Epilogue: acc -> Ys (u16x4, 8B-aligned, bank-floor), barrier, stencil:
//   thread (b=tid&7, nb8=(tid>>3)&63): outputs n = nb8+64*nn, j = b+8k.
//   Per (n,e): u16x8 Ys reads at rows {n, n+-16, n+-1}(clamped; alpha=0 for
//   invalid).  Bank slots (row+j) mod 8 uniform -> floor rate, 16B-aligned.
__global__ __launch_bounds__(512, 1) void gemm8p_kernel(
    const u16* __restrict__ A, const u16* __restrict__ Btp,
    const float* __restrict__ a_all, const float* __restrict__ gat_bias,
    u16* __restrict__ gat)
{
  extern __shared__ u16 lds[];
  u16* Ys  = lds;            // [256][264] u16 (overlays staging)
  u16* alf = lds + 67584;    // [256][40] bf16 alpha (beyond staging)

  const int tid = threadIdx.x;
  const int wave = tid >> 6, lane = tid & 63;
  const int wm = wave >> 2, wn = wave & 3;
  const int l15 = lane & 15, l4 = lane >> 4;

  // XCD-chunked swizzle over 1024 blocks (16 n-blocks x 64 m-blocks)
  int lin = blockIdx.y * 16 + blockIdx.x;
  lin = (lin & 7) * 128 + (lin >> 3);
  const int m0 = (lin >> 4) * 256;       // = img*256
  const int n0 = (lin & 15) * 256;       // Y'-col tile base
  const int img = lin >> 4;
  const int jbg = (lin & 15) * 32;       // gat col base
  const size_t nbase = (size_t)img * NPIX;

  // ---- alpha (bf16) for this image: 2048 (n,h) softmaxes, 4/thread ----
  {
    const float* a_src = a_all;
    const float* a_dst = a_all + (size_t)MTOT * HEADS;
#pragma unroll
    for (int i = 0; i < 4; ++i) {
      const int nh = tid + i * 512;
      const int n = nh >> 3, h = nh & 7;
      const int gi = n >> 4, gj = n & 15;
      int vv[5];
      vv[0] = n;
      vv[1] = (gi > 0)  ? n - 16 : -1;
      vv[2] = (gi < 15) ? n + 16 : -1;
      vv[3] = (gj > 0)  ? n - 1  : -1;
      vv[4] = (gj < 15) ? n + 1  : -1;
      const float ad = a_dst[(nbase + n) * HEADS + h];
      float l[5]; float mx = -1e30f;
#pragma unroll
      for (int e = 0; e < 5; ++e) {
        if (vv[e] >= 0) {
          const float xx = a_src[(nbase + vv[e]) * HEADS + h] + ad;
          l[e] = xx > 0.f ? xx : 0.2f * xx;   // leaky_relu(0.2)
          mx = fmaxf(mx, l[e]);
        } else l[e] = -1e30f;
      }
      float s = 0.f, ee[5];
#pragma unroll
      for (int e = 0; e < 5; ++e) {
        ee[e] = (vv[e] >= 0) ? __expf(l[e] - mx) : 0.f;
        s += ee[e];
      }
      const float inv = 0.125f / s;           // head-mean folded
#pragma unroll
      for (int e = 0; e < 5; ++e) alf[n * 40 + e * 8 + h] = f2b(ee[e] * inv);
    }
  }

  // ---- staging maps (R6 swizzle) ----
  int offS[2], ldsS[2];
#pragma unroll
  for (int i = 0; i < 2; ++i) {
    const int f = i * 512 + tid;
    const int r = f >> 2;
    const int kb = (f & 3) ^ ((r >> 1) & 3);
    offS[i] = r * 512 + kb * 8;
    ldsS[i] = (i * 512 + wave * 64) * 8;
  }
  const u16* gA = A + (size_t)m0 * 512;
  const u16* gB = Btp + (size_t)n0 * 512;

  auto stageA = [&](int kt) {
    const int bo = (kt & 3) * 16384;
    gload_lds16(gA + kt * 32 + offS[0], &lds[bo + ldsS[0]]);
    gload_lds16(gA + kt * 32 + offS[1], &lds[bo + ldsS[1]]);
  };
  auto stageB = [&](int kt) {
    const int bo = (kt & 3) * 16384 + 8192;
    gload_lds16(gB + kt * 32 + offS[0], &lds[bo + ldsS[0]]);
    gload_lds16(gB + kt * 32 + offS[1], &lds[bo + ldsS[1]]);
  };

  f32x4 acc[8][4];
#pragma unroll
  for (int i = 0; i < 8; ++i)
#pragma unroll
    for (int j = 0; j < 4; ++j) acc[i][j] = f32x4{0.f, 0.f, 0.f, 0.f};

  const int kq = (l4 ^ ((l15 >> 1) & 3)) * 8;
  const int aBase = (wm * 128 + l15) * 32 + kq;
  const int bBase = 8192 + (wn * 64 + l15) * 32 + kq;

  stageA(0); stageB(0); stageA(1); stageB(1);
  __syncthreads();   // drains vmcnt+lgkm: tile0 resident, alpha published

  for (int kt = 0; kt < 16; ++kt) {
    if (kt > 0) {
      if (kt == 15) { asm volatile("s_waitcnt vmcnt(0)" ::: "memory"); }
      else         { asm volatile("s_waitcnt vmcnt(4)" ::: "memory"); }
      __builtin_amdgcn_s_barrier();
    }
    const int bo = (kt & 3) * 16384;
    bf16x8 bfr[4], af0[4], af1[4];
#pragma unroll
    for (int f = 0; f < 4; ++f)
      bfr[f] = *(const bf16x8*)&lds[bo + bBase + f * 512];
#pragma unroll
    for (int f = 0; f < 4; ++f)
      af0[f] = *(const bf16x8*)&lds[bo + aBase + f * 512];
#pragma unroll
    for (int f = 0; f < 4; ++f)
      af1[f] = *(const bf16x8*)&lds[bo + aBase + (f + 4) * 512];
    if (kt < 14) { stageA(kt + 2); stageB(kt + 2); }
    __builtin_amdgcn_s_setprio(1);
    // SWAPPED operands (R4-verified): D transposed in regs.
#pragma unroll
    for (int fm = 0; fm < 4; ++fm)
#pragma unroll
      for (int fn = 0; fn < 4; ++fn)
        acc[fm][fn] = __builtin_amdgcn_mfma_f32_16x16x32_bf16(
            bfr[fn], af0[fm], acc[fm][fn], 0, 0, 0);
#pragma unroll
    for (int fm = 0; fm < 4; ++fm)
#pragma unroll
      for (int fn = 0; fn < 4; ++fn)
        acc[fm + 4][fn] = __builtin_amdgcn_mfma_f32_16x16x32_bf16(
            bfr[fn], af1[fm], acc[fm + 4][fn], 0, 0, 0);
    __builtin_amdgcn_s_setprio(0);
  }
  asm volatile("s_waitcnt vmcnt(0)" ::: "memory");
  __builtin_amdgcn_s_barrier();   // staging dead; Ys region free

  // ---- acc -> Ys  (swapped layout: node = ..+fm*16+l15, col = ..+l4*4+r) --
#pragma unroll
  for (int fm = 0; fm < 8; ++fm) {
    const int nloc = wm * 128 + fm * 16 + l15;
#pragma unroll
    for (int fn = 0; fn < 4; ++fn) {
      const int cloc = wn * 64 + fn * 16 + l4 * 4;
      u16x4 ov;
#pragma unroll
      for (int r = 0; r < 4; ++r) ov[r] = f2b(acc[fm][fn][r]);
      *(u16x4*)&Ys[nloc * 264 + cloc] = ov;
    }
  }
  __syncthreads();

  // ---- stencil: gat[n][jbg+j] = bias + sum_e sum_h alf*Ys[v_e][j*8+h] ----
  const int b = tid & 7;
  const int nb8 = (tid >> 3) & 63;
  float fb[4];
#pragma unroll
  for (int k = 0; k < 4; ++k) fb[k] = gat_bias[jbg + b + 8 * k];
#pragma unroll
  for (int nn = 0; nn < 4; ++nn) {
    const int n = nb8 + nn * 64;
    const int gi = n >> 4, gj = n & 15;
    int vv[5];
    vv[0] = n;
    vv[1] = (gi > 0)  ? n - 16 : n;   // invalid -> alpha==0, read self
    vv[2] = (gi < 15) ? n + 16 : n;
    vv[3] = (gj > 0)  ? n - 1  : n;
    vv[4] = (gj < 15) ? n + 1  : n;
    float o[4] = { fb[0], fb[1], fb[2], fb[3] };
#pragma unroll
    for (int e = 0; e < 5; ++e) {
      const u16x8 av = *(const u16x8*)&alf[n * 40 + e * 8];
      float a8[8];
#pragma unroll
      for (int h = 0; h < 8; ++h) a8[h] = b2f(av[h]);
      const u16* yrow = &Ys[vv[e] * 264];
#pragma unroll
      for (int k = 0; k < 4; ++k) {
        const u16x8 yv = *(const u16x8*)&yrow[(b + 8 * k) * 8];
#pragma unroll
        for (int h = 0; h < 8; ++h) o[k] += a8[h] * b2f(yv[h]);
      }
    }
    const size_t gr = (nbase + n) * (size_t)CRED + jbg;
#pragma unroll
    for (int k = 0; k < 4; ++k) gat[gr + b + 8 * k] = f2b(o[k]);
  }
}

// ===== WgT2p[j*8+h][k] = bf16(w_gat[k][h*512+j])  (column reorder) =========
__global__ __launch_bounds__(256) void wgatp_kernel(
    const float* __restrict__ w_gat, u16* __restrict__ out)
{
  __shared__ float tile[64][65];       // [k_local][c'_local]
  const int cb = blockIdx.x;           // j0 = cb*8, c' = cb*64..+63
  const int kb = blockIdx.y;           // k0 = kb*64
  const int t = threadIdx.x;
  const int jl = t & 7, h = (t >> 3) & 7, k4 = t >> 6;
#pragma unroll
  for (int i = 0; i < 16; ++i) {
    const int kl = k4 * 16 + i;
    tile[kl][jl * 8 + h] =
        w_gat[(size_t)(kb * 64 + kl) * KGAT + h * 512 + cb * 8 + jl];
  }
  __syncthreads();
#pragma unroll
  for (int i = 0; i < 4; ++i) {
    const int idx = i * 256 + t;
    const int cl = idx >> 4;
    const int kq = (idx & 15) * 4;
    u16x4 ov;
#pragma unroll
    for (int q = 0; q < 4; ++q) ov[q] = f2b(tile[kq + q][cl]);
    *(u16x4*)&out[(size_t)(cb * 64 + cl) * CRED + kb * 64 + kq] = ov;
  }
}

// ====== 64x128 FUSED reduce GEMM: xr = relu(bn(x_nchw @ w_reduce^T)) =======
__global__ __launch_bounds__(256, 2) void gemm_redf_kernel(
    const float* __restrict__ x, const u16* __restrict__ Bt,
    u16* __restrict__ out16,
    const float* __restrict__ pg, const float* __restrict__ pb,
    const float* __restrict__ pm, const float* __restrict__ pv)
{
  __shared__ u16 As[64 * 32];
  __shared__ u16 Bs[128 * 32];
  const int tid = threadIdx.x;
  const int wave = tid >> 6, lane = tid & 63;
  const int gx = gridDim.x;
  const int nwg = gx * gridDim.y;
  int lin = blockIdx.y * gx + blockIdx.x;
  lin = (lin & 7) * (nwg >> 3) + (lin >> 3);
  const int m0 = (lin / gx) * 64, n0 = (lin % gx) * 128;
  const int bimg = m0 >> 8, p0 = m0 & 255;

  const float* xsrc = x + (size_t)bimg * CIN * NPIX + p0 + lane;

  int offB[2], dstB[2];
#pragma unroll
  for (int i = 0; i < 2; ++i) {
    const int f = i * 256 + tid;
    const int r = f >> 2;
    const int kb = (f & 3) ^ ((r >> 1) & 3);
    offB[i] = r * CIN + kb * 8;
    dstB[i] = (i * 256 + wave * 64) * 8;
  }
  const u16* gB = Bt + (size_t)n0 * CIN;

  const int aWr = (lane * 4 + (wave ^ ((lane >> 1) & 3))) * 8;

  f32x4 acc[2][4];
#pragma unroll
  for (int i = 0; i < 2; ++i)
#pragma unroll
    for (int j = 0; j < 4; ++j) acc[i][j] = f32x4{0.f, 0.f, 0.f, 0.f};

  const int wr = wave >> 1, wc = wave & 1;
  const int l15 = lane & 15, l4 = lane >> 4;
  const int kq = (l4 ^ ((l15 >> 1) & 3)) * 8;

  float av[8];
#pragma unroll
  for (int j = 0; j < 8; ++j) av[j] = xsrc[(wave * 8 + j) * NPIX];

  for (int kt = 0; kt < CIN; kt += 32) {
    u16x8 pvv;
#pragma unroll
    for (int j = 0; j < 8; ++j) pvv[j] = f2b(av[j]);
    *(u16x8*)&As[aWr] = pvv;
    gload_lds16(gB + kt + offB[0], &Bs[dstB[0]]);
    gload_lds16(gB + kt + offB[1], &Bs[dstB[1]]);
    __syncthreads();
    if (kt + 32 < CIN) {
#pragma unroll
      for (int j = 0; j < 8; ++j)
        av[j] = xsrc[(kt + 32 + wave * 8 + j) * NPIX];
    }
    bf16x8 af[2], bfr[4];
#pragma unroll
    for (int f = 0; f < 2; ++f)
      af[f] = *(const bf16x8*)&As[(wr * 32 + f * 16 + l15) * 32 + kq];
#pragma unroll
    for (int f = 0; f < 4; ++f)
      bfr[f] = *(const bf16x8*)&Bs[(wc * 64 + f * 16 + l15) * 32 + kq];
#pragma unroll
    for (int fm = 0; fm < 2; ++fm)
#pragma unroll
      for (int fn = 0; fn < 4; ++fn)
        acc[fm][fn] = __builtin_amdgcn_mfma_f32_16x16x32_bf16(
            af[fm], bfr[fn], acc[fm][fn], 0, 0, 0);
    __syncthreads();
  }

  const int rowb = m0 + wr * 32 + (lane >> 4) * 4;
#pragma unroll
  for (int fn = 0; fn < 4; ++fn) {
    const int col = n0 + wc * 64 + fn * 16 + l15;
    const float sc = pg[col] * rsqrtf(pv[col] + EPSB);
    const float off = pb[col] - pm[col] * sc;
#pragma unroll
    for (int fm = 0; fm < 2; ++fm) {
      const int row = rowb + fm * 16;
#pragma unroll
      for (int r = 0; r < 4; ++r) {
        const float y = fmaxf(acc[fm][fn][r] * sc + off, 0.f);
        out16[(size_t)(row + r) * CRED + col] = f2b(y);
      }
    }
  }
}

// --------------------- elementwise fp32 -> bf16 convert --------------------
__global__ __launch_bounds__(256) void cvt_kernel(
    const float* __restrict__ src, u16* __restrict__ dst)
{
  const int i = (blockIdx.x * 256 + threadIdx.x) * 8;
  const float4 a = *(const float4*)&src[i];
  const float4 b = *(const float4*)&src[i + 4];
  u16x8 o;
  o[0] = f2b(a.x); o[1] = f2b(a.y); o[2] = f2b(a.z); o[3] = f2b(a.w);
  o[4] = f2b(b.x); o[5] = f2b(b.y); o[6] = f2b(b.z); o[7] = f2b(b.w);
  *(u16x8*)&dst[i] = o;
}

// ---- 128x128 restore GEMM, both-sides swizzle: out = relu(bn+res) ---------
__global__ __launch_bounds__(256, 2) void gemm_res_kernel(
    const u16* __restrict__ A, const u16* __restrict__ Bt,
    float* __restrict__ out32,
    const float* __restrict__ pg, const float* __restrict__ pb,
    const float* __restrict__ pm, const float* __restrict__ pv,
    const float* __restrict__ auxf)
{
  const int K = CRED;
  const int gx = gridDim.x;
  const int nwg = gx * gridDim.y;
  int lin = blockIdx.y * gx + blockIdx.x;
  lin = (lin & 7) * (nwg >> 3) + (lin >> 3);
  const int m0 = (lin / gx) * 128, n0 = (lin % gx) * 128;

  __shared__ u16 As[128 * 32];
  __shared__ u16 Bs[128 * 32];
  const int tid = threadIdx.x;
  const int wave = tid >> 6, lane = tid & 63;

  int offS[2], dstS[2];
#pragma unroll
  for (int i = 0; i < 2; ++i) {
    const int f = i * 256 + tid;
    const int r = f >> 2;
    const int kb = (f & 3) ^ ((r >> 1) & 3);
    offS[i] = r * K + kb * 8;
    dstS[i] = (i * 256 + wave * 64) * 8;
  }
  const u16* gA = A + (size_t)m0 * K;
  const u16* gB = Bt + (size_t)n0 * K;

  f32x4 acc[4][4];
#pragma unroll
  for (int i = 0; i < 4; ++i)
#pragma unroll
    for (int j = 0; j < 4; ++j) acc[i][j] = f32x4{0.f, 0.f, 0.f, 0.f};

  const int wr = wave >> 1, wc = wave & 1;
  const int l15 = lane & 15, l4 = lane >> 4;
  const int kq = (l4 ^ ((l15 >> 1) & 3)) * 8;

  for (int kt = 0; kt < K; kt += 32) {
    gload_lds16(gA + kt + offS[0], &As[dstS[0]]);
    gload_lds16(gA + kt + offS[1], &As[dstS[1]]);
    gload_lds16(gB + kt + offS[0], &Bs[dstS[0]]);
    gload_lds16(gB + kt + offS[1], &Bs[dstS[1]]);
    __syncthreads();
    bf16x8 af[4], bfr[4];
#pragma unroll
    for (int f = 0; f < 4; ++f) {
      af[f]  = *(const bf16x8*)&As[(wr * 64 + f * 16 + l15) * 32 + kq];
      bfr[f] = *(const bf16x8*)&Bs[(wc * 64 + f * 16 + l15) * 32 + kq];
    }
#pragma unroll
    for (int fm = 0; fm < 4; ++fm)
#pragma unroll
      for (int fn = 0; fn < 4; ++fn)
        acc[fm][fn] = __builtin_amdgcn_mfma_f32_16x16x32_bf16(
            af[fm], bfr[fn], acc[fm][fn], 0, 0, 0);
    __syncthreads();
  }

  const int rowb = m0 + wr * 64 + (lane >> 4) * 4;
#pragma unroll
  for (int fn = 0; fn < 4; ++fn) {
    const int col = n0 + wc * 64 + fn * 16 + l15;
    const float sc = pg[col] * rsqrtf(pv[col] + EPSB);
    const float off = pb[col] - pm[col] * sc;
#pragma unroll
    for (int fm = 0; fm < 4; ++fm) {
      const int row = rowb + fm * 16;
      const int bimg = row >> 8, p0 = row & 255;
      const size_t oa = (size_t)bimg * (COUT * NPIX) + (size_t)col * NPIX + p0;
      const float4 rv = *(const float4*)&auxf[oa];
      float4 ov;
      ov.x = fmaxf(acc[fm][fn][0] * sc + off + rv.x, 0.f);
      ov.y = fmaxf(acc[fm][fn][1] * sc + off + rv.y, 0.f);
      ov.z = fmaxf(acc[fm][fn][2] * sc + off + rv.z, 0.f);
      ov.w = fmaxf(acc[fm][fn][3] * sc + off + rv.w, 0.f);
      *(float4*)&out32[oa] = ov;
    }
  }
}

// ---------- P[s][h][c] = sum_t w_gat[c][h*512+t] * att_s[h][t] -------------
__global__ __launch_bounds__(128) void attproj_kernel(
    const float* __restrict__ w_gat, const float* __restrict__ att_src,
    const float* __restrict__ att_dst, float* __restrict__ P)
{
  __shared__ float av[CRED];
  const int bi = blockIdx.x;
  const int sh = bi & 15, q = bi >> 4;
  const int s = sh >> 3, h = sh & 7;
  const float* att = (s == 0) ? att_src : att_dst;
  for (int t = threadIdx.x; t < CRED; t += 128) av[t] = att[h * CRED + t];
  __syncthreads();
  const int c = q * 128 + threadIdx.x;
  const float* wrow = w_gat + (size_t)c * KGAT + h * CRED;
  float acc = 0.f;
  for (int j = 0; j < CRED; j += 4) {
    const float4 w = *(const float4*)&wrow[j];
    acc += w.x * av[j] + w.y * av[j + 1] + w.z * av[j + 2] + w.w * av[j + 3];
  }
  P[(size_t)sh * CRED + c] = acc;
}

// ---------- a_all[s][n][h] = xr[n] . P[s][h]   (one wave per node) ---------
__global__ __launch_bounds__(256) void att_kernel(
    const u16* __restrict__ xr, const float* __restrict__ P,
    float* __restrict__ a_all)
{
  const int wave = threadIdx.x >> 6, lane = threadIdx.x & 63;
  const int m = blockIdx.x * 4 + wave;
  const int sh = lane & 15, q = lane >> 4;
  const u16* xp = xr + (size_t)m * CRED + q * 128;
  const float* Pp = P + (size_t)sh * CRED + q * 128;
  float s = 0.f;
#pragma unroll
  for (int c = 0; c < 128; c += 8) {
    u16x8 xv = *(const u16x8*)&xp[c];
#pragma unroll
    for (int t = 0; t < 8; ++t) s += b2f(xv[t]) * Pp[c + t];
  }
  s += __shfl_xor(s, 16);
  s += __shfl_xor(s, 32);
  if (q == 0)
    a_all[(size_t)(sh >> 3) * MTOT * HEADS + (size_t)m * HEADS + (sh & 7)] = s;
}

// ---------------------------------------------------------------------------
extern "C" void kernel_launch(void* const* d_in, const int* in_sizes, int n_in,
                              void* d_out, int out_size, void* d_ws, size_t ws_size,
                              hipStream_t stream)
{
  const float* x         = (const float*)d_in[0];
  const float* w_reduce  = (const float*)d_in[1];
  const float* g_red     = (const float*)d_in[2];
  const float* b_red     = (const float*)d_in[3];
  const float* m_red     = (const float*)d_in[4];
  const float* v_red     = (const float*)d_in[5];
  const float* w_gat     = (const float*)d_in[6];
  const float* att_src   = (const float*)d_in[7];
  const float* att_dst   = (const float*)d_in[8];
  const float* gat_bias  = (const float*)d_in[9];
  const float* w_restore = (const float*)d_in[10];
  const float* g_res     = (const float*)d_in[11];
  const float* b_res     = (const float*)d_in[12];
  const float* m_res     = (const float*)d_in[13];
  const float* v_res     = (const float*)d_in[14];

  constexpr size_t SZ_XR   = (size_t)MTOT * CRED * 2;   // 16,777,216
  constexpr size_t SZ_GAT  = SZ_XR;
  constexpr size_t SZ_WGT  = (size_t)KGAT * CRED * 2;   //  4,194,304
  constexpr size_t SZ_WRD  = (size_t)CRED * CIN * 2;
  constexpr size_t SZ_WRS  = (size_t)COUT * CRED * 2;
  constexpr size_t SZ_P    = (size_t)16 * CRED * 4;
  char* ws = (char*)d_ws;
  u16*   xr     = (u16*)ws;
  u16*   gat    = (u16*)(ws + SZ_XR);
  u16*   WgT2p  = (u16*)(ws + SZ_XR + SZ_GAT);
  u16*   wred_b = (u16*)(ws + SZ_XR + SZ_GAT + SZ_WGT);
  u16*   wres_b = (u16*)(ws + SZ_XR + SZ_GAT + SZ_WGT + SZ_WRD);
  float* P      = (float*)(ws + SZ_XR + SZ_GAT + SZ_WGT + SZ_WRD + SZ_WRS);
  float* a_all  = (float*)(ws + SZ_XR + SZ_GAT + SZ_WGT + SZ_WRD + SZ_WRS + SZ_P);
  float* outp   = (float*)d_out;

  // Ys[256][264] u16 (135168 B) + alf[256][40] u16 (20480 B) = 155648 B
  hipFuncSetAttribute((const void*)gemm8p_kernel,
                      hipFuncAttributeMaxDynamicSharedMemorySize, 155648);

  wgatp_kernel<<<dim3(64, 8), 256, 0, stream>>>(w_gat, WgT2p);
  cvt_kernel<<<(CRED * CIN) / 2048, 256, 0, stream>>>(w_reduce, wred_b);
  cvt_kernel<<<(COUT * CRED) / 2048, 256, 0, stream>>>(w_restore, wres_b);
  gemm_redf_kernel<<<dim3(4, 256), 256, 0, stream>>>(
      x, wred_b, xr, g_red, b_red, m_red, v_red);
  attproj_kernel<<<64, 128, 0, stream>>>(w_gat, att_src, att_dst, P);
  att_kernel<<<MTOT / 4, 256, 0, stream>>>(xr, P, a_all);
  gemm8p_kernel<<<dim3(16, 64), 512, 155648, stream>>>(
      xr, WgT2p, a_all, gat_bias, gat);
  gemm_res_kernel<<<dim3(8, 128), 256, 0, stream>>>(
      gat, wres_b, outp, g_res, b_res, m_res, v_res, x);
  (void)in_sizes; (void)n_in; (void)out_size; (void)ws_size;
}

// Round 16
// 250.872 us; speedup vs baseline: 3.4023x; 1.0132x over previous
//
#include <hip/hip_runtime.h>

// ---------------------------------------------------------------------------
// GATBottleneck (ALL I/O fp32; compute bf16 MFMA, fp32 accum)
//
//  1. wgatp: WgT2p bf16 [4096][512]; WgT2p[j*8+h][k] = w_gat[k][h*512+j]
//  2. cvt  : w_reduce, w_restore fp32 -> bf16
//  3. gemm_redf: xr = relu(bn(x_nchw @ w_reduce^T))  [16384][512] bf16
//  4. attproj/att: alpha logits via factored projections       (fp32)
//  5. gemm8p : FUSED Y-projection + GAT stencil (R15 structure) with
//              (a) staging issued BEFORE alpha phase (overlap), and
//              (b) head-sum via v_dot2_f32_bf16 when available.
//  6. gemm_res: out = relu(bn(gat @ w_restore^T) + x) -> fp32 NCHW
// edge_index is the fixed 4-neighbor grid + self loops -> analytic.
// ---------------------------------------------------------------------------

typedef unsigned short u16;
typedef __attribute__((ext_vector_type(4))) unsigned short u16x4;
typedef __attribute__((ext_vector_type(8))) unsigned short u16x8;
typedef __attribute__((ext_vector_type(8))) __bf16 bf16x8;
typedef __attribute__((ext_vector_type(2))) __bf16 bf16x2;
typedef __attribute__((ext_vector_type(4))) float f32x4;

#if defined(__has_builtin)
#if __has_builtin(__builtin_amdgcn_fdot2_f32_bf16)
#define HAVE_DOT2 1
#endif
#endif

#define B_    64
#define CIN   1024
#define CRED  512
#define COUT  1024
#define NPIX  256
#define HEADS 8
#define KGAT  4096
#define MTOT  16384
#define EPSB  1e-5f

__device__ __forceinline__ float b2f(u16 u) {
  union { unsigned u; float f; } c; c.u = ((unsigned)u) << 16; return c.f;
}
__device__ __forceinline__ u16 f2b(float f) {
  union { float f; unsigned u; } c; c.f = f;
  unsigned r = (c.u + 0x7FFFu + ((c.u >> 16) & 1u)) >> 16;
  return (u16)r;
}

__device__ __forceinline__ void gload_lds16(const void* g, void* lds) {
  __builtin_amdgcn_global_load_lds(
      (const __attribute__((address_space(1))) void*)g,
      (__attribute__((address_space(3))) void*)lds, 16, 0, 0);
}

union U8u {
  u16x8 v;
  bf16x2 p[4];
};

// ===== FUSED 256x256 GEMM + GAT stencil: gat-tile = stencil(xr @ Btp^T) ====
// K-loop: R6-verified schedule, SWAPPED operands (D transposed in regs).
// LDS: staging [0,131072)B (dead after K-loop) | Ys[256][264] u16 overlay |
//      alf[256][40] bf16 @135168B (disjoint from staging).
__global__ __launch_bounds__(512, 1) void gemm8p_kernel(
    const u16* __restrict__ A, const u16* __restrict__ Btp,
    const float* __restrict__ a_all, const float* __restrict__ gat_bias,
    u16* __restrict__ gat)
{
  extern __shared__ u16 lds[];
  u16* Ys  = lds;            // [256][264] u16 (overlays staging)
  u16* alf = lds + 67584;    // [256][40] bf16 alpha (beyond staging)

  const int tid = threadIdx.x;
  const int wave = tid >> 6, lane = tid & 63;
  const int wm = wave >> 2, wn = wave & 3;
  const int l15 = lane & 15, l4 = lane >> 4;

  int lin = blockIdx.y * 16 + blockIdx.x;
  lin = (lin & 7) * 128 + (lin >> 3);
  const int m0 = (lin >> 4) * 256;       // = img*256
  const int n0 = (lin & 15) * 256;       // Y'-col tile base
  const int img = lin >> 4;
  const int jbg = (lin & 15) * 32;       // gat col base
  const size_t nbase = (size_t)img * NPIX;

  // ---- staging maps (R6 swizzle) ----
  int offS[2], ldsS[2];
#pragma unroll
  for (int i = 0; i < 2; ++i) {
    const int f = i * 512 + tid;
    const int r = f >> 2;
    const int kb = (f & 3) ^ ((r >> 1) & 3);
    offS[i] = r * 512 + kb * 8;
    ldsS[i] = (i * 512 + wave * 64) * 8;
  }
  const u16* gA = A + (size_t)m0 * 512;
  const u16* gB = Btp + (size_t)n0 * 512;

  auto stageA = [&](int kt) {
    const int bo = (kt & 3) * 16384;
    gload_lds16(gA + kt * 32 + offS[0], &lds[bo + ldsS[0]]);
    gload_lds16(gA + kt * 32 + offS[1], &lds[bo + ldsS[1]]);
  };
  auto stageB = [&](int kt) {
    const int bo = (kt & 3) * 16384 + 8192;
    gload_lds16(gB + kt * 32 + offS[0], &lds[bo + ldsS[0]]);
    gload_lds16(gB + kt * 32 + offS[1], &lds[bo + ldsS[1]]);
  };

  // issue first two K-tiles BEFORE alpha phase: HBM latency hides under
  // the alpha softmaxes (disjoint LDS regions; barrier below publishes both)
  stageA(0); stageB(0); stageA(1); stageB(1);

  // ---- alpha (bf16) for this image: 2048 (n,h) softmaxes, 4/thread ----
  {
    const float* a_src = a_all;
    const float* a_dst = a_all + (size_t)MTOT * HEADS;
#pragma unroll
    for (int i = 0; i < 4; ++i) {
      const int nh = tid + i * 512;
      const int n = nh >> 3, h = nh & 7;
      const int gi = n >> 4, gj = n & 15;
      int vv[5];
      vv[0] = n;
      vv[1] = (gi > 0)  ? n - 16 : -1;
      vv[2] = (gi < 15) ? n + 16 : -1;
      vv[3] = (gj > 0)  ? n - 1  : -1;
      vv[4] = (gj < 15) ? n + 1  : -1;
      const float ad = a_dst[(nbase + n) * HEADS + h];
      float l[5]; float mx = -1e30f;
#pragma unroll
      for (int e = 0; e < 5; ++e) {
        if (vv[e] >= 0) {
          const float xx = a_src[(nbase + vv[e]) * HEADS + h] + ad;
          l[e] = xx > 0.f ? xx : 0.2f * xx;   // leaky_relu(0.2)
          mx = fmaxf(mx, l[e]);
        } else l[e] = -1e30f;
      }
      float s = 0.f, ee[5];
#pragma unroll
      for (int e = 0; e < 5; ++e) {
        ee[e] = (vv[e] >= 0) ? __expf(l[e] - mx) : 0.f;
        s += ee[e];
      }
      const float inv = 0.125f / s;           // head-mean folded
#pragma unroll
      for (int e = 0; e < 5; ++e) alf[n * 40 + e * 8 + h] = f2b(ee[e] * inv);
    }
  }

  f32x4 acc[8][4];
#pragma unroll
  for (int i = 0; i < 8; ++i)
#pragma unroll
    for (int j = 0; j < 4; ++j) acc[i][j] = f32x4{0.f, 0.f, 0.f, 0.f};

  const int kq = (l4 ^ ((l15 >> 1) & 3)) * 8;
  const int aBase = (wm * 128 + l15) * 32 + kq;
  const int bBase = 8192 + (wn * 64 + l15) * 32 + kq;

  __syncthreads();   // drains vmcnt+lgkm: tile0 resident, alpha published

  for (int kt = 0; kt < 16; ++kt) {
    if (kt > 0) {
      if (kt == 15) { asm volatile("s_waitcnt vmcnt(0)" ::: "memory"); }
      else         { asm volatile("s_waitcnt vmcnt(4)" ::: "memory"); }
      __builtin_amdgcn_s_barrier();
    }
    const int bo = (kt & 3) * 16384;
    bf16x8 bfr[4], af0[4], af1[4];
#pragma unroll
    for (int f = 0; f < 4; ++f)
      bfr[f] = *(const bf16x8*)&lds[bo + bBase + f * 512];
#pragma unroll
    for (int f = 0; f < 4; ++f)
      af0[f] = *(const bf16x8*)&lds[bo + aBase + f * 512];
#pragma unroll
    for (int f = 0; f < 4; ++f)
      af1[f] = *(const bf16x8*)&lds[bo + aBase + (f + 4) * 512];
    if (kt < 14) { stageA(kt + 2); stageB(kt + 2); }
    __builtin_amdgcn_s_setprio(1);
#pragma unroll
    for (int fm = 0; fm < 4; ++fm)
#pragma unroll
      for (int fn = 0; fn < 4; ++fn)
        acc[fm][fn] = __builtin_amdgcn_mfma_f32_16x16x32_bf16(
            bfr[fn], af0[fm], acc[fm][fn], 0, 0, 0);
#pragma unroll
    for (int fm = 0; fm < 4; ++fm)
#pragma unroll
      for (int fn = 0; fn < 4; ++fn)
        acc[fm + 4][fn] = __builtin_amdgcn_mfma_f32_16x16x32_bf16(
            bfr[fn], af1[fm], acc[fm + 4][fn], 0, 0, 0);
    __builtin_amdgcn_s_setprio(0);
  }
  asm volatile("s_waitcnt vmcnt(0)" ::: "memory");
  __builtin_amdgcn_s_barrier();   // staging dead; Ys region free

  // ---- acc -> Ys  (swapped layout: node = ..+fm*16+l15, col = ..+l4*4+r) --
#pragma unroll
  for (int fm = 0; fm < 8; ++fm) {
    const int nloc = wm * 128 + fm * 16 + l15;
#pragma unroll
    for (int fn = 0; fn < 4; ++fn) {
      const int cloc = wn * 64 + fn * 16 + l4 * 4;
      u16x4 ov;
#pragma unroll
      for (int r = 0; r < 4; ++r) ov[r] = f2b(acc[fm][fn][r]);
      *(u16x4*)&Ys[nloc * 264 + cloc] = ov;
    }
  }
  __syncthreads();

  // ---- stencil: gat[n][jbg+j] = bias + sum_e sum_h alf*Ys[v_e][j*8+h] ----
  const int b = tid & 7;
  const int nb8 = (tid >> 3) & 63;
  float fb[4];
#pragma unroll
  for (int k = 0; k < 4; ++k) fb[k] = gat_bias[jbg + b + 8 * k];
#pragma unroll
  for (int nn = 0; nn < 4; ++nn) {
    const int n = nb8 + nn * 64;
    const int gi = n >> 4, gj = n & 15;
    int vv[5];
    vv[0] = n;
    vv[1] = (gi > 0)  ? n - 16 : n;   // invalid -> alpha==0, read self
    vv[2] = (gi < 15) ? n + 16 : n;
    vv[3] = (gj > 0)  ? n - 1  : n;
    vv[4] = (gj < 15) ? n + 1  : n;
    float o[4] = { fb[0], fb[1], fb[2], fb[3] };
#pragma unroll
    for (int e = 0; e < 5; ++e) {
      U8u au;
      au.v = *(const u16x8*)&alf[n * 40 + e * 8];
      const u16* yrow = &Ys[vv[e] * 264];
#if defined(HAVE_DOT2)
#pragma unroll
      for (int k = 0; k < 4; ++k) {
        U8u yu;
        yu.v = *(const u16x8*)&yrow[(b + 8 * k) * 8];
        float s = o[k];
        s = __builtin_amdgcn_fdot2_f32_bf16(yu.p[0], au.p[0], s, false);
        s = __builtin_amdgcn_fdot2_f32_bf16(yu.p[1], au.p[1], s, false);
        s = __builtin_amdgcn_fdot2_f32_bf16(yu.p[2], au.p[2], s, false);
        s = __builtin_amdgcn_fdot2_f32_bf16(yu.p[3], au.p[3], s, false);
        o[k] = s;
      }
#else
      float a8[8];
#pragma unroll
      for (int h = 0; h < 8; ++h) a8[h] = b2f(au.v[h]);
#pragma unroll
      for (int k = 0; k < 4; ++k) {
        const u16x8 yv = *(const u16x8*)&yrow[(b + 8 * k) * 8];
#pragma unroll
        for (int h = 0; h < 8; ++h) o[k] += a8[h] * b2f(yv[h]);
      }
#endif
    }
    const size_t gr = (nbase + n) * (size_t)CRED + jbg;
#pragma unroll
    for (int k = 0; k < 4; ++k) gat[gr + b + 8 * k] = f2b(o[k]);
  }
}

// ===== WgT2p[j*8+h][k] = bf16(w_gat[k][h*512+j])  (column reorder) =========
__global__ __launch_bounds__(256) void wgatp_kernel(
    const float* __restrict__ w_gat, u16* __restrict__ out)
{
  __shared__ float tile[64][65];       // [k_local][c'_local]
  const int cb = blockIdx.x;           // j0 = cb*8, c' = cb*64..+63
  const int kb = blockIdx.y;           // k0 = kb*64
  const int t = threadIdx.x;
  const int jl = t & 7, h = (t >> 3) & 7, k4 = t >> 6;
#pragma unroll
  for (int i = 0; i < 16; ++i) {
    const int kl = k4 * 16 + i;
    tile[kl][jl * 8 + h] =
        w_gat[(size_t)(kb * 64 + kl) * KGAT + h * 512 + cb * 8 + jl];
  }
  __syncthreads();
#pragma unroll
  for (int i = 0; i < 4; ++i) {
    const int idx = i * 256 + t;
    const int cl = idx >> 4;
    const int kq = (idx & 15) * 4;
    u16x4 ov;
#pragma unroll
    for (int q = 0; q < 4; ++q) ov[q] = f2b(tile[kq + q][cl]);
    *(u16x4*)&out[(size_t)(cb * 64 + cl) * CRED + kb * 64 + kq] = ov;
  }
}

// ====== 64x128 FUSED reduce GEMM: xr = relu(bn(x_nchw @ w_reduce^T)) =======
__global__ __launch_bounds__(256, 2) void gemm_redf_kernel(
    const float* __restrict__ x, const u16* __restrict__ Bt,
    u16* __restrict__ out16,
    const float* __restrict__ pg, const float* __restrict__ pb,
    const float* __restrict__ pm, const float* __restrict__ pv)
{
  __shared__ u16 As[64 * 32];
  __shared__ u16 Bs[128 * 32];
  const int tid = threadIdx.x;
  const int wave = tid >> 6, lane = tid & 63;
  const int gx = gridDim.x;
  const int nwg = gx * gridDim.y;
  int lin = blockIdx.y * gx + blockIdx.x;
  lin = (lin & 7) * (nwg >> 3) + (lin >> 3);
  const int m0 = (lin / gx) * 64, n0 = (lin % gx) * 128;
  const int bimg = m0 >> 8, p0 = m0 & 255;

  const float* xsrc = x + (size_t)bimg * CIN * NPIX + p0 + lane;

  int offB[2], dstB[2];
#pragma unroll
  for (int i = 0; i < 2; ++i) {
    const int f = i * 256 + tid;
    const int r = f >> 2;
    const int kb = (f & 3) ^ ((r >> 1) & 3);
    offB[i] = r * CIN + kb * 8;
    dstB[i] = (i * 256 + wave * 64) * 8;
  }
  const u16* gB = Bt + (size_t)n0 * CIN;

  const int aWr = (lane * 4 + (wave ^ ((lane >> 1) & 3))) * 8;

  f32x4 acc[2][4];
#pragma unroll
  for (int i = 0; i < 2; ++i)
#pragma unroll
    for (int j = 0; j < 4; ++j) acc[i][j] = f32x4{0.f, 0.f, 0.f, 0.f};

  const int wr = wave >> 1, wc = wave & 1;
  const int l15 = lane & 15, l4 = lane >> 4;
  const int kq = (l4 ^ ((l15 >> 1) & 3)) * 8;

  float av[8];
#pragma unroll
  for (int j = 0; j < 8; ++j) av[j] = xsrc[(wave * 8 + j) * NPIX];

  for (int kt = 0; kt < CIN; kt += 32) {
    u16x8 pvv;
#pragma unroll
    for (int j = 0; j < 8; ++j) pvv[j] = f2b(av[j]);
    *(u16x8*)&As[aWr] = pvv;
    gload_lds16(gB + kt + offB[0], &Bs[dstB[0]]);
    gload_lds16(gB + kt + offB[1], &Bs[dstB[1]]);
    __syncthreads();
    if (kt + 32 < CIN) {
#pragma unroll
      for (int j = 0; j < 8; ++j)
        av[j] = xsrc[(kt + 32 + wave * 8 + j) * NPIX];
    }
    bf16x8 af[2], bfr[4];
#pragma unroll
    for (int f = 0; f < 2; ++f)
      af[f] = *(const bf16x8*)&As[(wr * 32 + f * 16 + l15) * 32 + kq];
#pragma unroll
    for (int f = 0; f < 4; ++f)
      bfr[f] = *(const bf16x8*)&Bs[(wc * 64 + f * 16 + l15) * 32 + kq];
#pragma unroll
    for (int fm = 0; fm < 2; ++fm)
#pragma unroll
      for (int fn = 0; fn < 4; ++fn)
        acc[fm][fn] = __builtin_amdgcn_mfma_f32_16x16x32_bf16(
            af[fm], bfr[fn], acc[fm][fn], 0, 0, 0);
    __syncthreads();
  }

  const int rowb = m0 + wr * 32 + (lane >> 4) * 4;
#pragma unroll
  for (int fn = 0; fn < 4; ++fn) {
    const int col = n0 + wc * 64 + fn * 16 + l15;
    const float sc = pg[col] * rsqrtf(pv[col] + EPSB);
    const float off = pb[col] - pm[col] * sc;
#pragma unroll
    for (int fm = 0; fm < 2; ++fm) {
      const int row = rowb + fm * 16;
#pragma unroll
      for (int r = 0; r < 4; ++r) {
        const float y = fmaxf(acc[fm][fn][r] * sc + off, 0.f);
        out16[(size_t)(row + r) * CRED + col] = f2b(y);
      }
    }
  }
}

// --------------------- elementwise fp32 -> bf16 convert --------------------
__global__ __launch_bounds__(256) void cvt_kernel(
    const float* __restrict__ src, u16* __restrict__ dst)
{
  const int i = (blockIdx.x * 256 + threadIdx.x) * 8;
  const float4 a = *(const float4*)&src[i];
  const float4 b = *(const float4*)&src[i + 4];
  u16x8 o;
  o[0] = f2b(a.x); o[1] = f2b(a.y); o[2] = f2b(a.z); o[3] = f2b(a.w);
  o[4] = f2b(b.x); o[5] = f2b(b.y); o[6] = f2b(b.z); o[7] = f2b(b.w);
  *(u16x8*)&dst[i] = o;
}

// ---- 128x128 restore GEMM, both-sides swizzle: out = relu(bn+res) ---------
__global__ __launch_bounds__(256, 2) void gemm_res_kernel(
    const u16* __restrict__ A, const u16* __restrict__ Bt,
    float* __restrict__ out32,
    const float* __restrict__ pg, const float* __restrict__ pb,
    const float* __restrict__ pm, const float* __restrict__ pv,
    const float* __restrict__ auxf)
{
  const int K = CRED;
  const int gx = gridDim.x;
  const int nwg = gx * gridDim.y;
  int lin = blockIdx.y * gx + blockIdx.x;
  lin = (lin & 7) * (nwg >> 3) + (lin >> 3);
  const int m0 = (lin / gx) * 128, n0 = (lin % gx) * 128;

  __shared__ u16 As[128 * 32];
  __shared__ u16 Bs[128 * 32];
  const int tid = threadIdx.x;
  const int wave = tid >> 6, lane = tid & 63;

  int offS[2], dstS[2];
#pragma unroll
  for (int i = 0; i < 2; ++i) {
    const int f = i * 256 + tid;
    const int r = f >> 2;
    const int kb = (f & 3) ^ ((r >> 1) & 3);
    offS[i] = r * K + kb * 8;
    dstS[i] = (i * 256 + wave * 64) * 8;
  }
  const u16* gA = A + (size_t)m0 * K;
  const u16* gB = Bt + (size_t)n0 * K;

  f32x4 acc[4][4];
#pragma unroll
  for (int i = 0; i < 4; ++i)
#pragma unroll
    for (int j = 0; j < 4; ++j) acc[i][j] = f32x4{0.f, 0.f, 0.f, 0.f};

  const int wr = wave >> 1, wc = wave & 1;
  const int l15 = lane & 15, l4 = lane >> 4;
  const int kq = (l4 ^ ((l15 >> 1) & 3)) * 8;

  for (int kt = 0; kt < K; kt += 32) {
    gload_lds16(gA + kt + offS[0], &As[dstS[0]]);
    gload_lds16(gA + kt + offS[1], &As[dstS[1]]);
    gload_lds16(gB + kt + offS[0], &Bs[dstS[0]]);
    gload_lds16(gB + kt + offS[1], &Bs[dstS[1]]);
    __syncthreads();
    bf16x8 af[4], bfr[4];
#pragma unroll
    for (int f = 0; f < 4; ++f) {
      af[f]  = *(const bf16x8*)&As[(wr * 64 + f * 16 + l15) * 32 + kq];
      bfr[f] = *(const bf16x8*)&Bs[(wc * 64 + f * 16 + l15) * 32 + kq];
    }
#pragma unroll
    for (int fm = 0; fm < 4; ++fm)
#pragma unroll
      for (int fn = 0; fn < 4; ++fn)
        acc[fm][fn] = __builtin_amdgcn_mfma_f32_16x16x32_bf16(
            af[fm], bfr[fn], acc[fm][fn], 0, 0, 0);
    __syncthreads();
  }

  const int rowb = m0 + wr * 64 + (lane >> 4) * 4;
#pragma unroll
  for (int fn = 0; fn < 4; ++fn) {
    const int col = n0 + wc * 64 + fn * 16 + l15;
    const float sc = pg[col] * rsqrtf(pv[col] + EPSB);
    const float off = pb[col] - pm[col] * sc;
#pragma unroll
    for (int fm = 0; fm < 4; ++fm) {
      const int row = rowb + fm * 16;
      const int bimg = row >> 8, p0 = row & 255;
      const size_t oa = (size_t)bimg * (COUT * NPIX) + (size_t)col * NPIX + p0;
      const float4 rv = *(const float4*)&auxf[oa];
      float4 ov;
      ov.x = fmaxf(acc[fm][fn][0] * sc + off + rv.x, 0.f);
      ov.y = fmaxf(acc[fm][fn][1] * sc + off + rv.y, 0.f);
      ov.z = fmaxf(acc[fm][fn][2] * sc + off + rv.z, 0.f);
      ov.w = fmaxf(acc[fm][fn][3] * sc + off + rv.w, 0.f);
      *(float4*)&out32[oa] = ov;
    }
  }
}

// ---------- P[s][h][c] = sum_t w_gat[c][h*512+t] * att_s[h][t] -------------
__global__ __launch_bounds__(128) void attproj_kernel(
    const float* __restrict__ w_gat, const float* __restrict__ att_src,
    const float* __restrict__ att_dst, float* __restrict__ P)
{
  __shared__ float av[CRED];
  const int bi = blockIdx.x;
  const int sh = bi & 15, q = bi >> 4;
  const int s = sh >> 3, h = sh & 7;
  const float* att = (s == 0) ? att_src : att_dst;
  for (int t = threadIdx.x; t < CRED; t += 128) av[t] = att[h * CRED + t];
  __syncthreads();
  const int c = q * 128 + threadIdx.x;
  const float* wrow = w_gat + (size_t)c * KGAT + h * CRED;
  float acc = 0.f;
  for (int j = 0; j < CRED; j += 4) {
    const float4 w = *(const float4*)&wrow[j];
    acc += w.x * av[j] + w.y * av[j + 1] + w.z * av[j + 2] + w.w * av[j + 3];
  }
  P[(size_t)sh * CRED + c] = acc;
}

// ---------- a_all[s][n][h] = xr[n] . P[s][h]   (one wave per node) ---------
__global__ __launch_bounds__(256) void att_kernel(
    const u16* __restrict__ xr, const float* __restrict__ P,
    float* __restrict__ a_all)
{
  const int wave = threadIdx.x >> 6, lane = threadIdx.x & 63;
  const int m = blockIdx.x * 4 + wave;
  const int sh = lane & 15, q = lane >> 4;
  const u16* xp = xr + (size_t)m * CRED + q * 128;
  const float* Pp = P + (size_t)sh * CRED + q * 128;
  float s = 0.f;
#pragma unroll
  for (int c = 0; c < 128; c += 8) {
    u16x8 xv = *(const u16x8*)&xp[c];
#pragma unroll
    for (int t = 0; t < 8; ++t) s += b2f(xv[t]) * Pp[c + t];
  }
  s += __shfl_xor(s, 16);
  s += __shfl_xor(s, 32);
  if (q == 0)
    a_all[(size_t)(sh >> 3) * MTOT * HEADS + (size_t)m * HEADS + (sh & 7)] = s;
}

// ---------------------------------------------------------------------------
extern "C" void kernel_launch(void* const* d_in, const int* in_sizes, int n_in,
                              void* d_out, int out_size, void* d_ws, size_t ws_size,
                              hipStream_t stream)
{
  const float* x         = (const float*)d_in[0];
  const float* w_reduce  = (const float*)d_in[1];
  const float* g_red     = (const float*)d_in[2];
  const float* b_red     = (const float*)d_in[3];
  const float* m_red     = (const float*)d_in[4];
  const float* v_red     = (const float*)d_in[5];
  const float* w_gat     = (const float*)d_in[6];
  const float* att_src   = (const float*)d_in[7];
  const float* att_dst   = (const float*)d_in[8];
  const float* gat_bias  = (const float*)d_in[9];
  const float* w_restore = (const float*)d_in[10];
  const float* g_res     = (const float*)d_in[11];
  const float* b_res     = (const float*)d_in[12];
  const float* m_res     = (const float*)d_in[13];
  const float* v_res     = (const float*)d_in[14];

  constexpr size_t SZ_XR   = (size_t)MTOT * CRED * 2;
  constexpr size_t SZ_GAT  = SZ_XR;
  constexpr size_t SZ_WGT  = (size_t)KGAT * CRED * 2;
  constexpr size_t SZ_WRD  = (size_t)CRED * CIN * 2;
  constexpr size_t SZ_WRS  = (size_t)COUT * CRED * 2;
  constexpr size_t SZ_P    = (size_t)16 * CRED * 4;
  char* ws = (char*)d_ws;
  u16*   xr     = (u16*)ws;
  u16*   gat    = (u16*)(ws + SZ_XR);
  u16*   WgT2p  = (u16*)(ws + SZ_XR + SZ_GAT);
  u16*   wred_b = (u16*)(ws + SZ_XR + SZ_GAT + SZ_WGT);
  u16*   wres_b = (u16*)(ws + SZ_XR + SZ_GAT + SZ_WGT + SZ_WRD);
  float* P      = (float*)(ws + SZ_XR + SZ_GAT + SZ_WGT + SZ_WRD + SZ_WRS);
  float* a_all  = (float*)(ws + SZ_XR + SZ_GAT + SZ_WGT + SZ_WRD + SZ_WRS + SZ_P);
  float* outp   = (float*)d_out;

  hipFuncSetAttribute((const void*)gemm8p_kernel,
                      hipFuncAttributeMaxDynamicSharedMemorySize, 155648);

  wgatp_kernel<<<dim3(64, 8), 256, 0, stream>>>(w_gat, WgT2p);
  cvt_kernel<<<(CRED * CIN) / 2048, 256, 0, stream>>>(w_reduce, wred_b);
  cvt_kernel<<<(COUT * CRED) / 2048, 256, 0, stream>>>(w_restore, wres_b);
  gemm_redf_kernel<<<dim3(4, 256), 256, 0, stream>>>(
      x, wred_b, xr, g_red, b_red, m_red, v_red);
  attproj_kernel<<<64, 128, 0, stream>>>(w_gat, att_src, att_dst, P);
  att_kernel<<<MTOT / 4, 256, 0, stream>>>(xr, P, a_all);
  gemm8p_kernel<<<dim3(16, 64), 512, 155648, stream>>>(
      xr, WgT2p, a_all, gat_bias, gat);
  gemm_res_kernel<<<dim3(8, 128), 256, 0, stream>>>(
      gat, wres_b, outp, g_res, b_res, m_res, v_res, x);
  (void)in_sizes; (void)n_in; (void)out_size; (void)ws_size;
}

// Round 17
// 250.414 us; speedup vs baseline: 3.4085x; 1.0018x over previous
//
#include <hip/hip_runtime.h>

// ---------------------------------------------------------------------------
// GATBottleneck (ALL I/O fp32; compute bf16 MFMA, fp32 accum)
//
//  1. wgatp: WgT2p bf16 [4096][512]; WgT2p[j*8+h][k] = w_gat[k][h*512+j]
//  2. cvt2 : w_reduce + w_restore fp32 -> bf16 (single launch)
//  3. gemm_redf: xr = relu(bn(x_nchw @ w_reduce^T))  [16384][512] bf16
//  4. attproj/att: alpha logits via factored projections       (fp32)
//  5. gemm8p : FUSED Y-projection + GAT stencil (R16 structure: R6 K-loop,
//              swapped operands, dot2 head-sum stencil epilogue)
//  6. gemm_res: out = relu(bn(gat @ w_restore^T) + x) -> fp32 NCHW
//              NOW 256x256 R6 schedule (same K=512/16-tile loop as gemm8p,
//              normal operand order -> reg r = 4 consecutive pixels ->
//              float4 NCHW stores), grid 256 blocks (1 round).
// edge_index is the fixed 4-neighbor grid + self loops -> analytic.
// ---------------------------------------------------------------------------

typedef unsigned short u16;
typedef __attribute__((ext_vector_type(4))) unsigned short u16x4;
typedef __attribute__((ext_vector_type(8))) unsigned short u16x8;
typedef __attribute__((ext_vector_type(8))) __bf16 bf16x8;
typedef __attribute__((ext_vector_type(2))) __bf16 bf16x2;
typedef __attribute__((ext_vector_type(4))) float f32x4;

#if defined(__has_builtin)
#if __has_builtin(__builtin_amdgcn_fdot2_f32_bf16)
#define HAVE_DOT2 1
#endif
#endif

#define B_    64
#define CIN   1024
#define CRED  512
#define COUT  1024
#define NPIX  256
#define HEADS 8
#define KGAT  4096
#define MTOT  16384
#define EPSB  1e-5f

__device__ __forceinline__ float b2f(u16 u) {
  union { unsigned u; float f; } c; c.u = ((unsigned)u) << 16; return c.f;
}
__device__ __forceinline__ u16 f2b(float f) {
  union { float f; unsigned u; } c; c.f = f;
  unsigned r = (c.u + 0x7FFFu + ((c.u >> 16) & 1u)) >> 16;
  return (u16)r;
}

__device__ __forceinline__ void gload_lds16(const void* g, void* lds) {
  __builtin_amdgcn_global_load_lds(
      (const __attribute__((address_space(1))) void*)g,
      (__attribute__((address_space(3))) void*)lds, 16, 0, 0);
}

union U8u {
  u16x8 v;
  bf16x2 p[4];
};

// ===== FUSED 256x256 GEMM + GAT stencil (R16-verified) =====================
__global__ __launch_bounds__(512, 1) void gemm8p_kernel(
    const u16* __restrict__ A, const u16* __restrict__ Btp,
    const float* __restrict__ a_all, const float* __restrict__ gat_bias,
    u16* __restrict__ gat)
{
  extern __shared__ u16 lds[];
  u16* Ys  = lds;            // [256][264] u16 (overlays staging)
  u16* alf = lds + 67584;    // [256][40] bf16 alpha (beyond staging)

  const int tid = threadIdx.x;
  const int wave = tid >> 6, lane = tid & 63;
  const int wm = wave >> 2, wn = wave & 3;
  const int l15 = lane & 15, l4 = lane >> 4;

  int lin = blockIdx.y * 16 + blockIdx.x;
  lin = (lin & 7) * 128 + (lin >> 3);
  const int m0 = (lin >> 4) * 256;       // = img*256
  const int n0 = (lin & 15) * 256;       // Y'-col tile base
  const int img = lin >> 4;
  const int jbg = (lin & 15) * 32;       // gat col base
  const size_t nbase = (size_t)img * NPIX;

  int offS[2], ldsS[2];
#pragma unroll
  for (int i = 0; i < 2; ++i) {
    const int f = i * 512 + tid;
    const int r = f >> 2;
    const int kb = (f & 3) ^ ((r >> 1) & 3);
    offS[i] = r * 512 + kb * 8;
    ldsS[i] = (i * 512 + wave * 64) * 8;
  }
  const u16* gA = A + (size_t)m0 * 512;
  const u16* gB = Btp + (size_t)n0 * 512;

  auto stageA = [&](int kt) {
    const int bo = (kt & 3) * 16384;
    gload_lds16(gA + kt * 32 + offS[0], &lds[bo + ldsS[0]]);
    gload_lds16(gA + kt * 32 + offS[1], &lds[bo + ldsS[1]]);
  };
  auto stageB = [&](int kt) {
    const int bo = (kt & 3) * 16384 + 8192;
    gload_lds16(gB + kt * 32 + offS[0], &lds[bo + ldsS[0]]);
    gload_lds16(gB + kt * 32 + offS[1], &lds[bo + ldsS[1]]);
  };

  // issue first two K-tiles BEFORE alpha phase (latency overlap)
  stageA(0); stageB(0); stageA(1); stageB(1);

  // ---- alpha (bf16) for this image: 2048 (n,h) softmaxes, 4/thread ----
  {
    const float* a_src = a_all;
    const float* a_dst = a_all + (size_t)MTOT * HEADS;
#pragma unroll
    for (int i = 0; i < 4; ++i) {
      const int nh = tid + i * 512;
      const int n = nh >> 3, h = nh & 7;
      const int gi = n >> 4, gj = n & 15;
      int vv[5];
      vv[0] = n;
      vv[1] = (gi > 0)  ? n - 16 : -1;
      vv[2] = (gi < 15) ? n + 16 : -1;
      vv[3] = (gj > 0)  ? n - 1  : -1;
      vv[4] = (gj < 15) ? n + 1  : -1;
      const float ad = a_dst[(nbase + n) * HEADS + h];
      float l[5]; float mx = -1e30f;
#pragma unroll
      for (int e = 0; e < 5; ++e) {
        if (vv[e] >= 0) {
          const float xx = a_src[(nbase + vv[e]) * HEADS + h] + ad;
          l[e] = xx > 0.f ? xx : 0.2f * xx;   // leaky_relu(0.2)
          mx = fmaxf(mx, l[e]);
        } else l[e] = -1e30f;
      }
      float s = 0.f, ee[5];
#pragma unroll
      for (int e = 0; e < 5; ++e) {
        ee[e] = (vv[e] >= 0) ? __expf(l[e] - mx) : 0.f;
        s += ee[e];
      }
      const float inv = 0.125f / s;           // head-mean folded
#pragma unroll
      for (int e = 0; e < 5; ++e) alf[n * 40 + e * 8 + h] = f2b(ee[e] * inv);
    }
  }

  f32x4 acc[8][4];
#pragma unroll
  for (int i = 0; i < 8; ++i)
#pragma unroll
    for (int j = 0; j < 4; ++j) acc[i][j] = f32x4{0.f, 0.f, 0.f, 0.f};

  const int kq = (l4 ^ ((l15 >> 1) & 3)) * 8;
  const int aBase = (wm * 128 + l15) * 32 + kq;
  const int bBase = 8192 + (wn * 64 + l15) * 32 + kq;

  __syncthreads();

  for (int kt = 0; kt < 16; ++kt) {
    if (kt > 0) {
      if (kt == 15) { asm volatile("s_waitcnt vmcnt(0)" ::: "memory"); }
      else         { asm volatile("s_waitcnt vmcnt(4)" ::: "memory"); }
      __builtin_amdgcn_s_barrier();
    }
    const int bo = (kt & 3) * 16384;
    bf16x8 bfr[4], af0[4], af1[4];
#pragma unroll
    for (int f = 0; f < 4; ++f)
      bfr[f] = *(const bf16x8*)&lds[bo + bBase + f * 512];
#pragma unroll
    for (int f = 0; f < 4; ++f)
      af0[f] = *(const bf16x8*)&lds[bo + aBase + f * 512];
#pragma unroll
    for (int f = 0; f < 4; ++f)
      af1[f] = *(const bf16x8*)&lds[bo + aBase + (f + 4) * 512];
    if (kt < 14) { stageA(kt + 2); stageB(kt + 2); }
    __builtin_amdgcn_s_setprio(1);
#pragma unroll
    for (int fm = 0; fm < 4; ++fm)
#pragma unroll
      for (int fn = 0; fn < 4; ++fn)
        acc[fm][fn] = __builtin_amdgcn_mfma_f32_16x16x32_bf16(
            bfr[fn], af0[fm], acc[fm][fn], 0, 0, 0);
#pragma unroll
    for (int fm = 0; fm < 4; ++fm)
#pragma unroll
      for (int fn = 0; fn < 4; ++fn)
        acc[fm + 4][fn] = __builtin_amdgcn_mfma_f32_16x16x32_bf16(
            bfr[fn], af1[fm], acc[fm + 4][fn], 0, 0, 0);
    __builtin_amdgcn_s_setprio(0);
  }
  asm volatile("s_waitcnt vmcnt(0)" ::: "memory");
  __builtin_amdgcn_s_barrier();

  // ---- acc -> Ys (swapped layout: node = ..+fm*16+l15, col = ..+l4*4+r) ---
#pragma unroll
  for (int fm = 0; fm < 8; ++fm) {
    const int nloc = wm * 128 + fm * 16 + l15;
#pragma unroll
    for (int fn = 0; fn < 4; ++fn) {
      const int cloc = wn * 64 + fn * 16 + l4 * 4;
      u16x4 ov;
#pragma unroll
      for (int r = 0; r < 4; ++r) ov[r] = f2b(acc[fm][fn][r]);
      *(u16x4*)&Ys[nloc * 264 + cloc] = ov;
    }
  }
  __syncthreads();

  // ---- stencil: gat[n][jbg+j] = bias + sum_e sum_h alf*Ys[v_e][j*8+h] ----
  const int b = tid & 7;
  const int nb8 = (tid >> 3) & 63;
  float fb[4];
#pragma unroll
  for (int k = 0; k < 4; ++k) fb[k] = gat_bias[jbg + b + 8 * k];
#pragma unroll
  for (int nn = 0; nn < 4; ++nn) {
    const int n = nb8 + nn * 64;
    const int gi = n >> 4, gj = n & 15;
    int vv[5];
    vv[0] = n;
    vv[1] = (gi > 0)  ? n - 16 : n;
    vv[2] = (gi < 15) ? n + 16 : n;
    vv[3] = (gj > 0)  ? n - 1  : n;
    vv[4] = (gj < 15) ? n + 1  : n;
    float o[4] = { fb[0], fb[1], fb[2], fb[3] };
#pragma unroll
    for (int e = 0; e < 5; ++e) {
      U8u au;
      au.v = *(const u16x8*)&alf[n * 40 + e * 8];
      const u16* yrow = &Ys[vv[e] * 264];
#if defined(HAVE_DOT2)
#pragma unroll
      for (int k = 0; k < 4; ++k) {
        U8u yu;
        yu.v = *(const u16x8*)&yrow[(b + 8 * k) * 8];
        float s = o[k];
        s = __builtin_amdgcn_fdot2_f32_bf16(yu.p[0], au.p[0], s, false);
        s = __builtin_amdgcn_fdot2_f32_bf16(yu.p[1], au.p[1], s, false);
        s = __builtin_amdgcn_fdot2_f32_bf16(yu.p[2], au.p[2], s, false);
        s = __builtin_amdgcn_fdot2_f32_bf16(yu.p[3], au.p[3], s, false);
        o[k] = s;
      }
#else
      float a8[8];
#pragma unroll
      for (int h = 0; h < 8; ++h) a8[h] = b2f(au.v[h]);
#pragma unroll
      for (int k = 0; k < 4; ++k) {
        const u16x8 yv = *(const u16x8*)&yrow[(b + 8 * k) * 8];
#pragma unroll
        for (int h = 0; h < 8; ++h) o[k] += a8[h] * b2f(yv[h]);
      }
#endif
    }
    const size_t gr = (nbase + n) * (size_t)CRED + jbg;
#pragma unroll
    for (int k = 0; k < 4; ++k) gat[gr + b + 8 * k] = f2b(o[k]);
  }
}

// ===== 256x256 R6-schedule restore GEMM: out = relu(bn(gat@w^T)+x) ========
// Same K=512/16-tile loop as gemm8p; NORMAL operand order -> reg r = 4
// consecutive pixels -> float4 NCHW stores.  Grid 4x64 = 256 blocks.
__global__ __launch_bounds__(512, 1) void gemm_res2_kernel(
    const u16* __restrict__ A, const u16* __restrict__ Bt,
    float* __restrict__ out32,
    const float* __restrict__ pg, const float* __restrict__ pb,
    const float* __restrict__ pm, const float* __restrict__ pv,
    const float* __restrict__ auxf)
{
  extern __shared__ u16 lds[];
  const int tid = threadIdx.x;
  const int wave = tid >> 6, lane = tid & 63;
  const int wm = wave >> 2, wn = wave & 3;
  const int l15 = lane & 15, l4 = lane >> 4;

  // XCD swizzle over 256 blocks (4 n-blocks x 64 m-blocks)
  int lin = blockIdx.y * 4 + blockIdx.x;
  lin = (lin & 7) * 32 + (lin >> 3);
  const int m0 = (lin >> 2) * 256;
  const int n0 = (lin & 3) * 256;

  int offS[2], ldsS[2];
#pragma unroll
  for (int i = 0; i < 2; ++i) {
    const int f = i * 512 + tid;
    const int r = f >> 2;
    const int kb = (f & 3) ^ ((r >> 1) & 3);
    offS[i] = r * 512 + kb * 8;
    ldsS[i] = (i * 512 + wave * 64) * 8;
  }
  const u16* gA = A + (size_t)m0 * 512;
  const u16* gB = Bt + (size_t)n0 * 512;

  auto stageA = [&](int kt) {
    const int bo = (kt & 3) * 16384;
    gload_lds16(gA + kt * 32 + offS[0], &lds[bo + ldsS[0]]);
    gload_lds16(gA + kt * 32 + offS[1], &lds[bo + ldsS[1]]);
  };
  auto stageB = [&](int kt) {
    const int bo = (kt & 3) * 16384 + 8192;
    gload_lds16(gB + kt * 32 + offS[0], &lds[bo + ldsS[0]]);
    gload_lds16(gB + kt * 32 + offS[1], &lds[bo + ldsS[1]]);
  };

  f32x4 acc[8][4];
#pragma unroll
  for (int i = 0; i < 8; ++i)
#pragma unroll
    for (int j = 0; j < 4; ++j) acc[i][j] = f32x4{0.f, 0.f, 0.f, 0.f};

  const int kq = (l4 ^ ((l15 >> 1) & 3)) * 8;
  const int aBase = (wm * 128 + l15) * 32 + kq;
  const int bBase = 8192 + (wn * 64 + l15) * 32 + kq;

  stageA(0); stageB(0); stageA(1); stageB(1);

  for (int kt = 0; kt < 16; ++kt) {
    if (kt == 15) { asm volatile("s_waitcnt vmcnt(0)" ::: "memory"); }
    else         { asm volatile("s_waitcnt vmcnt(4)" ::: "memory"); }
    __builtin_amdgcn_s_barrier();
    const int bo = (kt & 3) * 16384;
    bf16x8 bfr[4], af0[4], af1[4];
#pragma unroll
    for (int f = 0; f < 4; ++f)
      bfr[f] = *(const bf16x8*)&lds[bo + bBase + f * 512];
#pragma unroll
    for (int f = 0; f < 4; ++f)
      af0[f] = *(const bf16x8*)&lds[bo + aBase + f * 512];
#pragma unroll
    for (int f = 0; f < 4; ++f)
      af1[f] = *(const bf16x8*)&lds[bo + aBase + (f + 4) * 512];
    if (kt < 14) { stageA(kt + 2); stageB(kt + 2); }
    __builtin_amdgcn_s_setprio(1);
#pragma unroll
    for (int fm = 0; fm < 4; ++fm)
#pragma unroll
      for (int fn = 0; fn < 4; ++fn)
        acc[fm][fn] = __builtin_amdgcn_mfma_f32_16x16x32_bf16(
            af0[fm], bfr[fn], acc[fm][fn], 0, 0, 0);
#pragma unroll
    for (int fm = 0; fm < 4; ++fm)
#pragma unroll
      for (int fn = 0; fn < 4; ++fn)
        acc[fm + 4][fn] = __builtin_amdgcn_mfma_f32_16x16x32_bf16(
            af1[fm], bfr[fn], acc[fm + 4][fn], 0, 0, 0);
    __builtin_amdgcn_s_setprio(0);
  }

  // epilogue: row = m0 + wm*128 + fm*16 + l4*4 + r (pixel), col = n0+wn*64+fn*16+l15
  const int rowb = m0 + wm * 128 + l4 * 4;
#pragma unroll
  for (int fn = 0; fn < 4; ++fn) {
    const int col = n0 + wn * 64 + fn * 16 + l15;
    const float sc = pg[col] * rsqrtf(pv[col] + EPSB);
    const float off = pb[col] - pm[col] * sc;
#pragma unroll
    for (int fm = 0; fm < 8; ++fm) {
      const int row = rowb + fm * 16;
      const int bimg = row >> 8, p0 = row & 255;
      const size_t oa = (size_t)bimg * (COUT * NPIX) + (size_t)col * NPIX + p0;
      const float4 rv = *(const float4*)&auxf[oa];
      float4 ov;
      ov.x = fmaxf(acc[fm][fn][0] * sc + off + rv.x, 0.f);
      ov.y = fmaxf(acc[fm][fn][1] * sc + off + rv.y, 0.f);
      ov.z = fmaxf(acc[fm][fn][2] * sc + off + rv.z, 0.f);
      ov.w = fmaxf(acc[fm][fn][3] * sc + off + rv.w, 0.f);
      *(float4*)&out32[oa] = ov;
    }
  }
}

// ===== WgT2p[j*8+h][k] = bf16(w_gat[k][h*512+j])  (column reorder) =========
__global__ __launch_bounds__(256) void wgatp_kernel(
    const float* __restrict__ w_gat, u16* __restrict__ out)
{
  __shared__ float tile[64][65];
  const int cb = blockIdx.x;
  const int kb = blockIdx.y;
  const int t = threadIdx.x;
  const int jl = t & 7, h = (t >> 3) & 7, k4 = t >> 6;
#pragma unroll
  for (int i = 0; i < 16; ++i) {
    const int kl = k4 * 16 + i;
    tile[kl][jl * 8 + h] =
        w_gat[(size_t)(kb * 64 + kl) * KGAT + h * 512 + cb * 8 + jl];
  }
  __syncthreads();
#pragma unroll
  for (int i = 0; i < 4; ++i) {
    const int idx = i * 256 + t;
    const int cl = idx >> 4;
    const int kq = (idx & 15) * 4;
    u16x4 ov;
#pragma unroll
    for (int q = 0; q < 4; ++q) ov[q] = f2b(tile[kq + q][cl]);
    *(u16x4*)&out[(size_t)(cb * 64 + cl) * CRED + kb * 64 + kq] = ov;
  }
}

// ====== 64x128 FUSED reduce GEMM: xr = relu(bn(x_nchw @ w_reduce^T)) =======
__global__ __launch_bounds__(256, 2) void gemm_redf_kernel(
    const float* __restrict__ x, const u16* __restrict__ Bt,
    u16* __restrict__ out16,
    const float* __restrict__ pg, const float* __restrict__ pb,
    const float* __restrict__ pm, const float* __restrict__ pv)
{
  __shared__ u16 As[64 * 32];
  __shared__ u16 Bs[128 * 32];
  const int tid = threadIdx.x;
  const int wave = tid >> 6, lane = tid & 63;
  const int gx = gridDim.x;
  const int nwg = gx * gridDim.y;
  int lin = blockIdx.y * gx + blockIdx.x;
  lin = (lin & 7) * (nwg >> 3) + (lin >> 3);
  const int m0 = (lin / gx) * 64, n0 = (lin % gx) * 128;
  const int bimg = m0 >> 8, p0 = m0 & 255;

  const float* xsrc = x + (size_t)bimg * CIN * NPIX + p0 + lane;

  int offB[2], dstB[2];
#pragma unroll
  for (int i = 0; i < 2; ++i) {
    const int f = i * 256 + tid;
    const int r = f >> 2;
    const int kb = (f & 3) ^ ((r >> 1) & 3);
    offB[i] = r * CIN + kb * 8;
    dstB[i] = (i * 256 + wave * 64) * 8;
  }
  const u16* gB = Bt + (size_t)n0 * CIN;

  const int aWr = (lane * 4 + (wave ^ ((lane >> 1) & 3))) * 8;

  f32x4 acc[2][4];
#pragma unroll
  for (int i = 0; i < 2; ++i)
#pragma unroll
    for (int j = 0; j < 4; ++j) acc[i][j] = f32x4{0.f, 0.f, 0.f, 0.f};

  const int wr = wave >> 1, wc = wave & 1;
  const int l15 = lane & 15, l4 = lane >> 4;
  const int kq = (l4 ^ ((l15 >> 1) & 3)) * 8;

  float av[8];
#pragma unroll
  for (int j = 0; j < 8; ++j) av[j] = xsrc[(wave * 8 + j) * NPIX];

  for (int kt = 0; kt < CIN; kt += 32) {
    u16x8 pvv;
#pragma unroll
    for (int j = 0; j < 8; ++j) pvv[j] = f2b(av[j]);
    *(u16x8*)&As[aWr] = pvv;
    gload_lds16(gB + kt + offB[0], &Bs[dstB[0]]);
    gload_lds16(gB + kt + offB[1], &Bs[dstB[1]]);
    __syncthreads();
    if (kt + 32 < CIN) {
#pragma unroll
      for (int j = 0; j < 8; ++j)
        av[j] = xsrc[(kt + 32 + wave * 8 + j) * NPIX];
    }
    bf16x8 af[2], bfr[4];
#pragma unroll
    for (int f = 0; f < 2; ++f)
      af[f] = *(const bf16x8*)&As[(wr * 32 + f * 16 + l15) * 32 + kq];
#pragma unroll
    for (int f = 0; f < 4; ++f)
      bfr[f] = *(const bf16x8*)&Bs[(wc * 64 + f * 16 + l15) * 32 + kq];
#pragma unroll
    for (int fm = 0; fm < 2; ++fm)
#pragma unroll
      for (int fn = 0; fn < 4; ++fn)
        acc[fm][fn] = __builtin_amdgcn_mfma_f32_16x16x32_bf16(
            af[fm], bfr[fn], acc[fm][fn], 0, 0, 0);
    __syncthreads();
  }

  const int rowb = m0 + wr * 32 + (lane >> 4) * 4;
#pragma unroll
  for (int fn = 0; fn < 4; ++fn) {
    const int col = n0 + wc * 64 + fn * 16 + l15;
    const float sc = pg[col] * rsqrtf(pv[col] + EPSB);
    const float off = pb[col] - pm[col] * sc;
#pragma unroll
    for (int fm = 0; fm < 2; ++fm) {
      const int row = rowb + fm * 16;
#pragma unroll
      for (int r = 0; r < 4; ++r) {
        const float y = fmaxf(acc[fm][fn][r] * sc + off, 0.f);
        out16[(size_t)(row + r) * CRED + col] = f2b(y);
      }
    }
  }
}

// --------- elementwise fp32 -> bf16 convert, two buffers, one launch -------
__global__ __launch_bounds__(256) void cvt2_kernel(
    const float* __restrict__ s0, u16* __restrict__ d0,
    const float* __restrict__ s1, u16* __restrict__ d1, int half)
{
  const int bi = blockIdx.x;
  const float* src = (bi < half) ? s0 : s1;
  u16* dst = (bi < half) ? d0 : d1;
  const int i = ((bi < half ? bi : bi - half) * 256 + threadIdx.x) * 8;
  const float4 a = *(const float4*)&src[i];
  const float4 b = *(const float4*)&src[i + 4];
  u16x8 o;
  o[0] = f2b(a.x); o[1] = f2b(a.y); o[2] = f2b(a.z); o[3] = f2b(a.w);
  o[4] = f2b(b.x); o[5] = f2b(b.y); o[6] = f2b(b.z); o[7] = f2b(b.w);
  *(u16x8*)&dst[i] = o;
}

// ---------- P[s][h][c] = sum_t w_gat[c][h*512+t] * att_s[h][t] -------------
__global__ __launch_bounds__(128) void attproj_kernel(
    const float* __restrict__ w_gat, const float* __restrict__ att_src,
    const float* __restrict__ att_dst, float* __restrict__ P)
{
  __shared__ float av[CRED];
  const int bi = blockIdx.x;
  const int sh = bi & 15, q = bi >> 4;
  const int s = sh >> 3, h = sh & 7;
  const float* att = (s == 0) ? att_src : att_dst;
  for (int t = threadIdx.x; t < CRED; t += 128) av[t] = att[h * CRED + t];
  __syncthreads();
  const int c = q * 128 + threadIdx.x;
  const float* wrow = w_gat + (size_t)c * KGAT + h * CRED;
  float acc = 0.f;
  for (int j = 0; j < CRED; j += 4) {
    const float4 w = *(const float4*)&wrow[j];
    acc += w.x * av[j] + w.y * av[j + 1] + w.z * av[j + 2] + w.w * av[j + 3];
  }
  P[(size_t)sh * CRED + c] = acc;
}

// ---------- a_all[s][n][h] = xr[n] . P[s][h]   (one wave per node) ---------
__global__ __launch_bounds__(256) void att_kernel(
    const u16* __restrict__ xr, const float* __restrict__ P,
    float* __restrict__ a_all)
{
  const int wave = threadIdx.x >> 6, lane = threadIdx.x & 63;
  const int m = blockIdx.x * 4 + wave;
  const int sh = lane & 15, q = lane >> 4;
  const u16* xp = xr + (size_t)m * CRED + q * 128;
  const float* Pp = P + (size_t)sh * CRED + q * 128;
  float s = 0.f;
#pragma unroll
  for (int c = 0; c < 128; c += 8) {
    u16x8 xv = *(const u16x8*)&xp[c];
#pragma unroll
    for (int t = 0; t < 8; ++t) s += b2f(xv[t]) * Pp[c + t];
  }
  s += __shfl_xor(s, 16);
  s += __shfl_xor(s, 32);
  if (q == 0)
    a_all[(size_t)(sh >> 3) * MTOT * HEADS + (size_t)m * HEADS + (sh & 7)] = s;
}

// ---------------------------------------------------------------------------
extern "C" void kernel_launch(void* const* d_in, const int* in_sizes, int n_in,
                              void* d_out, int out_size, void* d_ws, size_t ws_size,
                              hipStream_t stream)
{
  const float* x         = (const float*)d_in[0];
  const float* w_reduce  = (const float*)d_in[1];
  const float* g_red     = (const float*)d_in[2];
  const float* b_red     = (const float*)d_in[3];
  const float* m_red     = (const float*)d_in[4];
  const float* v_red     = (const float*)d_in[5];
  const float* w_gat     = (const float*)d_in[6];
  const float* att_src   = (const float*)d_in[7];
  const float* att_dst   = (const float*)d_in[8];
  const float* gat_bias  = (const float*)d_in[9];
  const float* w_restore = (const float*)d_in[10];
  const float* g_res     = (const float*)d_in[11];
  const float* b_res     = (const float*)d_in[12];
  const float* m_res     = (const float*)d_in[13];
  const float* v_res     = (const float*)d_in[14];

  constexpr size_t SZ_XR   = (size_t)MTOT * CRED * 2;
  constexpr size_t SZ_GAT  = SZ_XR;
  constexpr size_t SZ_WGT  = (size_t)KGAT * CRED * 2;
  constexpr size_t SZ_WRD  = (size_t)CRED * CIN * 2;
  constexpr size_t SZ_WRS  = (size_t)COUT * CRED * 2;
  constexpr size_t SZ_P    = (size_t)16 * CRED * 4;
  char* ws = (char*)d_ws;
  u16*   xr     = (u16*)ws;
  u16*   gat    = (u16*)(ws + SZ_XR);
  u16*   WgT2p  = (u16*)(ws + SZ_XR + SZ_GAT);
  u16*   wred_b = (u16*)(ws + SZ_XR + SZ_GAT + SZ_WGT);
  u16*   wres_b = (u16*)(ws + SZ_XR + SZ_GAT + SZ_WGT + SZ_WRD);
  float* P      = (float*)(ws + SZ_XR + SZ_GAT + SZ_WGT + SZ_WRD + SZ_WRS);
  float* a_all  = (float*)(ws + SZ_XR + SZ_GAT + SZ_WGT + SZ_WRD + SZ_WRS + SZ_P);
  float* outp   = (float*)d_out;

  hipFuncSetAttribute((const void*)gemm8p_kernel,
                      hipFuncAttributeMaxDynamicSharedMemorySize, 155648);
  hipFuncSetAttribute((const void*)gemm_res2_kernel,
                      hipFuncAttributeMaxDynamicSharedMemorySize, 131072);

  wgatp_kernel<<<dim3(64, 8), 256, 0, stream>>>(w_gat, WgT2p);
  cvt2_kernel<<<512, 256, 0, stream>>>(
      w_reduce, wred_b, w_restore, wres_b, 256);
  gemm_redf_kernel<<<dim3(4, 256), 256, 0, stream>>>(
      x, wred_b, xr, g_red, b_red, m_red, v_red);
  attproj_kernel<<<64, 128, 0, stream>>>(w_gat, att_src, att_dst, P);
  att_kernel<<<MTOT / 4, 256, 0, stream>>>(xr, P, a_all);
  gemm8p_kernel<<<dim3(16, 64), 512, 155648, stream>>>(
      xr, WgT2p, a_all, gat_bias, gat);
  gemm_res2_kernel<<<dim3(4, 64), 512, 131072, stream>>>(
      gat, wres_b, outp, g_res, b_res, m_res, v_res, x);
  (void)in_sizes; (void)n_in; (void)out_size; (void)ws_size;
}

// Round 18
// 243.079 us; speedup vs baseline: 3.5113x; 1.0302x over previous
//
#include <hip/hip_runtime.h>

// ---------------------------------------------------------------------------
// GATBottleneck (ALL I/O fp32; compute bf16 MFMA, fp32 accum)
//
//  1. wgatp: WgT2p bf16 [4096][512]; WgT2p[j*8+h][k] = w_gat[k][h*512+j]
//  2. cvt2 : w_reduce + w_restore fp32 -> bf16 (single launch)
//  3. gemm_redf: xr = relu(bn(x_nchw @ w_reduce^T))  [16384][512] bf16
//  4. attproj/att: alpha logits via factored projections       (fp32)
//  5. alphapre: per-(node,head) 5-edge softmax -> alf_g bf16 [16384][40]
//              (computed ONCE; previously recomputed in all 16 col-tile
//               blocks of each image inside gemm8p)
//  6. gemm8p : FUSED Y-projection + GAT stencil (R16 structure; alpha now
//              a 10KB coalesced LDS copy instead of 2048 softmaxes)
//  7. gemm_res2: out = relu(bn(gat @ w_restore^T) + x) -> fp32 NCHW
// edge_index is the fixed 4-neighbor grid + self loops -> analytic.
// ---------------------------------------------------------------------------

typedef unsigned short u16;
typedef __attribute__((ext_vector_type(4))) unsigned short u16x4;
typedef __attribute__((ext_vector_type(8))) unsigned short u16x8;
typedef __attribute__((ext_vector_type(8))) __bf16 bf16x8;
typedef __attribute__((ext_vector_type(2))) __bf16 bf16x2;
typedef __attribute__((ext_vector_type(4))) float f32x4;

#if defined(__has_builtin)
#if __has_builtin(__builtin_amdgcn_fdot2_f32_bf16)
#define HAVE_DOT2 1
#endif
#endif

#define B_    64
#define CIN   1024
#define CRED  512
#define COUT  1024
#define NPIX  256
#define HEADS 8
#define KGAT  4096
#define MTOT  16384
#define EPSB  1e-5f

__device__ __forceinline__ float b2f(u16 u) {
  union { unsigned u; float f; } c; c.u = ((unsigned)u) << 16; return c.f;
}
__device__ __forceinline__ u16 f2b(float f) {
  union { float f; unsigned u; } c; c.f = f;
  unsigned r = (c.u + 0x7FFFu + ((c.u >> 16) & 1u)) >> 16;
  return (u16)r;
}

__device__ __forceinline__ void gload_lds16(const void* g, void* lds) {
  __builtin_amdgcn_global_load_lds(
      (const __attribute__((address_space(1))) void*)g,
      (__attribute__((address_space(3))) void*)lds, 16, 0, 0);
}

union U8u {
  u16x8 v;
  bf16x2 p[4];
};

// ---- alphapre: alf_g[n][e*8+h] = softmax-alpha (1/8 folded), bf16 ---------
__global__ __launch_bounds__(256) void alphapre_kernel(
    const float* __restrict__ a_all, u16* __restrict__ alf_g)
{
  const int nh = blockIdx.x * 256 + threadIdx.x;   // 0..131071
  const int ng = nh >> 3, h = nh & 7;              // global node, head
  const int n = ng & 255;
  const size_t nbase = (size_t)(ng >> 8) * NPIX;
  const int gi = n >> 4, gj = n & 15;
  int vv[5];
  vv[0] = n;
  vv[1] = (gi > 0)  ? n - 16 : -1;
  vv[2] = (gi < 15) ? n + 16 : -1;
  vv[3] = (gj > 0)  ? n - 1  : -1;
  vv[4] = (gj < 15) ? n + 1  : -1;
  const float* a_src = a_all;
  const float* a_dst = a_all + (size_t)MTOT * HEADS;
  const float ad = a_dst[(nbase + n) * HEADS + h];
  float l[5]; float mx = -1e30f;
#pragma unroll
  for (int e = 0; e < 5; ++e) {
    if (vv[e] >= 0) {
      const float xx = a_src[(nbase + vv[e]) * HEADS + h] + ad;
      l[e] = xx > 0.f ? xx : 0.2f * xx;            // leaky_relu(0.2)
      mx = fmaxf(mx, l[e]);
    } else l[e] = -1e30f;
  }
  float s = 0.f, ee[5];
#pragma unroll
  for (int e = 0; e < 5; ++e) {
    ee[e] = (vv[e] >= 0) ? __expf(l[e] - mx) : 0.f;
    s += ee[e];
  }
  const float inv = 0.125f / s;                    // head-mean folded
#pragma unroll
  for (int e = 0; e < 5; ++e)
    alf_g[(size_t)ng * 40 + e * 8 + h] = f2b(ee[e] * inv);
}

// ===== FUSED 256x256 GEMM + GAT stencil (R16-verified K-loop/stencil) ======
__global__ __launch_bounds__(512, 1) void gemm8p_kernel(
    const u16* __restrict__ A, const u16* __restrict__ Btp,
    const u16* __restrict__ alf_g, const float* __restrict__ gat_bias,
    u16* __restrict__ gat)
{
  extern __shared__ u16 lds[];
  u16* Ys  = lds;            // [256][264] u16 (overlays staging)
  u16* alf = lds + 67584;    // [256][40] bf16 alpha (beyond staging)

  const int tid = threadIdx.x;
  const int wave = tid >> 6, lane = tid & 63;
  const int wm = wave >> 2, wn = wave & 3;
  const int l15 = lane & 15, l4 = lane >> 4;

  int lin = blockIdx.y * 16 + blockIdx.x;
  lin = (lin & 7) * 128 + (lin >> 3);
  const int m0 = (lin >> 4) * 256;       // = img*256
  const int n0 = (lin & 15) * 256;       // Y'-col tile base
  const int img = lin >> 4;
  const int jbg = (lin & 15) * 32;       // gat col base
  const size_t nbase = (size_t)img * NPIX;

  int offS[2], ldsS[2];
#pragma unroll
  for (int i = 0; i < 2; ++i) {
    const int f = i * 512 + tid;
    const int r = f >> 2;
    const int kb = (f & 3) ^ ((r >> 1) & 3);
    offS[i] = r * 512 + kb * 8;
    ldsS[i] = (i * 512 + wave * 64) * 8;
  }
  const u16* gA = A + (size_t)m0 * 512;
  const u16* gB = Btp + (size_t)n0 * 512;

  auto stageA = [&](int kt) {
    const int bo = (kt & 3) * 16384;
    gload_lds16(gA + kt * 32 + offS[0], &lds[bo + ldsS[0]]);
    gload_lds16(gA + kt * 32 + offS[1], &lds[bo + ldsS[1]]);
  };
  auto stageB = [&](int kt) {
    const int bo = (kt & 3) * 16384 + 8192;
    gload_lds16(gB + kt * 32 + offS[0], &lds[bo + ldsS[0]]);
    gload_lds16(gB + kt * 32 + offS[1], &lds[bo + ldsS[1]]);
  };

  // issue first two K-tiles, then copy precomputed alpha (coalesced 10KB)
  stageA(0); stageB(0); stageA(1); stageB(1);
  {
    const u16* ag = alf_g + nbase * 40;
    for (int i = tid; i < 1280; i += 512)
      *(u16x8*)&alf[i * 8] = *(const u16x8*)&ag[i * 8];
  }

  f32x4 acc[8][4];
#pragma unroll
  for (int i = 0; i < 8; ++i)
#pragma unroll
    for (int j = 0; j < 4; ++j) acc[i][j] = f32x4{0.f, 0.f, 0.f, 0.f};

  const int kq = (l4 ^ ((l15 >> 1) & 3)) * 8;
  const int aBase = (wm * 128 + l15) * 32 + kq;
  const int bBase = 8192 + (wn * 64 + l15) * 32 + kq;

  __syncthreads();   // tile0 resident, alpha published

  for (int kt = 0; kt < 16; ++kt) {
    if (kt > 0) {
      if (kt == 15) { asm volatile("s_waitcnt vmcnt(0)" ::: "memory"); }
      else         { asm volatile("s_waitcnt vmcnt(4)" ::: "memory"); }
      __builtin_amdgcn_s_barrier();
    }
    const int bo = (kt & 3) * 16384;
    bf16x8 bfr[4], af0[4], af1[4];
#pragma unroll
    for (int f = 0; f < 4; ++f)
      bfr[f] = *(const bf16x8*)&lds[bo + bBase + f * 512];
#pragma unroll
    for (int f = 0; f < 4; ++f)
      af0[f] = *(const bf16x8*)&lds[bo + aBase + f * 512];
#pragma unroll
    for (int f = 0; f < 4; ++f)
      af1[f] = *(const bf16x8*)&lds[bo + aBase + (f + 4) * 512];
    if (kt < 14) { stageA(kt + 2); stageB(kt + 2); }
    __builtin_amdgcn_s_setprio(1);
#pragma unroll
    for (int fm = 0; fm < 4; ++fm)
#pragma unroll
      for (int fn = 0; fn < 4; ++fn)
        acc[fm][fn] = __builtin_amdgcn_mfma_f32_16x16x32_bf16(
            bfr[fn], af0[fm], acc[fm][fn], 0, 0, 0);
#pragma unroll
    for (int fm = 0; fm < 4; ++fm)
#pragma unroll
      for (int fn = 0; fn < 4; ++fn)
        acc[fm + 4][fn] = __builtin_amdgcn_mfma_f32_16x16x32_bf16(
            bfr[fn], af1[fm], acc[fm + 4][fn], 0, 0, 0);
    __builtin_amdgcn_s_setprio(0);
  }
  asm volatile("s_waitcnt vmcnt(0)" ::: "memory");
  __builtin_amdgcn_s_barrier();

  // ---- acc -> Ys (swapped layout: node = ..+fm*16+l15, col = ..+l4*4+r) ---
#pragma unroll
  for (int fm = 0; fm < 8; ++fm) {
    const int nloc = wm * 128 + fm * 16 + l15;
#pragma unroll
    for (int fn = 0; fn < 4; ++fn) {
      const int cloc = wn * 64 + fn * 16 + l4 * 4;
      u16x4 ov;
#pragma unroll
      for (int r = 0; r < 4; ++r) ov[r] = f2b(acc[fm][fn][r]);
      *(u16x4*)&Ys[nloc * 264 + cloc] = ov;
    }
  }
  __syncthreads();

  // ---- stencil: gat[n][jbg+j] = bias + sum_e sum_h alf*Ys[v_e][j*8+h] ----
  const int b = tid & 7;
  const int nb8 = (tid >> 3) & 63;
  float fb[4];
#pragma unroll
  for (int k = 0; k < 4; ++k) fb[k] = gat_bias[jbg + b + 8 * k];
#pragma unroll
  for (int nn = 0; nn < 4; ++nn) {
    const int n = nb8 + nn * 64;
    const int gi = n >> 4, gj = n & 15;
    int vv[5];
    vv[0] = n;
    vv[1] = (gi > 0)  ? n - 16 : n;
    vv[2] = (gi < 15) ? n + 16 : n;
    vv[3] = (gj > 0)  ? n - 1  : n;
    vv[4] = (gj < 15) ? n + 1  : n;
    float o[4] = { fb[0], fb[1], fb[2], fb[3] };
#pragma unroll
    for (int e = 0; e < 5; ++e) {
      U8u au;
      au.v = *(const u16x8*)&alf[n * 40 + e * 8];
      const u16* yrow = &Ys[vv[e] * 264];
#if defined(HAVE_DOT2)
#pragma unroll
      for (int k = 0; k < 4; ++k) {
        U8u yu;
        yu.v = *(const u16x8*)&yrow[(b + 8 * k) * 8];
        float s = o[k];
        s = __builtin_amdgcn_fdot2_f32_bf16(yu.p[0], au.p[0], s, false);
        s = __builtin_amdgcn_fdot2_f32_bf16(yu.p[1], au.p[1], s, false);
        s = __builtin_amdgcn_fdot2_f32_bf16(yu.p[2], au.p[2], s, false);
        s = __builtin_amdgcn_fdot2_f32_bf16(yu.p[3], au.p[3], s, false);
        o[k] = s;
      }
#else
      float a8[8];
#pragma unroll
      for (int h = 0; h < 8; ++h) a8[h] = b2f(au.v[h]);
#pragma unroll
      for (int k = 0; k < 4; ++k) {
        const u16x8 yv = *(const u16x8*)&yrow[(b + 8 * k) * 8];
#pragma unroll
        for (int h = 0; h < 8; ++h) o[k] += a8[h] * b2f(yv[h]);
      }
#endif
    }
    const size_t gr = (nbase + n) * (size_t)CRED + jbg;
#pragma unroll
    for (int k = 0; k < 4; ++k) gat[gr + b + 8 * k] = f2b(o[k]);
  }
}

// ===== 256x256 R6-schedule restore GEMM: out = relu(bn(gat@w^T)+x) ========
__global__ __launch_bounds__(512, 1) void gemm_res2_kernel(
    const u16* __restrict__ A, const u16* __restrict__ Bt,
    float* __restrict__ out32,
    const float* __restrict__ pg, const float* __restrict__ pb,
    const float* __restrict__ pm, const float* __restrict__ pv,
    const float* __restrict__ auxf)
{
  extern __shared__ u16 lds[];
  const int tid = threadIdx.x;
  const int wave = tid >> 6, lane = tid & 63;
  const int wm = wave >> 2, wn = wave & 3;
  const int l15 = lane & 15, l4 = lane >> 4;

  int lin = blockIdx.y * 4 + blockIdx.x;
  lin = (lin & 7) * 32 + (lin >> 3);
  const int m0 = (lin >> 2) * 256;
  const int n0 = (lin & 3) * 256;

  int offS[2], ldsS[2];
#pragma unroll
  for (int i = 0; i < 2; ++i) {
    const int f = i * 512 + tid;
    const int r = f >> 2;
    const int kb = (f & 3) ^ ((r >> 1) & 3);
    offS[i] = r * 512 + kb * 8;
    ldsS[i] = (i * 512 + wave * 64) * 8;
  }
  const u16* gA = A + (size_t)m0 * 512;
  const u16* gB = Bt + (size_t)n0 * 512;

  auto stageA = [&](int kt) {
    const int bo = (kt & 3) * 16384;
    gload_lds16(gA + kt * 32 + offS[0], &lds[bo + ldsS[0]]);
    gload_lds16(gA + kt * 32 + offS[1], &lds[bo + ldsS[1]]);
  };
  auto stageB = [&](int kt) {
    const int bo = (kt & 3) * 16384 + 8192;
    gload_lds16(gB + kt * 32 + offS[0], &lds[bo + ldsS[0]]);
    gload_lds16(gB + kt * 32 + offS[1], &lds[bo + ldsS[1]]);
  };

  f32x4 acc[8][4];
#pragma unroll
  for (int i = 0; i < 8; ++i)
#pragma unroll
    for (int j = 0; j < 4; ++j) acc[i][j] = f32x4{0.f, 0.f, 0.f, 0.f};

  const int kq = (l4 ^ ((l15 >> 1) & 3)) * 8;
  const int aBase = (wm * 128 + l15) * 32 + kq;
  const int bBase = 8192 + (wn * 64 + l15) * 32 + kq;

  stageA(0); stageB(0); stageA(1); stageB(1);

  for (int kt = 0; kt < 16; ++kt) {
    if (kt == 15) { asm volatile("s_waitcnt vmcnt(0)" ::: "memory"); }
    else         { asm volatile("s_waitcnt vmcnt(4)" ::: "memory"); }
    __builtin_amdgcn_s_barrier();
    const int bo = (kt & 3) * 16384;
    bf16x8 bfr[4], af0[4], af1[4];
#pragma unroll
    for (int f = 0; f < 4; ++f)
      bfr[f] = *(const bf16x8*)&lds[bo + bBase + f * 512];
#pragma unroll
    for (int f = 0; f < 4; ++f)
      af0[f] = *(const bf16x8*)&lds[bo + aBase + f * 512];
#pragma unroll
    for (int f = 0; f < 4; ++f)
      af1[f] = *(const bf16x8*)&lds[bo + aBase + (f + 4) * 512];
    if (kt < 14) { stageA(kt + 2); stageB(kt + 2); }
    __builtin_amdgcn_s_setprio(1);
#pragma unroll
    for (int fm = 0; fm < 4; ++fm)
#pragma unroll
      for (int fn = 0; fn < 4; ++fn)
        acc[fm][fn] = __builtin_amdgcn_mfma_f32_16x16x32_bf16(
            af0[fm], bfr[fn], acc[fm][fn], 0, 0, 0);
#pragma unroll
    for (int fm = 0; fm < 4; ++fm)
#pragma unroll
      for (int fn = 0; fn < 4; ++fn)
        acc[fm + 4][fn] = __builtin_amdgcn_mfma_f32_16x16x32_bf16(
            af1[fm], bfr[fn], acc[fm + 4][fn], 0, 0, 0);
    __builtin_amdgcn_s_setprio(0);
  }

  const int rowb = m0 + wm * 128 + l4 * 4;
#pragma unroll
  for (int fn = 0; fn < 4; ++fn) {
    const int col = n0 + wn * 64 + fn * 16 + l15;
    const float sc = pg[col] * rsqrtf(pv[col] + EPSB);
    const float off = pb[col] - pm[col] * sc;
#pragma unroll
    for (int fm = 0; fm < 8; ++fm) {
      const int row = rowb + fm * 16;
      const int bimg = row >> 8, p0 = row & 255;
      const size_t oa = (size_t)bimg * (COUT * NPIX) + (size_t)col * NPIX + p0;
      const float4 rv = *(const float4*)&auxf[oa];
      float4 ov;
      ov.x = fmaxf(acc[fm][fn][0] * sc + off + rv.x, 0.f);
      ov.y = fmaxf(acc[fm][fn][1] * sc + off + rv.y, 0.f);
      ov.z = fmaxf(acc[fm][fn][2] * sc + off + rv.z, 0.f);
      ov.w = fmaxf(acc[fm][fn][3] * sc + off + rv.w, 0.f);
      *(float4*)&out32[oa] = ov;
    }
  }
}

// ===== WgT2p[j*8+h][k] = bf16(w_gat[k][h*512+j])  (column reorder) =========
__global__ __launch_bounds__(256) void wgatp_kernel(
    const float* __restrict__ w_gat, u16* __restrict__ out)
{
  __shared__ float tile[64][65];
  const int cb = blockIdx.x;
  const int kb = blockIdx.y;
  const int t = threadIdx.x;
  const int jl = t & 7, h = (t >> 3) & 7, k4 = t >> 6;
#pragma unroll
  for (int i = 0; i < 16; ++i) {
    const int kl = k4 * 16 + i;
    tile[kl][jl * 8 + h] =
        w_gat[(size_t)(kb * 64 + kl) * KGAT + h * 512 + cb * 8 + jl];
  }
  __syncthreads();
#pragma unroll
  for (int i = 0; i < 4; ++i) {
    const int idx = i * 256 + t;
    const int cl = idx >> 4;
    const int kq = (idx & 15) * 4;
    u16x4 ov;
#pragma unroll
    for (int q = 0; q < 4; ++q) ov[q] = f2b(tile[kq + q][cl]);
    *(u16x4*)&out[(size_t)(cb * 64 + cl) * CRED + kb * 64 + kq] = ov;
  }
}

// ====== 64x128 FUSED reduce GEMM: xr = relu(bn(x_nchw @ w_reduce^T)) =======
__global__ __launch_bounds__(256, 2) void gemm_redf_kernel(
    const float* __restrict__ x, const u16* __restrict__ Bt,
    u16* __restrict__ out16,
    const float* __restrict__ pg, const float* __restrict__ pb,
    const float* __restrict__ pm, const float* __restrict__ pv)
{
  __shared__ u16 As[64 * 32];
  __shared__ u16 Bs[128 * 32];
  const int tid = threadIdx.x;
  const int wave = tid >> 6, lane = tid & 63;
  const int gx = gridDim.x;
  const int nwg = gx * gridDim.y;
  int lin = blockIdx.y * gx + blockIdx.x;
  lin = (lin & 7) * (nwg >> 3) + (lin >> 3);
  const int m0 = (lin / gx) * 64, n0 = (lin % gx) * 128;
  const int bimg = m0 >> 8, p0 = m0 & 255;

  const float* xsrc = x + (size_t)bimg * CIN * NPIX + p0 + lane;

  int offB[2], dstB[2];
#pragma unroll
  for (int i = 0; i < 2; ++i) {
    const int f = i * 256 + tid;
    const int r = f >> 2;
    const int kb = (f & 3) ^ ((r >> 1) & 3);
    offB[i] = r * CIN + kb * 8;
    dstB[i] = (i * 256 + wave * 64) * 8;
  }
  const u16* gB = Bt + (size_t)n0 * CIN;

  const int aWr = (lane * 4 + (wave ^ ((lane >> 1) & 3))) * 8;

  f32x4 acc[2][4];
#pragma unroll
  for (int i = 0; i < 2; ++i)
#pragma unroll
    for (int j = 0; j < 4; ++j) acc[i][j] = f32x4{0.f, 0.f, 0.f, 0.f};

  const int wr = wave >> 1, wc = wave & 1;
  const int l15 = lane & 15, l4 = lane >> 4;
  const int kq = (l4 ^ ((l15 >> 1) & 3)) * 8;

  float av[8];
#pragma unroll
  for (int j = 0; j < 8; ++j) av[j] = xsrc[(wave * 8 + j) * NPIX];

  for (int kt = 0; kt < CIN; kt += 32) {
    u16x8 pvv;
#pragma unroll
    for (int j = 0; j < 8; ++j) pvv[j] = f2b(av[j]);
    *(u16x8*)&As[aWr] = pvv;
    gload_lds16(gB + kt + offB[0], &Bs[dstB[0]]);
    gload_lds16(gB + kt + offB[1], &Bs[dstB[1]]);
    __syncthreads();
    if (kt + 32 < CIN) {
#pragma unroll
      for (int j = 0; j < 8; ++j)
        av[j] = xsrc[(kt + 32 + wave * 8 + j) * NPIX];
    }
    bf16x8 af[2], bfr[4];
#pragma unroll
    for (int f = 0; f < 2; ++f)
      af[f] = *(const bf16x8*)&As[(wr * 32 + f * 16 + l15) * 32 + kq];
#pragma unroll
    for (int f = 0; f < 4; ++f)
      bfr[f] = *(const bf16x8*)&Bs[(wc * 64 + f * 16 + l15) * 32 + kq];
#pragma unroll
    for (int fm = 0; fm < 2; ++fm)
#pragma unroll
      for (int fn = 0; fn < 4; ++fn)
        acc[fm][fn] = __builtin_amdgcn_mfma_f32_16x16x32_bf16(
            af[fm], bfr[fn], acc[fm][fn], 0, 0, 0);
    __syncthreads();
  }

  const int rowb = m0 + wr * 32 + (lane >> 4) * 4;
#pragma unroll
  for (int fn = 0; fn < 4; ++fn) {
    const int col = n0 + wc * 64 + fn * 16 + l15;
    const float sc = pg[col] * rsqrtf(pv[col] + EPSB);
    const float off = pb[col] - pm[col] * sc;
#pragma unroll
    for (int fm = 0; fm < 2; ++fm) {
      const int row = rowb + fm * 16;
#pragma unroll
      for (int r = 0; r < 4; ++r) {
        const float y = fmaxf(acc[fm][fn][r] * sc + off, 0.f);
        out16[(size_t)(row + r) * CRED + col] = f2b(y);
      }
    }
  }
}

// --------- elementwise fp32 -> bf16 convert, two buffers, one launch -------
__global__ __launch_bounds__(256) void cvt2_kernel(
    const float* __restrict__ s0, u16* __restrict__ d0,
    const float* __restrict__ s1, u16* __restrict__ d1, int half)
{
  const int bi = blockIdx.x;
  const float* src = (bi < half) ? s0 : s1;
  u16* dst = (bi < half) ? d0 : d1;
  const int i = ((bi < half ? bi : bi - half) * 256 + threadIdx.x) * 8;
  const float4 a = *(const float4*)&src[i];
  const float4 b = *(const float4*)&src[i + 4];
  u16x8 o;
  o[0] = f2b(a.x); o[1] = f2b(a.y); o[2] = f2b(a.z); o[3] = f2b(a.w);
  o[4] = f2b(b.x); o[5] = f2b(b.y); o[6] = f2b(b.z); o[7] = f2b(b.w);
  *(u16x8*)&dst[i] = o;
}

// ---------- P[s][h][c] = sum_t w_gat[c][h*512+t] * att_s[h][t] -------------
__global__ __launch_bounds__(128) void attproj_kernel(
    const float* __restrict__ w_gat, const float* __restrict__ att_src,
    const float* __restrict__ att_dst, float* __restrict__ P)
{
  __shared__ float av[CRED];
  const int bi = blockIdx.x;
  const int sh = bi & 15, q = bi >> 4;
  const int s = sh >> 3, h = sh & 7;
  const float* att = (s == 0) ? att_src : att_dst;
  for (int t = threadIdx.x; t < CRED; t += 128) av[t] = att[h * CRED + t];
  __syncthreads();
  const int c = q * 128 + threadIdx.x;
  const float* wrow = w_gat + (size_t)c * KGAT + h * CRED;
  float acc = 0.f;
  for (int j = 0; j < CRED; j += 4) {
    const float4 w = *(const float4*)&wrow[j];
    acc += w.x * av[j] + w.y * av[j + 1] + w.z * av[j + 2] + w.w * av[j + 3];
  }
  P[(size_t)sh * CRED + c] = acc;
}

// ---------- a_all[s][n][h] = xr[n] . P[s][h]   (one wave per node) ---------
__global__ __launch_bounds__(256) void att_kernel(
    const u16* __restrict__ xr, const float* __restrict__ P,
    float* __restrict__ a_all)
{
  const int wave = threadIdx.x >> 6, lane = threadIdx.x & 63;
  const int m = blockIdx.x * 4 + wave;
  const int sh = lane & 15, q = lane >> 4;
  const u16* xp = xr + (size_t)m * CRED + q * 128;
  const float* Pp = P + (size_t)sh * CRED + q * 128;
  float s = 0.f;
#pragma unroll
  for (int c = 0; c < 128; c += 8) {
    u16x8 xv = *(const u16x8*)&xp[c];
#pragma unroll
    for (int t = 0; t < 8; ++t) s += b2f(xv[t]) * Pp[c + t];
  }
  s += __shfl_xor(s, 16);
  s += __shfl_xor(s, 32);
  if (q == 0)
    a_all[(size_t)(sh >> 3) * MTOT * HEADS + (size_t)m * HEADS + (sh & 7)] = s;
}

// ---------------------------------------------------------------------------
extern "C" void kernel_launch(void* const* d_in, const int* in_sizes, int n_in,
                              void* d_out, int out_size, void* d_ws, size_t ws_size,
                              hipStream_t stream)
{
  const float* x         = (const float*)d_in[0];
  const float* w_reduce  = (const float*)d_in[1];
  const float* g_red     = (const float*)d_in[2];
  const float* b_red     = (const float*)d_in[3];
  const float* m_red     = (const float*)d_in[4];
  const float* v_red     = (const float*)d_in[5];
  const float* w_gat     = (const float*)d_in[6];
  const float* att_src   = (const float*)d_in[7];
  const float* att_dst   = (const float*)d_in[8];
  const float* gat_bias  = (const float*)d_in[9];
  const float* w_restore = (const float*)d_in[10];
  const float* g_res     = (const float*)d_in[11];
  const float* b_res     = (const float*)d_in[12];
  const float* m_res     = (const float*)d_in[13];
  const float* v_res     = (const float*)d_in[14];

  constexpr size_t SZ_XR   = (size_t)MTOT * CRED * 2;
  constexpr size_t SZ_GAT  = SZ_XR;
  constexpr size_t SZ_WGT  = (size_t)KGAT * CRED * 2;
  constexpr size_t SZ_WRD  = (size_t)CRED * CIN * 2;
  constexpr size_t SZ_WRS  = (size_t)COUT * CRED * 2;
  constexpr size_t SZ_P    = (size_t)16 * CRED * 4;
  constexpr size_t SZ_AALL = (size_t)2 * MTOT * HEADS * 4;
  char* ws = (char*)d_ws;
  u16*   xr     = (u16*)ws;
  u16*   gat    = (u16*)(ws + SZ_XR);
  u16*   WgT2p  = (u16*)(ws + SZ_XR + SZ_GAT);
  u16*   wred_b = (u16*)(ws + SZ_XR + SZ_GAT + SZ_WGT);
  u16*   wres_b = (u16*)(ws + SZ_XR + SZ_GAT + SZ_WGT + SZ_WRD);
  float* P      = (float*)(ws + SZ_XR + SZ_GAT + SZ_WGT + SZ_WRD + SZ_WRS);
  float* a_all  = (float*)(ws + SZ_XR + SZ_GAT + SZ_WGT + SZ_WRD + SZ_WRS + SZ_P);
  u16*   alf_g  = (u16*)(ws + SZ_XR + SZ_GAT + SZ_WGT + SZ_WRD + SZ_WRS + SZ_P + SZ_AALL);
  float* outp   = (float*)d_out;

  hipFuncSetAttribute((const void*)gemm8p_kernel,
                      hipFuncAttributeMaxDynamicSharedMemorySize, 155648);
  hipFuncSetAttribute((const void*)gemm_res2_kernel,
                      hipFuncAttributeMaxDynamicSharedMemorySize, 131072);

  wgatp_kernel<<<dim3(64, 8), 256, 0, stream>>>(w_gat, WgT2p);
  cvt2_kernel<<<512, 256, 0, stream>>>(
      w_reduce, wred_b, w_restore, wres_b, 256);
  gemm_redf_kernel<<<dim3(4, 256), 256, 0, stream>>>(
      x, wred_b, xr, g_red, b_red, m_red, v_red);
  attproj_kernel<<<64, 128, 0, stream>>>(w_gat, att_src, att_dst, P);
  att_kernel<<<MTOT / 4, 256, 0, stream>>>(xr, P, a_all);
  alphapre_kernel<<<512, 256, 0, stream>>>(a_all, alf_g);
  gemm8p_kernel<<<dim3(16, 64), 512, 155648, stream>>>(
      xr, WgT2p, alf_g, gat_bias, gat);
  gemm_res2_kernel<<<dim3(4, 64), 512, 131072, stream>>>(
      gat, wres_b, outp, g_res, b_res, m_res, v_res, x);
  (void)in_sizes; (void)n_in; (void)out_size; (void)ws_size;
}

// Round 19
// 236.370 us; speedup vs baseline: 3.6110x; 1.0284x over previous
//
#include <hip/hip_runtime.h>

// ---------------------------------------------------------------------------
// GATBottleneck (ALL I/O fp32; compute bf16 MFMA, fp32 accum)
//
//  1. wgatp: WgT2p bf16 [4096][512]; WgT2p[j*8+h][k] = w_gat[k][h*512+j]
//  2. cvt2 : w_reduce + w_restore fp32 -> bf16 (single launch)
//  3. gemm_redf: xr = relu(bn(x_nchw @ w_reduce^T))  [16384][512] bf16
//  4. attproj/att: alpha logits via factored projections       (fp32)
//  5. alphapre: per-(node,head) 5-edge softmax -> alf_g bf16 [16384][40]
//  6. gemmf2 : FUSED Y-projection + GAT stencil, 256x128 tile, acc[4][4],
//              2-deep LDS (48KB) + Ys overlay (68KB) -> 2 BLOCKS/CU so the
//              per-tile vmcnt(0)+barrier drain hides under the sibling
//              block (m114).  Alpha in registers (1 node/thread stencil).
//  7. gemm_res2: out = relu(bn(gat @ w_restore^T) + x) -> fp32 NCHW
// edge_index is the fixed 4-neighbor grid + self loops -> analytic.
// ---------------------------------------------------------------------------

typedef unsigned short u16;
typedef __attribute__((ext_vector_type(4))) unsigned short u16x4;
typedef __attribute__((ext_vector_type(8))) unsigned short u16x8;
typedef __attribute__((ext_vector_type(8))) __bf16 bf16x8;
typedef __attribute__((ext_vector_type(2))) __bf16 bf16x2;
typedef __attribute__((ext_vector_type(4))) float f32x4;

#if defined(__has_builtin)
#if __has_builtin(__builtin_amdgcn_fdot2_f32_bf16)
#define HAVE_DOT2 1
#endif
#endif

#define B_    64
#define CIN   1024
#define CRED  512
#define COUT  1024
#define NPIX  256
#define HEADS 8
#define KGAT  4096
#define MTOT  16384
#define EPSB  1e-5f

__device__ __forceinline__ float b2f(u16 u) {
  union { unsigned u; float f; } c; c.u = ((unsigned)u) << 16; return c.f;
}
__device__ __forceinline__ u16 f2b(float f) {
  union { float f; unsigned u; } c; c.f = f;
  unsigned r = (c.u + 0x7FFFu + ((c.u >> 16) & 1u)) >> 16;
  return (u16)r;
}

__device__ __forceinline__ void gload_lds16(const void* g, void* lds) {
  __builtin_amdgcn_global_load_lds(
      (const __attribute__((address_space(1))) void*)g,
      (__attribute__((address_space(3))) void*)lds, 16, 0, 0);
}

union U8u {
  u16x8 v;
  bf16x2 p[4];
};

// ---- alphapre: alf_g[n][e*8+h] = softmax-alpha (1/8 folded), bf16 ---------
__global__ __launch_bounds__(256) void alphapre_kernel(
    const float* __restrict__ a_all, u16* __restrict__ alf_g)
{
  const int nh = blockIdx.x * 256 + threadIdx.x;   // 0..131071
  const int ng = nh >> 3, h = nh & 7;              // global node, head
  const int n = ng & 255;
  const size_t nbase = (size_t)(ng >> 8) * NPIX;
  const int gi = n >> 4, gj = n & 15;
  int vv[5];
  vv[0] = n;
  vv[1] = (gi > 0)  ? n - 16 : -1;
  vv[2] = (gi < 15) ? n + 16 : -1;
  vv[3] = (gj > 0)  ? n - 1  : -1;
  vv[4] = (gj < 15) ? n + 1  : -1;
  const float* a_src = a_all;
  const float* a_dst = a_all + (size_t)MTOT * HEADS;
  const float ad = a_dst[(nbase + n) * HEADS + h];
  float l[5]; float mx = -1e30f;
#pragma unroll
  for (int e = 0; e < 5; ++e) {
    if (vv[e] >= 0) {
      const float xx = a_src[(nbase + vv[e]) * HEADS + h] + ad;
      l[e] = xx > 0.f ? xx : 0.2f * xx;            // leaky_relu(0.2)
      mx = fmaxf(mx, l[e]);
    } else l[e] = -1e30f;
  }
  float s = 0.f, ee[5];
#pragma unroll
  for (int e = 0; e < 5; ++e) {
    ee[e] = (vv[e] >= 0) ? __expf(l[e] - mx) : 0.f;
    s += ee[e];
  }
  const float inv = 0.125f / s;                    // head-mean folded
#pragma unroll
  for (int e = 0; e < 5; ++e)
    alf_g[(size_t)ng * 40 + e * 8 + h] = f2b(ee[e] * inv);
}

// ===== FUSED 256x128 GEMM + GAT stencil, 2 blocks/CU =======================
// K-loop: BK=32, 16 tiles, 2-deep LDS (A[256][32]@d*12288, B[128][32]@
// d*12288+8192 u16), one vmcnt(0)+barrier per tile (R9-safe ledger: stage
// t+1 targets the buffer whose readers finished before this barrier).
// Operands SWAPPED (node = lane dim).  Epilogue: acc -> Ys[256][136] u16
// (overlays staging) -> per-node stencil: thread owns (n = tid>>1,
// half = tid&1): 8 j-cols, alpha in 5 u16x8 REGS from alf_g, dot2 head-sum.
__global__ __launch_bounds__(512, 4) void gemmf2_kernel(
    const u16* __restrict__ A, const u16* __restrict__ Btp,
    const u16* __restrict__ alf_g, const float* __restrict__ gat_bias,
    u16* __restrict__ gat)
{
  extern __shared__ u16 lds[];
  u16* Ys = lds;                         // [256][136] u16 (overlay)

  const int tid = threadIdx.x;
  const int wave = tid >> 6, lane = tid & 63;
  const int wm = wave >> 1, wn = wave & 1;   // 4M x 2N, wave tile 64x64
  const int l15 = lane & 15, l4 = lane >> 4;

  // grid 2048 = 64 img x 32 ntiles; XCD-chunk: same-img blocks share an XCD
  const int raw = blockIdx.x;
  const int lin = (raw & 7) * 256 + (raw >> 3);
  const int img = lin >> 5;
  const int ntile = lin & 31;
  const int n0 = ntile * 128;            // Y'-col tile base
  const int jbg = ntile * 16;            // gat col base
  const size_t nbase = (size_t)img * NPIX;

  // staging maps (R6 swizzle): A 1024 chunks (2/thread), B 512 (1/thread)
  int offA[2], dstA[2];
#pragma unroll
  for (int i = 0; i < 2; ++i) {
    const int f = i * 512 + tid;
    const int r = f >> 2;
    const int kb = (f & 3) ^ ((r >> 1) & 3);
    offA[i] = r * 512 + kb * 8;
    dstA[i] = (i * 512 + wave * 64) * 8;
  }
  const int rB = tid >> 2;
  const int kbB = (tid & 3) ^ ((rB >> 1) & 3);
  const int offB = rB * 512 + kbB * 8;
  const int dstB = wave * 64 * 8;

  const u16* gA = A + (size_t)img * 256 * 512;
  const u16* gB = Btp + (size_t)n0 * 512;

  auto stage = [&](int t) {
    const int d = (t & 1) * 12288;
    gload_lds16(gA + t * 32 + offA[0], &lds[d + dstA[0]]);
    gload_lds16(gA + t * 32 + offA[1], &lds[d + dstA[1]]);
    gload_lds16(gB + t * 32 + offB, &lds[d + 8192 + dstB]);
  };

  f32x4 acc[4][4];
#pragma unroll
  for (int i = 0; i < 4; ++i)
#pragma unroll
    for (int j = 0; j < 4; ++j) acc[i][j] = f32x4{0.f, 0.f, 0.f, 0.f};

  const int kq = (l4 ^ ((l15 >> 1) & 3)) * 8;
  const int aBase = (wm * 64 + l15) * 32 + kq;
  const int bBase = 8192 + (wn * 64 + l15) * 32 + kq;

  stage(0);

  for (int t = 0; t < 16; ++t) {
    asm volatile("s_waitcnt vmcnt(0)" ::: "memory");
    __builtin_amdgcn_s_barrier();
    const int d = (t & 1) * 12288;
    bf16x8 af[4], bfr[4];
#pragma unroll
    for (int f = 0; f < 4; ++f) {
      af[f]  = *(const bf16x8*)&lds[d + aBase + f * 512];
      bfr[f] = *(const bf16x8*)&lds[d + bBase + f * 512];
    }
    if (t < 15) stage(t + 1);
    __builtin_amdgcn_s_setprio(1);
    // SWAPPED operands: D transposed (node dim = lane&15)
#pragma unroll
    for (int fm = 0; fm < 4; ++fm)
#pragma unroll
      for (int fn = 0; fn < 4; ++fn)
        acc[fm][fn] = __builtin_amdgcn_mfma_f32_16x16x32_bf16(
            bfr[fn], af[fm], acc[fm][fn], 0, 0, 0);
    __builtin_amdgcn_s_setprio(0);
  }
  __syncthreads();   // staging dead; Ys region free

  // ---- acc -> Ys  (node = wm*64+fm*16+l15, col = wn*64+fn*16+l4*4+r) -----
#pragma unroll
  for (int fm = 0; fm < 4; ++fm) {
    const int nloc = wm * 64 + fm * 16 + l15;
#pragma unroll
    for (int fn = 0; fn < 4; ++fn) {
      const int cloc = wn * 64 + fn * 16 + l4 * 4;
      u16x4 ov;
#pragma unroll
      for (int r = 0; r < 4; ++r) ov[r] = f2b(acc[fm][fn][r]);
      *(u16x4*)&Ys[nloc * 136 + cloc] = ov;
    }
  }
  __syncthreads();

  // ---- stencil: thread owns node n = tid>>1, j-cols half*8..half*8+7 -----
  const int n = tid >> 1, half = tid & 1;
  const int gi = n >> 4, gj = n & 15;
  int vv[5];
  vv[0] = n;
  vv[1] = (gi > 0)  ? n - 16 : n;   // invalid -> alpha==0, read self
  vv[2] = (gi < 15) ? n + 16 : n;
  vv[3] = (gj > 0)  ? n - 1  : n;
  vv[4] = (gj < 15) ? n + 1  : n;
  U8u au[5];
  {
    const u16* ag = alf_g + (nbase + n) * 40;
#pragma unroll
    for (int e = 0; e < 5; ++e) au[e].v = *(const u16x8*)&ag[e * 8];
  }
  float o[8];
  {
    const int jb = jbg + half * 8;
    const float4 b0 = *(const float4*)&gat_bias[jb];
    const float4 b1 = *(const float4*)&gat_bias[jb + 4];
    o[0] = b0.x; o[1] = b0.y; o[2] = b0.z; o[3] = b0.w;
    o[4] = b1.x; o[5] = b1.y; o[6] = b1.z; o[7] = b1.w;
  }
#pragma unroll
  for (int e = 0; e < 5; ++e) {
    const u16* yrow = &Ys[vv[e] * 136 + half * 64];
#if defined(HAVE_DOT2)
#pragma unroll
    for (int k = 0; k < 8; ++k) {
      U8u yu;
      yu.v = *(const u16x8*)&yrow[k * 8];
      float s = o[k];
      s = __builtin_amdgcn_fdot2_f32_bf16(yu.p[0], au[e].p[0], s, false);
      s = __builtin_amdgcn_fdot2_f32_bf16(yu.p[1], au[e].p[1], s, false);
      s = __builtin_amdgcn_fdot2_f32_bf16(yu.p[2], au[e].p[2], s, false);
      s = __builtin_amdgcn_fdot2_f32_bf16(yu.p[3], au[e].p[3], s, false);
      o[k] = s;
    }
#else
    float a8[8];
#pragma unroll
    for (int h = 0; h < 8; ++h) a8[h] = b2f(au[e].v[h]);
#pragma unroll
    for (int k = 0; k < 8; ++k) {
      const u16x8 yv = *(const u16x8*)&yrow[k * 8];
#pragma unroll
      for (int h = 0; h < 8; ++h) o[k] += a8[h] * b2f(yv[h]);
    }
#endif
  }
  u16x8 ov;
#pragma unroll
  for (int k = 0; k < 8; ++k) ov[k] = f2b(o[k]);
  *(u16x8*)&gat[(nbase + n) * (size_t)CRED + jbg + half * 8] = ov;
}

// ===== 256x256 R6-schedule restore GEMM: out = relu(bn(gat@w^T)+x) ========
__global__ __launch_bounds__(512, 1) void gemm_res2_kernel(
    const u16* __restrict__ A, const u16* __restrict__ Bt,
    float* __restrict__ out32,
    const float* __restrict__ pg, const float* __restrict__ pb,
    const float* __restrict__ pm, const float* __restrict__ pv,
    const float* __restrict__ auxf)
{
  extern __shared__ u16 lds[];
  const int tid = threadIdx.x;
  const int wave = tid >> 6, lane = tid & 63;
  const int wm = wave >> 2, wn = wave & 3;
  const int l15 = lane & 15, l4 = lane >> 4;

  int lin = blockIdx.y * 4 + blockIdx.x;
  lin = (lin & 7) * 32 + (lin >> 3);
  const int m0 = (lin >> 2) * 256;
  const int n0 = (lin & 3) * 256;

  int offS[2], ldsS[2];
#pragma unroll
  for (int i = 0; i < 2; ++i) {
    const int f = i * 512 + tid;
    const int r = f >> 2;
    const int kb = (f & 3) ^ ((r >> 1) & 3);
    offS[i] = r * 512 + kb * 8;
    ldsS[i] = (i * 512 + wave * 64) * 8;
  }
  const u16* gA = A + (size_t)m0 * 512;
  const u16* gB = Bt + (size_t)n0 * 512;

  auto stageA = [&](int kt) {
    const int bo = (kt & 3) * 16384;
    gload_lds16(gA + kt * 32 + offS[0], &lds[bo + ldsS[0]]);
    gload_lds16(gA + kt * 32 + offS[1], &lds[bo + ldsS[1]]);
  };
  auto stageB = [&](int kt) {
    const int bo = (kt & 3) * 16384 + 8192;
    gload_lds16(gB + kt * 32 + offS[0], &lds[bo + ldsS[0]]);
    gload_lds16(gB + kt * 32 + offS[1], &lds[bo + ldsS[1]]);
  };

  f32x4 acc[8][4];
#pragma unroll
  for (int i = 0; i < 8; ++i)
#pragma unroll
    for (int j = 0; j < 4; ++j) acc[i][j] = f32x4{0.f, 0.f, 0.f, 0.f};

  const int kq = (l4 ^ ((l15 >> 1) & 3)) * 8;
  const int aBase = (wm * 128 + l15) * 32 + kq;
  const int bBase = 8192 + (wn * 64 + l15) * 32 + kq;

  stageA(0); stageB(0); stageA(1); stageB(1);

  for (int kt = 0; kt < 16; ++kt) {
    if (kt == 15) { asm volatile("s_waitcnt vmcnt(0)" ::: "memory"); }
    else         { asm volatile("s_waitcnt vmcnt(4)" ::: "memory"); }
    __builtin_amdgcn_s_barrier();
    const int bo = (kt & 3) * 16384;
    bf16x8 bfr[4], af0[4], af1[4];
#pragma unroll
    for (int f = 0; f < 4; ++f)
      bfr[f] = *(const bf16x8*)&lds[bo + bBase + f * 512];
#pragma unroll
    for (int f = 0; f < 4; ++f)
      af0[f] = *(const bf16x8*)&lds[bo + aBase + f * 512];
#pragma unroll
    for (int f = 0; f < 4; ++f)
      af1[f] = *(const bf16x8*)&lds[bo + aBase + (f + 4) * 512];
    if (kt < 14) { stageA(kt + 2); stageB(kt + 2); }
    __builtin_amdgcn_s_setprio(1);
#pragma unroll
    for (int fm = 0; fm < 4; ++fm)
#pragma unroll
      for (int fn = 0; fn < 4; ++fn)
        acc[fm][fn] = __builtin_amdgcn_mfma_f32_16x16x32_bf16(
            af0[fm], bfr[fn], acc[fm][fn], 0, 0, 0);
#pragma unroll
    for (int fm = 0; fm < 4; ++fm)
#pragma unroll
      for (int fn = 0; fn < 4; ++fn)
        acc[fm + 4][fn] = __builtin_amdgcn_mfma_f32_16x16x32_bf16(
            af1[fm], bfr[fn], acc[fm + 4][fn], 0, 0, 0);
    __builtin_amdgcn_s_setprio(0);
  }

  const int rowb = m0 + wm * 128 + l4 * 4;
#pragma unroll
  for (int fn = 0; fn < 4; ++fn) {
    const int col = n0 + wn * 64 + fn * 16 + l15;
    const float sc = pg[col] * rsqrtf(pv[col] + EPSB);
    const float off = pb[col] - pm[col] * sc;
#pragma unroll
    for (int fm = 0; fm < 8; ++fm) {
      const int row = rowb + fm * 16;
      const int bimg = row >> 8, p0 = row & 255;
      const size_t oa = (size_t)bimg * (COUT * NPIX) + (size_t)col * NPIX + p0;
      const float4 rv = *(const float4*)&auxf[oa];
      float4 ov;
      ov.x = fmaxf(acc[fm][fn][0] * sc + off + rv.x, 0.f);
      ov.y = fmaxf(acc[fm][fn][1] * sc + off + rv.y, 0.f);
      ov.z = fmaxf(acc[fm][fn][2] * sc + off + rv.z, 0.f);
      ov.w = fmaxf(acc[fm][fn][3] * sc + off + rv.w, 0.f);
      *(float4*)&out32[oa] = ov;
    }
  }
}

// ===== WgT2p[j*8+h][k] = bf16(w_gat[k][h*512+j])  (column reorder) =========
__global__ __launch_bounds__(256) void wgatp_kernel(
    const float* __restrict__ w_gat, u16* __restrict__ out)
{
  __shared__ float tile[64][65];
  const int cb = blockIdx.x;
  const int kb = blockIdx.y;
  const int t = threadIdx.x;
  const int jl = t & 7, h = (t >> 3) & 7, k4 = t >> 6;
#pragma unroll
  for (int i = 0; i < 16; ++i) {
    const int kl = k4 * 16 + i;
    tile[kl][jl * 8 + h] =
        w_gat[(size_t)(kb * 64 + kl) * KGAT + h * 512 + cb * 8 + jl];
  }
  __syncthreads();
#pragma unroll
  for (int i = 0; i < 4; ++i) {
    const int idx = i * 256 + t;
    const int cl = idx >> 4;
    const int kq = (idx & 15) * 4;
    u16x4 ov;
#pragma unroll
    for (int q = 0; q < 4; ++q) ov[q] = f2b(tile[kq + q][cl]);
    *(u16x4*)&out[(size_t)(cb * 64 + cl) * CRED + kb * 64 + kq] = ov;
  }
}

// ====== 64x128 FUSED reduce GEMM: xr = relu(bn(x_nchw @ w_reduce^T)) =======
__global__ __launch_bounds__(256, 2) void gemm_redf_kernel(
    const float* __restrict__ x, const u16* __restrict__ Bt,
    u16* __restrict__ out16,
    const float* __restrict__ pg, const float* __restrict__ pb,
    const float* __restrict__ pm, const float* __restrict__ pv)
{
  __shared__ u16 As[64 * 32];
  __shared__ u16 Bs[128 * 32];
  const int tid = threadIdx.x;
  const int wave = tid >> 6, lane = tid & 63;
  const int gx = gridDim.x;
  const int nwg = gx * gridDim.y;
  int lin = blockIdx.y * gx + blockIdx.x;
  lin = (lin & 7) * (nwg >> 3) + (lin >> 3);
  const int m0 = (lin / gx) * 64, n0 = (lin % gx) * 128;
  const int bimg = m0 >> 8, p0 = m0 & 255;

  const float* xsrc = x + (size_t)bimg * CIN * NPIX + p0 + lane;

  int offB[2], dstB[2];
#pragma unroll
  for (int i = 0; i < 2; ++i) {
    const int f = i * 256 + tid;
    const int r = f >> 2;
    const int kb = (f & 3) ^ ((r >> 1) & 3);
    offB[i] = r * CIN + kb * 8;
    dstB[i] = (i * 256 + wave * 64) * 8;
  }
  const u16* gB = Bt + (size_t)n0 * CIN;

  const int aWr = (lane * 4 + (wave ^ ((lane >> 1) & 3))) * 8;

  f32x4 acc[2][4];
#pragma unroll
  for (int i = 0; i < 2; ++i)
#pragma unroll
    for (int j = 0; j < 4; ++j) acc[i][j] = f32x4{0.f, 0.f, 0.f, 0.f};

  const int wr = wave >> 1, wc = wave & 1;
  const int l15 = lane & 15, l4 = lane >> 4;
  const int kq = (l4 ^ ((l15 >> 1) & 3)) * 8;

  float av[8];
#pragma unroll
  for (int j = 0; j < 8; ++j) av[j] = xsrc[(wave * 8 + j) * NPIX];

  for (int kt = 0; kt < CIN; kt += 32) {
    u16x8 pvv;
#pragma unroll
    for (int j = 0; j < 8; ++j) pvv[j] = f2b(av[j]);
    *(u16x8*)&As[aWr] = pvv;
    gload_lds16(gB + kt + offB[0], &Bs[dstB[0]]);
    gload_lds16(gB + kt + offB[1], &Bs[dstB[1]]);
    __syncthreads();
    if (kt + 32 < CIN) {
#pragma unroll
      for (int j = 0; j < 8; ++j)
        av[j] = xsrc[(kt + 32 + wave * 8 + j) * NPIX];
    }
    bf16x8 af[2], bfr[4];
#pragma unroll
    for (int f = 0; f < 2; ++f)
      af[f] = *(const bf16x8*)&As[(wr * 32 + f * 16 + l15) * 32 + kq];
#pragma unroll
    for (int f = 0; f < 4; ++f)
      bfr[f] = *(const bf16x8*)&Bs[(wc * 64 + f * 16 + l15) * 32 + kq];
#pragma unroll
    for (int fm = 0; fm < 2; ++fm)
#pragma unroll
      for (int fn = 0; fn < 4; ++fn)
        acc[fm][fn] = __builtin_amdgcn_mfma_f32_16x16x32_bf16(
            af[fm], bfr[fn], acc[fm][fn], 0, 0, 0);
    __syncthreads();
  }

  const int rowb = m0 + wr * 32 + (lane >> 4) * 4;
#pragma unroll
  for (int fn = 0; fn < 4; ++fn) {
    const int col = n0 + wc * 64 + fn * 16 + l15;
    const float sc = pg[col] * rsqrtf(pv[col] + EPSB);
    const float off = pb[col] - pm[col] * sc;
#pragma unroll
    for (int fm = 0; fm < 2; ++fm) {
      const int row = rowb + fm * 16;
#pragma unroll
      for (int r = 0; r < 4; ++r) {
        const float y = fmaxf(acc[fm][fn][r] * sc + off, 0.f);
        out16[(size_t)(row + r) * CRED + col] = f2b(y);
      }
    }
  }
}

// --------- elementwise fp32 -> bf16 convert, two buffers, one launch -------
__global__ __launch_bounds__(256) void cvt2_kernel(
    const float* __restrict__ s0, u16* __restrict__ d0,
    const float* __restrict__ s1, u16* __restrict__ d1, int half)
{
  const int bi = blockIdx.x;
  const float* src = (bi < half) ? s0 : s1;
  u16* dst = (bi < half) ? d0 : d1;
  const int i = ((bi < half ? bi : bi - half) * 256 + threadIdx.x) * 8;
  const float4 a = *(const float4*)&src[i];
  const float4 b = *(const float4*)&src[i + 4];
  u16x8 o;
  o[0] = f2b(a.x); o[1] = f2b(a.y); o[2] = f2b(a.z); o[3] = f2b(a.w);
  o[4] = f2b(b.x); o[5] = f2b(b.y); o[6] = f2b(b.z); o[7] = f2b(b.w);
  *(u16x8*)&dst[i] = o;
}

// ---------- P[s][h][c] = sum_t w_gat[c][h*512+t] * att_s[h][t] -------------
__global__ __launch_bounds__(128) void attproj_kernel(
    const float* __restrict__ w_gat, const float* __restrict__ att_src,
    const float* __restrict__ att_dst, float* __restrict__ P)
{
  __shared__ float av[CRED];
  const int bi = blockIdx.x;
  const int sh = bi & 15, q = bi >> 4;
  const int s = sh >> 3, h = sh & 7;
  const float* att = (s == 0) ? att_src : att_dst;
  for (int t = threadIdx.x; t < CRED; t += 128) av[t] = att[h * CRED + t];
  __syncthreads();
  const int c = q * 128 + threadIdx.x;
  const float* wrow = w_gat + (size_t)c * KGAT + h * CRED;
  float acc = 0.f;
  for (int j = 0; j < CRED; j += 4) {
    const float4 w = *(const float4*)&wrow[j];
    acc += w.x * av[j] + w.y * av[j + 1] + w.z * av[j + 2] + w.w * av[j + 3];
  }
  P[(size_t)sh * CRED + c] = acc;
}

// ---------- a_all[s][n][h] = xr[n] . P[s][h]   (one wave per node) ---------
__global__ __launch_bounds__(256) void att_kernel(
    const u16* __restrict__ xr, const float* __restrict__ P,
    float* __restrict__ a_all)
{
  const int wave = threadIdx.x >> 6, lane = threadIdx.x & 63;
  const int m = blockIdx.x * 4 + wave;
  const int sh = lane & 15, q = lane >> 4;
  const u16* xp = xr + (size_t)m * CRED + q * 128;
  const float* Pp = P + (size_t)sh * CRED + q * 128;
  float s = 0.f;
#pragma unroll
  for (int c = 0; c < 128; c += 8) {
    u16x8 xv = *(const u16x8*)&xp[c];
#pragma unroll
    for (int t = 0; t < 8; ++t) s += b2f(xv[t]) * Pp[c + t];
  }
  s += __shfl_xor(s, 16);
  s += __shfl_xor(s, 32);
  if (q == 0)
    a_all[(size_t)(sh >> 3) * MTOT * HEADS + (size_t)m * HEADS + (sh & 7)] = s;
}

// ---------------------------------------------------------------------------
extern "C" void kernel_launch(void* const* d_in, const int* in_sizes, int n_in,
                              void* d_out, int out_size, void* d_ws, size_t ws_size,
                              hipStream_t stream)
{
  const float* x         = (const float*)d_in[0];
  const float* w_reduce  = (const float*)d_in[1];
  const float* g_red     = (const float*)d_in[2];
  const float* b_red     = (const float*)d_in[3];
  const float* m_red     = (const float*)d_in[4];
  const float* v_red     = (const float*)d_in[5];
  const float* w_gat     = (const float*)d_in[6];
  const float* att_src   = (const float*)d_in[7];
  const float* att_dst   = (const float*)d_in[8];
  const float* gat_bias  = (const float*)d_in[9];
  const float* w_restore = (const float*)d_in[10];
  const float* g_res     = (const float*)d_in[11];
  const float* b_res     = (const float*)d_in[12];
  const float* m_res     = (const float*)d_in[13];
  const float* v_res     = (const float*)d_in[14];

  constexpr size_t SZ_XR   = (size_t)MTOT * CRED * 2;
  constexpr size_t SZ_GAT  = SZ_XR;
  constexpr size_t SZ_WGT  = (size_t)KGAT * CRED * 2;
  constexpr size_t SZ_WRD  = (size_t)CRED * CIN * 2;
  constexpr size_t SZ_WRS  = (size_t)COUT * CRED * 2;
  constexpr size_t SZ_P    = (size_t)16 * CRED * 4;
  constexpr size_t SZ_AALL = (size_t)2 * MTOT * HEADS * 4;
  char* ws = (char*)d_ws;
  u16*   xr     = (u16*)ws;
  u16*   gat    = (u16*)(ws + SZ_XR);
  u16*   WgT2p  = (u16*)(ws + SZ_XR + SZ_GAT);
  u16*   wred_b = (u16*)(ws + SZ_XR + SZ_GAT + SZ_WGT);
  u16*   wres_b = (u16*)(ws + SZ_XR + SZ_GAT + SZ_WGT + SZ_WRD);
  float* P      = (float*)(ws + SZ_XR + SZ_GAT + SZ_WGT + SZ_WRD + SZ_WRS);
  float* a_all  = (float*)(ws + SZ_XR + SZ_GAT + SZ_WGT + SZ_WRD + SZ_WRS + SZ_P);
  u16*   alf_g  = (u16*)(ws + SZ_XR + SZ_GAT + SZ_WGT + SZ_WRD + SZ_WRS + SZ_P + SZ_AALL);
  float* outp   = (float*)d_out;

  hipFuncSetAttribute((const void*)gemmf2_kernel,
                      hipFuncAttributeMaxDynamicSharedMemorySize, 69632);
  hipFuncSetAttribute((const void*)gemm_res2_kernel,
                      hipFuncAttributeMaxDynamicSharedMemorySize, 131072);

  wgatp_kernel<<<dim3(64, 8), 256, 0, stream>>>(w_gat, WgT2p);
  cvt2_kernel<<<512, 256, 0, stream>>>(
      w_reduce, wred_b, w_restore, wres_b, 256);
  gemm_redf_kernel<<<dim3(4, 256), 256, 0, stream>>>(
      x, wred_b, xr, g_red, b_red, m_red, v_red);
  attproj_kernel<<<64, 128, 0, stream>>>(w_gat, att_src, att_dst, P);
  att_kernel<<<MTOT / 4, 256, 0, stream>>>(xr, P, a_all);
  alphapre_kernel<<<512, 256, 0, stream>>>(a_all, alf_g);
  gemmf2_kernel<<<2048, 512, 69632, stream>>>(
      xr, WgT2p, alf_g, gat_bias, gat);
  gemm_res2_kernel<<<dim3(4, 64), 512, 131072, stream>>>(
      gat, wres_b, outp, g_res, b_res, m_res, v_res, x);
  (void)in_sizes; (void)n_in; (void)out_size; (void)ws_size;
}

// Round 20
// 234.741 us; speedup vs baseline: 3.6361x; 1.0069x over previous
//
#include <hip/hip_runtime.h>

// ---------------------------------------------------------------------------
// GATBottleneck (ALL I/O fp32; compute bf16 MFMA, fp32 accum)
//
//  1. wgatp: WgT2p bf16 [4096][512]; WgT2p[j*8+h][k] = w_gat[k][h*512+j]
//  2. cvt2 : w_reduce + w_restore fp32 -> bf16 (single launch)
//  3. gemm_redf: xr = relu(bn(x_nchw @ w_reduce^T))  [16384][512] bf16
//  4. attproj/att: alpha logits via factored projections       (fp32)
//  5. alphapre: per-(node,head) 5-edge softmax -> alf_g bf16 [16384][40]
//  6. gemmf2 : FUSED Y-projection + GAT stencil, 256x128, 2 blocks/CU
//              (R19-verified: occupancy 41%, 83us)
//  7. gemm_res3: out = relu(bn(gat @ w_restore^T) + x) -> fp32 NCHW
//              NOW 256x128 / acc[4][4] / 2-deep LDS (48KB) -> 3 blocks/CU
//              (same R19 recipe; was 256^2 @ 1 block/CU)
// edge_index is the fixed 4-neighbor grid + self loops -> analytic.
// ---------------------------------------------------------------------------

typedef unsigned short u16;
typedef __attribute__((ext_vector_type(4))) unsigned short u16x4;
typedef __attribute__((ext_vector_type(8))) unsigned short u16x8;
typedef __attribute__((ext_vector_type(8))) __bf16 bf16x8;
typedef __attribute__((ext_vector_type(2))) __bf16 bf16x2;
typedef __attribute__((ext_vector_type(4))) float f32x4;

#if defined(__has_builtin)
#if __has_builtin(__builtin_amdgcn_fdot2_f32_bf16)
#define HAVE_DOT2 1
#endif
#endif

#define B_    64
#define CIN   1024
#define CRED  512
#define COUT  1024
#define NPIX  256
#define HEADS 8
#define KGAT  4096
#define MTOT  16384
#define EPSB  1e-5f

__device__ __forceinline__ float b2f(u16 u) {
  union { unsigned u; float f; } c; c.u = ((unsigned)u) << 16; return c.f;
}
__device__ __forceinline__ u16 f2b(float f) {
  union { float f; unsigned u; } c; c.f = f;
  unsigned r = (c.u + 0x7FFFu + ((c.u >> 16) & 1u)) >> 16;
  return (u16)r;
}

__device__ __forceinline__ void gload_lds16(const void* g, void* lds) {
  __builtin_amdgcn_global_load_lds(
      (const __attribute__((address_space(1))) void*)g,
      (__attribute__((address_space(3))) void*)lds, 16, 0, 0);
}

union U8u {
  u16x8 v;
  bf16x2 p[4];
};

// ---- alphapre: alf_g[n][e*8+h] = softmax-alpha (1/8 folded), bf16 ---------
__global__ __launch_bounds__(256) void alphapre_kernel(
    const float* __restrict__ a_all, u16* __restrict__ alf_g)
{
  const int nh = blockIdx.x * 256 + threadIdx.x;   // 0..131071
  const int ng = nh >> 3, h = nh & 7;              // global node, head
  const int n = ng & 255;
  const size_t nbase = (size_t)(ng >> 8) * NPIX;
  const int gi = n >> 4, gj = n & 15;
  int vv[5];
  vv[0] = n;
  vv[1] = (gi > 0)  ? n - 16 : -1;
  vv[2] = (gi < 15) ? n + 16 : -1;
  vv[3] = (gj > 0)  ? n - 1  : -1;
  vv[4] = (gj < 15) ? n + 1  : -1;
  const float* a_src = a_all;
  const float* a_dst = a_all + (size_t)MTOT * HEADS;
  const float ad = a_dst[(nbase + n) * HEADS + h];
  float l[5]; float mx = -1e30f;
#pragma unroll
  for (int e = 0; e < 5; ++e) {
    if (vv[e] >= 0) {
      const float xx = a_src[(nbase + vv[e]) * HEADS + h] + ad;
      l[e] = xx > 0.f ? xx : 0.2f * xx;            // leaky_relu(0.2)
      mx = fmaxf(mx, l[e]);
    } else l[e] = -1e30f;
  }
  float s = 0.f, ee[5];
#pragma unroll
  for (int e = 0; e < 5; ++e) {
    ee[e] = (vv[e] >= 0) ? __expf(l[e] - mx) : 0.f;
    s += ee[e];
  }
  const float inv = 0.125f / s;                    // head-mean folded
#pragma unroll
  for (int e = 0; e < 5; ++e)
    alf_g[(size_t)ng * 40 + e * 8 + h] = f2b(ee[e] * inv);
}

// ===== FUSED 256x128 GEMM + GAT stencil, 2 blocks/CU (R19-verified) ========
__global__ __launch_bounds__(512, 4) void gemmf2_kernel(
    const u16* __restrict__ A, const u16* __restrict__ Btp,
    const u16* __restrict__ alf_g, const float* __restrict__ gat_bias,
    u16* __restrict__ gat)
{
  extern __shared__ u16 lds[];
  u16* Ys = lds;                         // [256][136] u16 (overlay)

  const int tid = threadIdx.x;
  const int wave = tid >> 6, lane = tid & 63;
  const int wm = wave >> 1, wn = wave & 1;   // 4M x 2N, wave tile 64x64
  const int l15 = lane & 15, l4 = lane >> 4;

  const int raw = blockIdx.x;
  const int lin = (raw & 7) * 256 + (raw >> 3);
  const int img = lin >> 5;
  const int ntile = lin & 31;
  const int n0 = ntile * 128;
  const int jbg = ntile * 16;
  const size_t nbase = (size_t)img * NPIX;

  int offA[2], dstA[2];
#pragma unroll
  for (int i = 0; i < 2; ++i) {
    const int f = i * 512 + tid;
    const int r = f >> 2;
    const int kb = (f & 3) ^ ((r >> 1) & 3);
    offA[i] = r * 512 + kb * 8;
    dstA[i] = (i * 512 + wave * 64) * 8;
  }
  const int rB = tid >> 2;
  const int kbB = (tid & 3) ^ ((rB >> 1) & 3);
  const int offB = rB * 512 + kbB * 8;
  const int dstB = wave * 64 * 8;

  const u16* gA = A + (size_t)img * 256 * 512;
  const u16* gB = Btp + (size_t)n0 * 512;

  auto stage = [&](int t) {
    const int d = (t & 1) * 12288;
    gload_lds16(gA + t * 32 + offA[0], &lds[d + dstA[0]]);
    gload_lds16(gA + t * 32 + offA[1], &lds[d + dstA[1]]);
    gload_lds16(gB + t * 32 + offB, &lds[d + 8192 + dstB]);
  };

  f32x4 acc[4][4];
#pragma unroll
  for (int i = 0; i < 4; ++i)
#pragma unroll
    for (int j = 0; j < 4; ++j) acc[i][j] = f32x4{0.f, 0.f, 0.f, 0.f};

  const int kq = (l4 ^ ((l15 >> 1) & 3)) * 8;
  const int aBase = (wm * 64 + l15) * 32 + kq;
  const int bBase = 8192 + (wn * 64 + l15) * 32 + kq;

  stage(0);

  for (int t = 0; t < 16; ++t) {
    asm volatile("s_waitcnt vmcnt(0)" ::: "memory");
    __builtin_amdgcn_s_barrier();
    const int d = (t & 1) * 12288;
    bf16x8 af[4], bfr[4];
#pragma unroll
    for (int f = 0; f < 4; ++f) {
      af[f]  = *(const bf16x8*)&lds[d + aBase + f * 512];
      bfr[f] = *(const bf16x8*)&lds[d + bBase + f * 512];
    }
    if (t < 15) stage(t + 1);
    __builtin_amdgcn_s_setprio(1);
#pragma unroll
    for (int fm = 0; fm < 4; ++fm)
#pragma unroll
      for (int fn = 0; fn < 4; ++fn)
        acc[fm][fn] = __builtin_amdgcn_mfma_f32_16x16x32_bf16(
            bfr[fn], af[fm], acc[fm][fn], 0, 0, 0);
    __builtin_amdgcn_s_setprio(0);
  }
  __syncthreads();

#pragma unroll
  for (int fm = 0; fm < 4; ++fm) {
    const int nloc = wm * 64 + fm * 16 + l15;
#pragma unroll
    for (int fn = 0; fn < 4; ++fn) {
      const int cloc = wn * 64 + fn * 16 + l4 * 4;
      u16x4 ov;
#pragma unroll
      for (int r = 0; r < 4; ++r) ov[r] = f2b(acc[fm][fn][r]);
      *(u16x4*)&Ys[nloc * 136 + cloc] = ov;
    }
  }
  __syncthreads();

  const int n = tid >> 1, half = tid & 1;
  const int gi = n >> 4, gj = n & 15;
  int vv[5];
  vv[0] = n;
  vv[1] = (gi > 0)  ? n - 16 : n;
  vv[2] = (gi < 15) ? n + 16 : n;
  vv[3] = (gj > 0)  ? n - 1  : n;
  vv[4] = (gj < 15) ? n + 1  : n;
  U8u au[5];
  {
    const u16* ag = alf_g + (nbase + n) * 40;
#pragma unroll
    for (int e = 0; e < 5; ++e) au[e].v = *(const u16x8*)&ag[e * 8];
  }
  float o[8];
  {
    const int jb = jbg + half * 8;
    const float4 b0 = *(const float4*)&gat_bias[jb];
    const float4 b1 = *(const float4*)&gat_bias[jb + 4];
    o[0] = b0.x; o[1] = b0.y; o[2] = b0.z; o[3] = b0.w;
    o[4] = b1.x; o[5] = b1.y; o[6] = b1.z; o[7] = b1.w;
  }
#pragma unroll
  for (int e = 0; e < 5; ++e) {
    const u16* yrow = &Ys[vv[e] * 136 + half * 64];
#if defined(HAVE_DOT2)
#pragma unroll
    for (int k = 0; k < 8; ++k) {
      U8u yu;
      yu.v = *(const u16x8*)&yrow[k * 8];
      float s = o[k];
      s = __builtin_amdgcn_fdot2_f32_bf16(yu.p[0], au[e].p[0], s, false);
      s = __builtin_amdgcn_fdot2_f32_bf16(yu.p[1], au[e].p[1], s, false);
      s = __builtin_amdgcn_fdot2_f32_bf16(yu.p[2], au[e].p[2], s, false);
      s = __builtin_amdgcn_fdot2_f32_bf16(yu.p[3], au[e].p[3], s, false);
      o[k] = s;
    }
#else
    float a8[8];
#pragma unroll
    for (int h = 0; h < 8; ++h) a8[h] = b2f(au[e].v[h]);
#pragma unroll
    for (int k = 0; k < 8; ++k) {
      const u16x8 yv = *(const u16x8*)&yrow[k * 8];
#pragma unroll
      for (int h = 0; h < 8; ++h) o[k] += a8[h] * b2f(yv[h]);
    }
#endif
  }
  u16x8 ov;
#pragma unroll
  for (int k = 0; k < 8; ++k) ov[k] = f2b(o[k]);
  *(u16x8*)&gat[(nbase + n) * (size_t)CRED + jbg + half * 8] = ov;
}

// ===== 256x128 restore GEMM, 2-deep LDS, 3 blocks/CU (R19 recipe) ==========
// out = relu(bn(gat @ w_restore^T) + x) -> fp32 NCHW.  8 waves (4M x 2N),
// acc[4][4], NORMAL operand order -> reg r = 4 consecutive pixels.
__global__ __launch_bounds__(512, 4) void gemm_res3_kernel(
    const u16* __restrict__ A, const u16* __restrict__ Bt,
    float* __restrict__ out32,
    const float* __restrict__ pg, const float* __restrict__ pb,
    const float* __restrict__ pm, const float* __restrict__ pv,
    const float* __restrict__ auxf)
{
  extern __shared__ u16 lds[];
  const int tid = threadIdx.x;
  const int wave = tid >> 6, lane = tid & 63;
  const int wm = wave >> 1, wn = wave & 1;   // 4M x 2N, wave tile 64x64
  const int l15 = lane & 15, l4 = lane >> 4;

  // grid 512 = 64 m-tiles x 8 n-tiles, XCD-chunked
  const int raw = blockIdx.x;
  const int lin = (raw & 7) * 64 + (raw >> 3);
  const int m0 = (lin >> 3) * 256;
  const int n0 = (lin & 7) * 128;

  int offA[2], dstA[2];
#pragma unroll
  for (int i = 0; i < 2; ++i) {
    const int f = i * 512 + tid;
    const int r = f >> 2;
    const int kb = (f & 3) ^ ((r >> 1) & 3);
    offA[i] = r * 512 + kb * 8;
    dstA[i] = (i * 512 + wave * 64) * 8;
  }
  const int rB = tid >> 2;
  const int kbB = (tid & 3) ^ ((rB >> 1) & 3);
  const int offB = rB * 512 + kbB * 8;
  const int dstB = wave * 64 * 8;

  const u16* gA = A + (size_t)m0 * 512;
  const u16* gB = Bt + (size_t)n0 * 512;

  auto stage = [&](int t) {
    const int d = (t & 1) * 12288;
    gload_lds16(gA + t * 32 + offA[0], &lds[d + dstA[0]]);
    gload_lds16(gA + t * 32 + offA[1], &lds[d + dstA[1]]);
    gload_lds16(gB + t * 32 + offB, &lds[d + 8192 + dstB]);
  };

  f32x4 acc[4][4];
#pragma unroll
  for (int i = 0; i < 4; ++i)
#pragma unroll
    for (int j = 0; j < 4; ++j) acc[i][j] = f32x4{0.f, 0.f, 0.f, 0.f};

  const int kq = (l4 ^ ((l15 >> 1) & 3)) * 8;
  const int aBase = (wm * 64 + l15) * 32 + kq;
  const int bBase = 8192 + (wn * 64 + l15) * 32 + kq;

  stage(0);

  for (int t = 0; t < 16; ++t) {
    asm volatile("s_waitcnt vmcnt(0)" ::: "memory");
    __builtin_amdgcn_s_barrier();
    const int d = (t & 1) * 12288;
    bf16x8 af[4], bfr[4];
#pragma unroll
    for (int f = 0; f < 4; ++f) {
      af[f]  = *(const bf16x8*)&lds[d + aBase + f * 512];
      bfr[f] = *(const bf16x8*)&lds[d + bBase + f * 512];
    }
    if (t < 15) stage(t + 1);
    __builtin_amdgcn_s_setprio(1);
    // NORMAL order: row dim from A-frag, reg r = 4 consecutive rows (pixels)
#pragma unroll
    for (int fm = 0; fm < 4; ++fm)
#pragma unroll
      for (int fn = 0; fn < 4; ++fn)
        acc[fm][fn] = __builtin_amdgcn_mfma_f32_16x16x32_bf16(
            af[fm], bfr[fn], acc[fm][fn], 0, 0, 0);
    __builtin_amdgcn_s_setprio(0);
  }

  // epilogue: row = m0 + wm*64 + fm*16 + l4*4 + r; col = n0 + wn*64 + fn*16 + l15
  const int rowb = m0 + wm * 64 + l4 * 4;
#pragma unroll
  for (int fn = 0; fn < 4; ++fn) {
    const int col = n0 + wn * 64 + fn * 16 + l15;
    const float sc = pg[col] * rsqrtf(pv[col] + EPSB);
    const float off = pb[col] - pm[col] * sc;
#pragma unroll
    for (int fm = 0; fm < 4; ++fm) {
      const int row = rowb + fm * 16;
      const int bimg = row >> 8, p0 = row & 255;
      const size_t oa = (size_t)bimg * (COUT * NPIX) + (size_t)col * NPIX + p0;
      const float4 rv = *(const float4*)&auxf[oa];
      float4 ov;
      ov.x = fmaxf(acc[fm][fn][0] * sc + off + rv.x, 0.f);
      ov.y = fmaxf(acc[fm][fn][1] * sc + off + rv.y, 0.f);
      ov.z = fmaxf(acc[fm][fn][2] * sc + off + rv.z, 0.f);
      ov.w = fmaxf(acc[fm][fn][3] * sc + off + rv.w, 0.f);
      *(float4*)&out32[oa] = ov;
    }
  }
}

// ===== WgT2p[j*8+h][k] = bf16(w_gat[k][h*512+j])  (column reorder) =========
__global__ __launch_bounds__(256) void wgatp_kernel(
    const float* __restrict__ w_gat, u16* __restrict__ out)
{
  __shared__ float tile[64][65];
  const int cb = blockIdx.x;
  const int kb = blockIdx.y;
  const int t = threadIdx.x;
  const int jl = t & 7, h = (t >> 3) & 7, k4 = t >> 6;
#pragma unroll
  for (int i = 0; i < 16; ++i) {
    const int kl = k4 * 16 + i;
    tile[kl][jl * 8 + h] =
        w_gat[(size_t)(kb * 64 + kl) * KGAT + h * 512 + cb * 8 + jl];
  }
  __syncthreads();
#pragma unroll
  for (int i = 0; i < 4; ++i) {
    const int idx = i * 256 + t;
    const int cl = idx >> 4;
    const int kq = (idx & 15) * 4;
    u16x4 ov;
#pragma unroll
    for (int q = 0; q < 4; ++q) ov[q] = f2b(tile[kq + q][cl]);
    *(u16x4*)&out[(size_t)(cb * 64 + cl) * CRED + kb * 64 + kq] = ov;
  }
}

// ====== 64x128 FUSED reduce GEMM: xr = relu(bn(x_nchw @ w_reduce^T)) =======
__global__ __launch_bounds__(256, 2) void gemm_redf_kernel(
    const float* __restrict__ x, const u16* __restrict__ Bt,
    u16* __restrict__ out16,
    const float* __restrict__ pg, const float* __restrict__ pb,
    const float* __restrict__ pm, const float* __restrict__ pv)
{
  __shared__ u16 As[64 * 32];
  __shared__ u16 Bs[128 * 32];
  const int tid = threadIdx.x;
  const int wave = tid >> 6, lane = tid & 63;
  const int gx = gridDim.x;
  const int nwg = gx * gridDim.y;
  int lin = blockIdx.y * gx + blockIdx.x;
  lin = (lin & 7) * (nwg >> 3) + (lin >> 3);
  const int m0 = (lin / gx) * 64, n0 = (lin % gx) * 128;
  const int bimg = m0 >> 8, p0 = m0 & 255;

  const float* xsrc = x + (size_t)bimg * CIN * NPIX + p0 + lane;

  int offB[2], dstB[2];
#pragma unroll
  for (int i = 0; i < 2; ++i) {
    const int f = i * 256 + tid;
    const int r = f >> 2;
    const int kb = (f & 3) ^ ((r >> 1) & 3);
    offB[i] = r * CIN + kb * 8;
    dstB[i] = (i * 256 + wave * 64) * 8;
  }
  const u16* gB = Bt + (size_t)n0 * CIN;

  const int aWr = (lane * 4 + (wave ^ ((lane >> 1) & 3))) * 8;

  f32x4 acc[2][4];
#pragma unroll
  for (int i = 0; i < 2; ++i)
#pragma unroll
    for (int j = 0; j < 4; ++j) acc[i][j] = f32x4{0.f, 0.f, 0.f, 0.f};

  const int wr = wave >> 1, wc = wave & 1;
  const int l15 = lane & 15, l4 = lane >> 4;
  const int kq = (l4 ^ ((l15 >> 1) & 3)) * 8;

  float av[8];
#pragma unroll
  for (int j = 0; j < 8; ++j) av[j] = xsrc[(wave * 8 + j) * NPIX];

  for (int kt = 0; kt < CIN; kt += 32) {
    u16x8 pvv;
#pragma unroll
    for (int j = 0; j < 8; ++j) pvv[j] = f2b(av[j]);
    *(u16x8*)&As[aWr] = pvv;
    gload_lds16(gB + kt + offB[0], &Bs[dstB[0]]);
    gload_lds16(gB + kt + offB[1], &Bs[dstB[1]]);
    __syncthreads();
    if (kt + 32 < CIN) {
#pragma unroll
      for (int j = 0; j < 8; ++j)
        av[j] = xsrc[(kt + 32 + wave * 8 + j) * NPIX];
    }
    bf16x8 af[2], bfr[4];
#pragma unroll
    for (int f = 0; f < 2; ++f)
      af[f] = *(const bf16x8*)&As[(wr * 32 + f * 16 + l15) * 32 + kq];
#pragma unroll
    for (int f = 0; f < 4; ++f)
      bfr[f] = *(const bf16x8*)&Bs[(wc * 64 + f * 16 + l15) * 32 + kq];
#pragma unroll
    for (int fm = 0; fm < 2; ++fm)
#pragma unroll
      for (int fn = 0; fn < 4; ++fn)
        acc[fm][fn] = __builtin_amdgcn_mfma_f32_16x16x32_bf16(
            af[fm], bfr[fn], acc[fm][fn], 0, 0, 0);
    __syncthreads();
  }

  const int rowb = m0 + wr * 32 + (lane >> 4) * 4;
#pragma unroll
  for (int fn = 0; fn < 4; ++fn) {
    const int col = n0 + wc * 64 + fn * 16 + l15;
    const float sc = pg[col] * rsqrtf(pv[col] + EPSB);
    const float off = pb[col] - pm[col] * sc;
#pragma unroll
    for (int fm = 0; fm < 2; ++fm) {
      const int row = rowb + fm * 16;
#pragma unroll
      for (int r = 0; r < 4; ++r) {
        const float y = fmaxf(acc[fm][fn][r] * sc + off, 0.f);
        out16[(size_t)(row + r) * CRED + col] = f2b(y);
      }
    }
  }
}

// --------- elementwise fp32 -> bf16 convert, two buffers, one launch -------
__global__ __launch_bounds__(256) void cvt2_kernel(
    const float* __restrict__ s0, u16* __restrict__ d0,
    const float* __restrict__ s1, u16* __restrict__ d1, int half)
{
  const int bi = blockIdx.x;
  const float* src = (bi < half) ? s0 : s1;
  u16* dst = (bi < half) ? d0 : d1;
  const int i = ((bi < half ? bi : bi - half) * 256 + threadIdx.x) * 8;
  const float4 a = *(const float4*)&src[i];
  const float4 b = *(const float4*)&src[i + 4];
  u16x8 o;
  o[0] = f2b(a.x); o[1] = f2b(a.y); o[2] = f2b(a.z); o[3] = f2b(a.w);
  o[4] = f2b(b.x); o[5] = f2b(b.y); o[6] = f2b(b.z); o[7] = f2b(b.w);
  *(u16x8*)&dst[i] = o;
}

// ---------- P[s][h][c] = sum_t w_gat[c][h*512+t] * att_s[h][t] -------------
__global__ __launch_bounds__(128) void attproj_kernel(
    const float* __restrict__ w_gat, const float* __restrict__ att_src,
    const float* __restrict__ att_dst, float* __restrict__ P)
{
  __shared__ float av[CRED];
  const int bi = blockIdx.x;
  const int sh = bi & 15, q = bi >> 4;
  const int s = sh >> 3, h = sh & 7;
  const float* att = (s == 0) ? att_src : att_dst;
  for (int t = threadIdx.x; t < CRED; t += 128) av[t] = att[h * CRED + t];
  __syncthreads();
  const int c = q * 128 + threadIdx.x;
  const float* wrow = w_gat + (size_t)c * KGAT + h * CRED;
  float acc = 0.f;
  for (int j = 0; j < CRED; j += 4) {
    const float4 w = *(const float4*)&wrow[j];
    acc += w.x * av[j] + w.y * av[j + 1] + w.z * av[j + 2] + w.w * av[j + 3];
  }
  P[(size_t)sh * CRED + c] = acc;
}

// ---------- a_all[s][n][h] = xr[n] . P[s][h]   (one wave per node) ---------
__global__ __launch_bounds__(256) void att_kernel(
    const u16* __restrict__ xr, const float* __restrict__ P,
    float* __restrict__ a_all)
{
  const int wave = threadIdx.x >> 6, lane = threadIdx.x & 63;
  const int m = blockIdx.x * 4 + wave;
  const int sh = lane & 15, q = lane >> 4;
  const u16* xp = xr + (size_t)m * CRED + q * 128;
  const float* Pp = P + (size_t)sh * CRED + q * 128;
  float s = 0.f;
#pragma unroll
  for (int c = 0; c < 128; c += 8) {
    u16x8 xv = *(const u16x8*)&xp[c];
#pragma unroll
    for (int t = 0; t < 8; ++t) s += b2f(xv[t]) * Pp[c + t];
  }
  s += __shfl_xor(s, 16);
  s += __shfl_xor(s, 32);
  if (q == 0)
    a_all[(size_t)(sh >> 3) * MTOT * HEADS + (size_t)m * HEADS + (sh & 7)] = s;
}

// ---------------------------------------------------------------------------
extern "C" void kernel_launch(void* const* d_in, const int* in_sizes, int n_in,
                              void* d_out, int out_size, void* d_ws, size_t ws_size,
                              hipStream_t stream)
{
  const float* x         = (const float*)d_in[0];
  const float* w_reduce  = (const float*)d_in[1];
  const float* g_red     = (const float*)d_in[2];
  const float* b_red     = (const float*)d_in[3];
  const float* m_red     = (const float*)d_in[4];
  const float* v_red     = (const float*)d_in[5];
  const float* w_gat     = (const float*)d_in[6];
  const float* att_src   = (const float*)d_in[7];
  const float* att_dst   = (const float*)d_in[8];
  const float* gat_bias  = (const float*)d_in[9];
  const float* w_restore = (const float*)d_in[10];
  const float* g_res     = (const float*)d_in[11];
  const float* b_res     = (const float*)d_in[12];
  const float* m_res     = (const float*)d_in[13];
  const float* v_res     = (const float*)d_in[14];

  constexpr size_t SZ_XR   = (size_t)MTOT * CRED * 2;
  constexpr size_t SZ_GAT  = SZ_XR;
  constexpr size_t SZ_WGT  = (size_t)KGAT * CRED * 2;
  constexpr size_t SZ_WRD  = (size_t)CRED * CIN * 2;
  constexpr size_t SZ_WRS  = (size_t)COUT * CRED * 2;
  constexpr size_t SZ_P    = (size_t)16 * CRED * 4;
  constexpr size_t SZ_AALL = (size_t)2 * MTOT * HEADS * 4;
  char* ws = (char*)d_ws;
  u16*   xr     = (u16*)ws;
  u16*   gat    = (u16*)(ws + SZ_XR);
  u16*   WgT2p  = (u16*)(ws + SZ_XR + SZ_GAT);
  u16*   wred_b = (u16*)(ws + SZ_XR + SZ_GAT + SZ_WGT);
  u16*   wres_b = (u16*)(ws + SZ_XR + SZ_GAT + SZ_WGT + SZ_WRD);
  float* P      = (float*)(ws + SZ_XR + SZ_GAT + SZ_WGT + SZ_WRD + SZ_WRS);
  float* a_all  = (float*)(ws + SZ_XR + SZ_GAT + SZ_WGT + SZ_WRD + SZ_WRS + SZ_P);
  u16*   alf_g  = (u16*)(ws + SZ_XR + SZ_GAT + SZ_WGT + SZ_WRD + SZ_WRS + SZ_P + SZ_AALL);
  float* outp   = (float*)d_out;

  hipFuncSetAttribute((const void*)gemmf2_kernel,
                      hipFuncAttributeMaxDynamicSharedMemorySize, 69632);
  hipFuncSetAttribute((const void*)gemm_res3_kernel,
                      hipFuncAttributeMaxDynamicSharedMemorySize, 49152);

  wgatp_kernel<<<dim3(64, 8), 256, 0, stream>>>(w_gat, WgT2p);
  cvt2_kernel<<<512, 256, 0, stream>>>(
      w_reduce, wred_b, w_restore, wres_b, 256);
  gemm_redf_kernel<<<dim3(4, 256), 256, 0, stream>>>(
      x, wred_b, xr, g_red, b_red, m_red, v_red);
  attproj_kernel<<<64, 128, 0, stream>>>(w_gat, att_src, att_dst, P);
  att_kernel<<<MTOT / 4, 256, 0, stream>>>(xr, P, a_all);
  alphapre_kernel<<<512, 256, 0, stream>>>(a_all, alf_g);
  gemmf2_kernel<<<2048, 512, 69632, stream>>>(
      xr, WgT2p, alf_g, gat_bias, gat);
  gemm_res3_kernel<<<512, 512, 49152, stream>>>(
      gat, wres_b, outp, g_res, b_res, m_res, v_res, x);
  (void)in_sizes; (void)n_in; (void)out_size; (void)ws_size;
}